// Round 1
// baseline (535.708 us; speedup 1.0000x reference)
//
#include <hip/hip_runtime.h>
#include <hip/hip_bf16.h>

#define A_  512
#define D_  512
#define H_  8
#define HD_ 64
#define TD_ 1536   // 3*D
#define RH_ 512    // REL_HID

// ---------------------------------------------------------------------------
// Kernel 0: mask -> float bias (-1e9 / 0), with on-device layout detection.
// jax bool may arrive as 1-byte bool or int32; in int32 {0,1} layout every
// byte at index%4!=0 is zero. 10% bernoulli over 768 such bytes makes the
// bool layout detectable with certainty. Deterministic given fixed inputs.
// ---------------------------------------------------------------------------
__global__ __launch_bounds__(1024) void mask_kernel(const void* __restrict__ mraw,
                                                    float* __restrict__ maskf) {
    __shared__ int anyOdd;
    const int tid = threadIdx.x;          // 0..1023 == B*A
    if (tid == 0) anyOdd = 0;
    __syncthreads();
    const unsigned char* mb = (const unsigned char*)mraw;
    unsigned char v = mb[tid];            // safe: buffer is >= 1024 bytes either way
    if ((tid & 3) != 0 && v != 0) atomicOr(&anyOdd, 1);
    __syncthreads();
    const bool isByte = (anyOdd != 0);
    int set = isByte ? (mb[tid] != 0) : (((const int*)mraw)[tid] != 0);
    maskf[tid] = set ? -1e9f : 0.0f;
}

// ---------------------------------------------------------------------------
// Generic fp32 tiled GEMM: C[M,N] = op(A[M,K] @ B[K,N] + bias), op = relu?
// BM=BN=64, BK=16, 256 threads, 4x4 micro-tile per thread.
// ---------------------------------------------------------------------------
template<int RELU>
__global__ __launch_bounds__(256) void gemm_kernel(const float* __restrict__ Am,
                                                   const float* __restrict__ Bm,
                                                   const float* __restrict__ bias,
                                                   float* __restrict__ Cm,
                                                   int M, int N, int K) {
    __shared__ float As[64][17];   // +1 pad: tm-groups land on distinct banks
    __shared__ float Bs[16][68];   // row stride 272B keeps 16B alignment
    const int tid = threadIdx.x;
    const int bm = blockIdx.y * 64, bn = blockIdx.x * 64;
    const int tn = tid & 15, tm = tid >> 4;
    const int ar = tid >> 2, ac = (tid & 3) << 2;
    const int br = tid >> 4, bc = (tid & 15) << 2;
    float acc[4][4] = {};
    for (int k0 = 0; k0 < K; k0 += 16) {
        float4 av = *reinterpret_cast<const float4*>(&Am[(size_t)(bm + ar) * K + k0 + ac]);
        float4 bv = *reinterpret_cast<const float4*>(&Bm[(size_t)(k0 + br) * N + bn + bc]);
        As[ar][ac]   = av.x; As[ar][ac+1] = av.y; As[ar][ac+2] = av.z; As[ar][ac+3] = av.w;
        Bs[br][bc]   = bv.x; Bs[br][bc+1] = bv.y; Bs[br][bc+2] = bv.z; Bs[br][bc+3] = bv.w;
        __syncthreads();
        #pragma unroll
        for (int kk = 0; kk < 16; ++kk) {
            const float a0 = As[tm*4+0][kk];
            const float a1 = As[tm*4+1][kk];
            const float a2 = As[tm*4+2][kk];
            const float a3 = As[tm*4+3][kk];
            const float4 b4 = *reinterpret_cast<const float4*>(&Bs[kk][tn*4]);
            acc[0][0] += a0*b4.x; acc[0][1] += a0*b4.y; acc[0][2] += a0*b4.z; acc[0][3] += a0*b4.w;
            acc[1][0] += a1*b4.x; acc[1][1] += a1*b4.y; acc[1][2] += a1*b4.z; acc[1][3] += a1*b4.w;
            acc[2][0] += a2*b4.x; acc[2][1] += a2*b4.y; acc[2][2] += a2*b4.z; acc[2][3] += a2*b4.w;
            acc[3][0] += a3*b4.x; acc[3][1] += a3*b4.y; acc[3][2] += a3*b4.z; acc[3][3] += a3*b4.w;
        }
        __syncthreads();
    }
    const int c0 = bn + tn*4;
    #pragma unroll
    for (int r = 0; r < 4; ++r) {
        float4 o;
        o.x = acc[r][0] + bias[c0+0];
        o.y = acc[r][1] + bias[c0+1];
        o.z = acc[r][2] + bias[c0+2];
        o.w = acc[r][3] + bias[c0+3];
        if (RELU) {
            o.x = fmaxf(o.x, 0.f); o.y = fmaxf(o.y, 0.f);
            o.z = fmaxf(o.z, 0.f); o.w = fmaxf(o.w, 0.f);
        }
        *reinterpret_cast<float4*>(&Cm[(size_t)(bm + tm*4 + r) * N + c0]) = o;
    }
}

// ---------------------------------------------------------------------------
// Relation MLP: per pair (b,i,j): 16*sigmoid( relu(rel@W1+b1) @ W2 )
// One thread per pair; n-loop index is block-uniform so weight loads
// scalarize to s_load. Writes relb[(b*H+h)*A*A + i*A + j].
// ---------------------------------------------------------------------------
__global__ __launch_bounds__(256) void relmlp_kernel(const float* __restrict__ rel,
                                                     const float* __restrict__ w1,
                                                     const float* __restrict__ b1,
                                                     const float* __restrict__ w2,
                                                     float* __restrict__ relb) {
    const int p = blockIdx.x * 256 + threadIdx.x;   // 0 .. B*A*A-1
    const int b = p >> 18;
    const int ij = p & 262143;
    const int i = ij >> 9, j = ij & 511;
    const float4 r4 = *reinterpret_cast<const float4*>(&rel[(size_t)p * 4]);
    float acc[8] = {};
    #pragma unroll 4
    for (int n = 0; n < RH_; ++n) {
        float hv = b1[n];
        hv += r4.x * w1[n];
        hv += r4.y * w1[RH_ + n];
        hv += r4.z * w1[2*RH_ + n];
        hv += r4.w * w1[3*RH_ + n];
        hv = fmaxf(hv, 0.0f);
        #pragma unroll
        for (int h = 0; h < 8; ++h) acc[h] += hv * w2[n*8 + h];
    }
    #pragma unroll
    for (int h = 0; h < 8; ++h) {
        const float s = 16.0f / (1.0f + __expf(-acc[h]));
        relb[(((size_t)(b*H_ + h) * A_ + i) * A_) + j] = s;
    }
}

// ---------------------------------------------------------------------------
// Attention: one block (256 thr) per (b,h,i) row. logits -> softmax -> @V.
// relb already holds 16*sigmoid(rel_emb); maskf holds -1e9/0 per (b,j).
// ---------------------------------------------------------------------------
__global__ __launch_bounds__(256) void attn_kernel(const float* __restrict__ qkv,
                                                   const float* __restrict__ relb,
                                                   const float* __restrict__ maskf,
                                                   float* __restrict__ outbuf) {
    const int row = blockIdx.x;           // (b*H+h)*A + i
    const int i  = row & (A_-1);
    const int bh = row >> 9;
    const int h  = bh & (H_-1), b = bh >> 3;
    const int tid = threadIdx.x;

    __shared__ float qs[64];
    __shared__ float ps[A_];
    __shared__ float rmax[4], rsum[4];
    __shared__ float oa[4][64];

    if (tid < 64) qs[tid] = qkv[(size_t)(b*A_ + i)*TD_ + h*HD_ + tid] * 0.125f;
    __syncthreads();

    const float* kbase = qkv + (size_t)b*A_*TD_ + D_ + h*HD_;
    const float* rbase = relb + (size_t)row * A_;
    const float* mbase = maskf + b*A_;

    float lg[2];
    float lmax = -3.0e38f;
    #pragma unroll
    for (int t = 0; t < 2; ++t) {
        const int j = tid + t*256;
        const float* krow = kbase + (size_t)j * TD_;
        float dot = 0.f;
        #pragma unroll
        for (int d4 = 0; d4 < 64; d4 += 4) {
            const float4 kv = *reinterpret_cast<const float4*>(&krow[d4]);
            const float4 qv = *reinterpret_cast<const float4*>(&qs[d4]);
            dot += qv.x*kv.x + qv.y*kv.y + qv.z*kv.z + qv.w*kv.w;
        }
        const float l = dot + rbase[j] + mbase[j];
        lg[t] = l;
        lmax = fmaxf(lmax, l);
    }
    #pragma unroll
    for (int o = 32; o > 0; o >>= 1) lmax = fmaxf(lmax, __shfl_down(lmax, o));
    if ((tid & 63) == 0) rmax[tid >> 6] = lmax;
    __syncthreads();
    const float bmax = fmaxf(fmaxf(rmax[0], rmax[1]), fmaxf(rmax[2], rmax[3]));

    float lsum = 0.f;
    #pragma unroll
    for (int t = 0; t < 2; ++t) {
        const int j = tid + t*256;
        const float e = __expf(lg[t] - bmax);
        ps[j] = e;
        lsum += e;
    }
    #pragma unroll
    for (int o = 32; o > 0; o >>= 1) lsum += __shfl_down(lsum, o);
    if ((tid & 63) == 0) rsum[tid >> 6] = lsum;
    __syncthreads();
    const float inv = 1.0f / (rsum[0] + rsum[1] + rsum[2] + rsum[3]);

    const int d = tid & 63, jg = tid >> 6;
    const float* vbase = qkv + (size_t)b*A_*TD_ + 2*D_ + h*HD_ + d;
    float acc = 0.f;
    #pragma unroll 4
    for (int j = jg; j < A_; j += 4) acc += ps[j] * vbase[(size_t)j * TD_];
    oa[jg][d] = acc;
    __syncthreads();
    if (tid < 64) {
        const float o = (oa[0][d] + oa[1][d] + oa[2][d] + oa[3][d]) * inv;
        outbuf[(size_t)(b*A_ + i)*D_ + h*HD_ + d] = o;
    }
}

// ---------------------------------------------------------------------------
// Fused residual + LayerNorm over last dim (512). One block per row.
// ---------------------------------------------------------------------------
__global__ __launch_bounds__(256) void ln_kernel(const float* __restrict__ a,
                                                 const float* __restrict__ r,
                                                 const float* __restrict__ g,
                                                 const float* __restrict__ bb,
                                                 float* __restrict__ out) {
    const int row = blockIdx.x;           // 0..B*A-1
    const int tid = threadIdx.x;
    const size_t base = (size_t)row * D_ + tid * 2;
    const float2 a2 = *reinterpret_cast<const float2*>(&a[base]);
    const float2 r2 = *reinterpret_cast<const float2*>(&r[base]);
    const float e0 = a2.x + r2.x, e1 = a2.y + r2.y;
    float s = e0 + e1;
    float q = e0*e0 + e1*e1;
    #pragma unroll
    for (int o = 32; o > 0; o >>= 1) { s += __shfl_down(s, o); q += __shfl_down(q, o); }
    __shared__ float rs[4], rq[4];
    if ((tid & 63) == 0) { rs[tid >> 6] = s; rq[tid >> 6] = q; }
    __syncthreads();
    const float S = rs[0]+rs[1]+rs[2]+rs[3];
    const float Q = rq[0]+rq[1]+rq[2]+rq[3];
    const float mean = S * (1.0f/512.0f);
    const float var  = Q * (1.0f/512.0f) - mean*mean;
    const float rstd = rsqrtf(var + 1e-5f);
    const int c = tid*2;
    float2 ov;
    ov.x = (e0 - mean)*rstd*g[c]   + bb[c];
    ov.y = (e1 - mean)*rstd*g[c+1] + bb[c+1];
    *reinterpret_cast<float2*>(&out[base]) = ov;
}

// ---------------------------------------------------------------------------
extern "C" void kernel_launch(void* const* d_in, const int* in_sizes, int n_in,
                              void* d_out, int out_size, void* d_ws, size_t ws_size,
                              hipStream_t stream) {
    const float* x        = (const float*)d_in[0];
    const void*  mask     = d_in[1];
    const float* relation = (const float*)d_in[2];
    const float* qkv_w    = (const float*)d_in[3];
    const float* qkv_b    = (const float*)d_in[4];
    const float* rel_w1   = (const float*)d_in[5];
    const float* rel_b1   = (const float*)d_in[6];
    const float* rel_w2   = (const float*)d_in[7];
    const float* ff_w1    = (const float*)d_in[8];
    const float* ff_b1    = (const float*)d_in[9];
    const float* ff_w2    = (const float*)d_in[10];
    const float* ff_b2    = (const float*)d_in[11];
    const float* ln1_g    = (const float*)d_in[12];
    const float* ln1_b    = (const float*)d_in[13];
    const float* ln2_g    = (const float*)d_in[14];
    const float* ln2_b    = (const float*)d_in[15];
    float* out = (float*)d_out;

    float* ws    = (float*)d_ws;
    float* qkv   = ws;                    // 2*512*1536      = 1,572,864 f
    float* relb  = qkv   + 1572864;       // 2*8*512*512     = 4,194,304 f
    float* maskf = relb  + 4194304;       // 1024 f
    float* attnb = maskf + 1024;          // 524,288 f
    float* x1    = attnb + 524288;        // 524,288 f
    float* ffh   = x1    + 524288;        // 1,572,864 f
    float* ff2o  = qkv;                   // reuse: qkv dead after attention

    mask_kernel<<<1, 1024, 0, stream>>>(mask, maskf);
    // qkv = x @ qkv_w + qkv_b            (1024 x 1536, K=512)
    gemm_kernel<0><<<dim3(1536/64, 1024/64), 256, 0, stream>>>(x, qkv_w, qkv_b, qkv, 1024, 1536, 512);
    // relb = 16*sigmoid(MLP(relation))   (B,H,A,A)
    relmlp_kernel<<<(2*512*512)/256, 256, 0, stream>>>(relation, rel_w1, rel_b1, rel_w2, relb);
    // attention
    attn_kernel<<<2*8*512, 256, 0, stream>>>(qkv, relb, maskf, attnb);
    // x1 = LN(attn + x)
    ln_kernel<<<1024, 256, 0, stream>>>(attnb, x, ln1_g, ln1_b, x1);
    // ffh = relu(x1 @ ff_w1 + ff_b1)     (1024 x 1536, K=512)
    gemm_kernel<1><<<dim3(1536/64, 1024/64), 256, 0, stream>>>(x1, ff_w1, ff_b1, ffh, 1024, 1536, 512);
    // ff2o = ffh @ ff_w2 + ff_b2         (1024 x 512, K=1536)
    gemm_kernel<0><<<dim3(512/64, 1024/64), 256, 0, stream>>>(ffh, ff_w2, ff_b2, ff2o, 1024, 512, 1536);
    // out = LN(ff2o + x1)
    ln_kernel<<<1024, 256, 0, stream>>>(ff2o, x1, ln2_g, ln2_b, out);
}

// Round 2
// 352.115 us; speedup vs baseline: 1.5214x; 1.5214x over previous
//
#include <hip/hip_runtime.h>
#include <hip/hip_bf16.h>

#define A_  512
#define D_  512
#define H_  8
#define HD_ 64
#define TD_ 1536   // 3*D
#define RH_ 512    // REL_HID

// ---------------------------------------------------------------------------
// Kernel 0: mask -> float bias (-1e9 / 0), with on-device layout detection.
// ---------------------------------------------------------------------------
__global__ __launch_bounds__(1024) void mask_kernel(const void* __restrict__ mraw,
                                                    float* __restrict__ maskf) {
    __shared__ int anyOdd;
    const int tid = threadIdx.x;          // 0..1023 == B*A
    if (tid == 0) anyOdd = 0;
    __syncthreads();
    const unsigned char* mb = (const unsigned char*)mraw;
    unsigned char v = mb[tid];
    if ((tid & 3) != 0 && v != 0) atomicOr(&anyOdd, 1);
    __syncthreads();
    const bool isByte = (anyOdd != 0);
    int set = isByte ? (mb[tid] != 0) : (((const int*)mraw)[tid] != 0);
    maskf[tid] = set ? -1e9f : 0.0f;
}

// ---------------------------------------------------------------------------
// Generic fp32 tiled GEMM: C[M,N] = op(A[M,K] @ B[K,N] + bias), op = relu?
// BM=BN=64, BK=16, 256 threads, 4x4 micro-tile per thread.
// ---------------------------------------------------------------------------
template<int RELU>
__global__ __launch_bounds__(256) void gemm_kernel(const float* __restrict__ Am,
                                                   const float* __restrict__ Bm,
                                                   const float* __restrict__ bias,
                                                   float* __restrict__ Cm,
                                                   int M, int N, int K) {
    __shared__ float As[64][17];
    __shared__ float Bs[16][68];
    const int tid = threadIdx.x;
    const int bm = blockIdx.y * 64, bn = blockIdx.x * 64;
    const int tn = tid & 15, tm = tid >> 4;
    const int ar = tid >> 2, ac = (tid & 3) << 2;
    const int br = tid >> 4, bc = (tid & 15) << 2;
    float acc[4][4] = {};
    for (int k0 = 0; k0 < K; k0 += 16) {
        float4 av = *reinterpret_cast<const float4*>(&Am[(size_t)(bm + ar) * K + k0 + ac]);
        float4 bv = *reinterpret_cast<const float4*>(&Bm[(size_t)(k0 + br) * N + bn + bc]);
        As[ar][ac]   = av.x; As[ar][ac+1] = av.y; As[ar][ac+2] = av.z; As[ar][ac+3] = av.w;
        Bs[br][bc]   = bv.x; Bs[br][bc+1] = bv.y; Bs[br][bc+2] = bv.z; Bs[br][bc+3] = bv.w;
        __syncthreads();
        #pragma unroll
        for (int kk = 0; kk < 16; ++kk) {
            const float a0 = As[tm*4+0][kk];
            const float a1 = As[tm*4+1][kk];
            const float a2 = As[tm*4+2][kk];
            const float a3 = As[tm*4+3][kk];
            const float4 b4 = *reinterpret_cast<const float4*>(&Bs[kk][tn*4]);
            acc[0][0] += a0*b4.x; acc[0][1] += a0*b4.y; acc[0][2] += a0*b4.z; acc[0][3] += a0*b4.w;
            acc[1][0] += a1*b4.x; acc[1][1] += a1*b4.y; acc[1][2] += a1*b4.z; acc[1][3] += a1*b4.w;
            acc[2][0] += a2*b4.x; acc[2][1] += a2*b4.y; acc[2][2] += a2*b4.z; acc[2][3] += a2*b4.w;
            acc[3][0] += a3*b4.x; acc[3][1] += a3*b4.y; acc[3][2] += a3*b4.z; acc[3][3] += a3*b4.w;
        }
        __syncthreads();
    }
    const int c0 = bn + tn*4;
    #pragma unroll
    for (int r = 0; r < 4; ++r) {
        float4 o;
        o.x = acc[r][0] + bias[c0+0];
        o.y = acc[r][1] + bias[c0+1];
        o.z = acc[r][2] + bias[c0+2];
        o.w = acc[r][3] + bias[c0+3];
        if (RELU) {
            o.x = fmaxf(o.x, 0.f); o.y = fmaxf(o.y, 0.f);
            o.z = fmaxf(o.z, 0.f); o.w = fmaxf(o.w, 0.f);
        }
        *reinterpret_cast<float4*>(&Cm[(size_t)(bm + tm*4 + r) * N + c0]) = o;
    }
}

// ---------------------------------------------------------------------------
// Relation MLP: per pair (b,i,j): 16*sigmoid( relu(rel@W1+b1) @ W2 )
// ---------------------------------------------------------------------------
__global__ __launch_bounds__(256) void relmlp_kernel(const float* __restrict__ rel,
                                                     const float* __restrict__ w1,
                                                     const float* __restrict__ b1,
                                                     const float* __restrict__ w2,
                                                     float* __restrict__ relb) {
    const int p = blockIdx.x * 256 + threadIdx.x;   // 0 .. B*A*A-1
    const int b = p >> 18;
    const int ij = p & 262143;
    const int i = ij >> 9, j = ij & 511;
    const float4 r4 = *reinterpret_cast<const float4*>(&rel[(size_t)p * 4]);
    float acc[8] = {};
    #pragma unroll 4
    for (int n = 0; n < RH_; ++n) {
        float hv = b1[n];
        hv += r4.x * w1[n];
        hv += r4.y * w1[RH_ + n];
        hv += r4.z * w1[2*RH_ + n];
        hv += r4.w * w1[3*RH_ + n];
        hv = fmaxf(hv, 0.0f);
        #pragma unroll
        for (int h = 0; h < 8; ++h) acc[h] += hv * w2[n*8 + h];
    }
    #pragma unroll
    for (int h = 0; h < 8; ++h) {
        const float s = 16.0f / (1.0f + __expf(-acc[h]));
        relb[(((size_t)(b*H_ + h) * A_ + i) * A_) + j] = s;
    }
}

// ---------------------------------------------------------------------------
// S = (Q*0.125) @ K^T + relb + maskbias   (in-place over relb)
// One block per (j-tile, i-tile, bh): 64x64 tile, K=64 staged once.
// K^T staged into LDS with 68-stride (16B-aligned rows, conflict-free reads).
// ---------------------------------------------------------------------------
__global__ __launch_bounds__(256) void sgemm_kernel(const float* __restrict__ qkv,
                                                    const float* __restrict__ maskf,
                                                    float* __restrict__ S) {
    const int bh = blockIdx.z;
    const int b = bh >> 3, h = bh & 7;
    const int bm = blockIdx.y * 64, bn = blockIdx.x * 64;
    const float* Qb = qkv + (size_t)b*A_*TD_ + h*HD_;         // Q[i][d], row stride TD_
    const float* Kb = qkv + (size_t)b*A_*TD_ + D_ + h*HD_;    // K[j][d], row stride TD_
    __shared__ __align__(16) float Qs[64][17];
    __shared__ __align__(16) float Ks[64][68];                // [d][j]
    const int tid = threadIdx.x;
    {
        const int r  = tid >> 2;            // 0..63 row within tile
        const int c4 = (tid & 3) * 16;      // d-base
        #pragma unroll
        for (int u = 0; u < 4; ++u) {
            float4 qv = *reinterpret_cast<const float4*>(&Qb[(size_t)(bm + r)*TD_ + c4 + u*4]);
            Qs[r][c4+u*4+0] = qv.x * 0.125f;
            Qs[r][c4+u*4+1] = qv.y * 0.125f;
            Qs[r][c4+u*4+2] = qv.z * 0.125f;
            Qs[r][c4+u*4+3] = qv.w * 0.125f;
            float4 kv = *reinterpret_cast<const float4*>(&Kb[(size_t)(bn + r)*TD_ + c4 + u*4]);
            Ks[c4+u*4+0][r] = kv.x;
            Ks[c4+u*4+1][r] = kv.y;
            Ks[c4+u*4+2][r] = kv.z;
            Ks[c4+u*4+3][r] = kv.w;
        }
    }
    __syncthreads();
    const int tn = tid & 15, tm = tid >> 4;
    float acc[4][4] = {};
    #pragma unroll 16
    for (int kk = 0; kk < 64; ++kk) {
        const float a0 = Qs[tm*4+0][kk];
        const float a1 = Qs[tm*4+1][kk];
        const float a2 = Qs[tm*4+2][kk];
        const float a3 = Qs[tm*4+3][kk];
        const float4 b4 = *reinterpret_cast<const float4*>(&Ks[kk][tn*4]);
        acc[0][0] += a0*b4.x; acc[0][1] += a0*b4.y; acc[0][2] += a0*b4.z; acc[0][3] += a0*b4.w;
        acc[1][0] += a1*b4.x; acc[1][1] += a1*b4.y; acc[1][2] += a1*b4.z; acc[1][3] += a1*b4.w;
        acc[2][0] += a2*b4.x; acc[2][1] += a2*b4.y; acc[2][2] += a2*b4.z; acc[2][3] += a2*b4.w;
        acc[3][0] += a3*b4.x; acc[3][1] += a3*b4.y; acc[3][2] += a3*b4.z; acc[3][3] += a3*b4.w;
    }
    float* Sb = S + (size_t)bh * A_ * A_;
    const int c0 = bn + tn*4;
    const float4 m4 = *reinterpret_cast<const float4*>(&maskf[b*A_ + c0]);
    #pragma unroll
    for (int r = 0; r < 4; ++r) {
        const int row = bm + tm*4 + r;
        float4 rb = *reinterpret_cast<const float4*>(&Sb[(size_t)row*A_ + c0]);
        float4 o;
        o.x = acc[r][0] + rb.x + m4.x;
        o.y = acc[r][1] + rb.y + m4.y;
        o.z = acc[r][2] + rb.z + m4.z;
        o.w = acc[r][3] + rb.w + m4.w;
        *reinterpret_cast<float4*>(&Sb[(size_t)row*A_ + c0]) = o;
    }
}

// ---------------------------------------------------------------------------
// Row softmax in-place: one block per row of S (8192 rows x 512).
// ---------------------------------------------------------------------------
__global__ __launch_bounds__(256) void softmax_kernel(float* __restrict__ P) {
    const size_t base = (size_t)blockIdx.x * A_;
    const int tid = threadIdx.x;
    float2 v = *reinterpret_cast<const float2*>(&P[base + tid*2]);
    float m = fmaxf(v.x, v.y);
    #pragma unroll
    for (int o = 32; o > 0; o >>= 1) m = fmaxf(m, __shfl_xor(m, o));
    __shared__ float rm[4], rs[4];
    if ((tid & 63) == 0) rm[tid >> 6] = m;
    __syncthreads();
    const float M = fmaxf(fmaxf(rm[0], rm[1]), fmaxf(rm[2], rm[3]));
    const float e0 = __expf(v.x - M), e1 = __expf(v.y - M);
    float s = e0 + e1;
    #pragma unroll
    for (int o = 32; o > 0; o >>= 1) s += __shfl_xor(s, o);
    if ((tid & 63) == 0) rs[tid >> 6] = s;
    __syncthreads();
    const float inv = 1.0f / (rs[0] + rs[1] + rs[2] + rs[3]);
    float2 ov;
    ov.x = e0 * inv;
    ov.y = e1 * inv;
    *reinterpret_cast<float2*>(&P[base + tid*2]) = ov;
}

// ---------------------------------------------------------------------------
// O = P @ V, per (b,h): M=512, N=64, K=512. Output scattered into
// attnb[(b*A + i)*D + h*64 + d]. Same inner loop as gemm_kernel.
// ---------------------------------------------------------------------------
__global__ __launch_bounds__(256) void pv_kernel(const float* __restrict__ P,
                                                 const float* __restrict__ qkv,
                                                 float* __restrict__ outb) {
    const int bh = blockIdx.y;
    const int b = bh >> 3, h = bh & 7;
    const int bm = blockIdx.x * 64;
    const float* Pb = P + (size_t)bh * A_ * A_;                 // [i][j], ld 512
    const float* Vb = qkv + (size_t)b*A_*TD_ + 2*D_ + h*HD_;    // [j][d], ld TD_
    __shared__ __align__(16) float As[64][17];
    __shared__ __align__(16) float Bs[16][68];
    const int tid = threadIdx.x;
    const int tn = tid & 15, tm = tid >> 4;
    const int ar = tid >> 2, ac = (tid & 3) << 2;
    const int br = tid >> 4, bc = (tid & 15) << 2;
    float acc[4][4] = {};
    for (int k0 = 0; k0 < A_; k0 += 16) {
        float4 av = *reinterpret_cast<const float4*>(&Pb[(size_t)(bm + ar)*A_ + k0 + ac]);
        float4 bv = *reinterpret_cast<const float4*>(&Vb[(size_t)(k0 + br)*TD_ + bc]);
        As[ar][ac]   = av.x; As[ar][ac+1] = av.y; As[ar][ac+2] = av.z; As[ar][ac+3] = av.w;
        Bs[br][bc]   = bv.x; Bs[br][bc+1] = bv.y; Bs[br][bc+2] = bv.z; Bs[br][bc+3] = bv.w;
        __syncthreads();
        #pragma unroll
        for (int kk = 0; kk < 16; ++kk) {
            const float a0 = As[tm*4+0][kk];
            const float a1 = As[tm*4+1][kk];
            const float a2 = As[tm*4+2][kk];
            const float a3 = As[tm*4+3][kk];
            const float4 b4 = *reinterpret_cast<const float4*>(&Bs[kk][tn*4]);
            acc[0][0] += a0*b4.x; acc[0][1] += a0*b4.y; acc[0][2] += a0*b4.z; acc[0][3] += a0*b4.w;
            acc[1][0] += a1*b4.x; acc[1][1] += a1*b4.y; acc[1][2] += a1*b4.z; acc[1][3] += a1*b4.w;
            acc[2][0] += a2*b4.x; acc[2][1] += a2*b4.y; acc[2][2] += a2*b4.z; acc[2][3] += a2*b4.w;
            acc[3][0] += a3*b4.x; acc[3][1] += a3*b4.y; acc[3][2] += a3*b4.z; acc[3][3] += a3*b4.w;
        }
        __syncthreads();
    }
    float* Cb = outb + (size_t)(b*A_ + bm) * D_ + h*HD_;
    #pragma unroll
    for (int r = 0; r < 4; ++r) {
        float4 o;
        o.x = acc[r][0]; o.y = acc[r][1]; o.z = acc[r][2]; o.w = acc[r][3];
        *reinterpret_cast<float4*>(&Cb[(size_t)(tm*4 + r)*D_ + tn*4]) = o;
    }
}

// ---------------------------------------------------------------------------
// Fused residual + LayerNorm over last dim (512). One block per row.
// ---------------------------------------------------------------------------
__global__ __launch_bounds__(256) void ln_kernel(const float* __restrict__ a,
                                                 const float* __restrict__ r,
                                                 const float* __restrict__ g,
                                                 const float* __restrict__ bb,
                                                 float* __restrict__ out) {
    const int row = blockIdx.x;
    const int tid = threadIdx.x;
    const size_t base = (size_t)row * D_ + tid * 2;
    const float2 a2 = *reinterpret_cast<const float2*>(&a[base]);
    const float2 r2 = *reinterpret_cast<const float2*>(&r[base]);
    const float e0 = a2.x + r2.x, e1 = a2.y + r2.y;
    float s = e0 + e1;
    float q = e0*e0 + e1*e1;
    #pragma unroll
    for (int o = 32; o > 0; o >>= 1) { s += __shfl_down(s, o); q += __shfl_down(q, o); }
    __shared__ float rs[4], rq[4];
    if ((tid & 63) == 0) { rs[tid >> 6] = s; rq[tid >> 6] = q; }
    __syncthreads();
    const float S = rs[0]+rs[1]+rs[2]+rs[3];
    const float Q = rq[0]+rq[1]+rq[2]+rq[3];
    const float mean = S * (1.0f/512.0f);
    const float var  = Q * (1.0f/512.0f) - mean*mean;
    const float rstd = rsqrtf(var + 1e-5f);
    const int c = tid*2;
    float2 ov;
    ov.x = (e0 - mean)*rstd*g[c]   + bb[c];
    ov.y = (e1 - mean)*rstd*g[c+1] + bb[c+1];
    *reinterpret_cast<float2*>(&out[base]) = ov;
}

// ---------------------------------------------------------------------------
extern "C" void kernel_launch(void* const* d_in, const int* in_sizes, int n_in,
                              void* d_out, int out_size, void* d_ws, size_t ws_size,
                              hipStream_t stream) {
    const float* x        = (const float*)d_in[0];
    const void*  mask     = d_in[1];
    const float* relation = (const float*)d_in[2];
    const float* qkv_w    = (const float*)d_in[3];
    const float* qkv_b    = (const float*)d_in[4];
    const float* rel_w1   = (const float*)d_in[5];
    const float* rel_b1   = (const float*)d_in[6];
    const float* rel_w2   = (const float*)d_in[7];
    const float* ff_w1    = (const float*)d_in[8];
    const float* ff_b1    = (const float*)d_in[9];
    const float* ff_w2    = (const float*)d_in[10];
    const float* ff_b2    = (const float*)d_in[11];
    const float* ln1_g    = (const float*)d_in[12];
    const float* ln1_b    = (const float*)d_in[13];
    const float* ln2_g    = (const float*)d_in[14];
    const float* ln2_b    = (const float*)d_in[15];
    float* out = (float*)d_out;

    float* ws    = (float*)d_ws;
    float* qkv   = ws;                    // 2*512*1536      = 1,572,864 f
    float* relb  = qkv   + 1572864;       // 2*8*512*512     = 4,194,304 f  (relb -> S -> P)
    float* maskf = relb  + 4194304;       // 1024 f
    float* attnb = maskf + 1024;          // 524,288 f
    float* x1    = attnb + 524288;        // 524,288 f
    float* ffh   = x1    + 524288;        // 1,572,864 f
    float* ff2o  = qkv;                   // reuse: qkv dead after attention

    mask_kernel<<<1, 1024, 0, stream>>>(mask, maskf);
    // qkv = x @ qkv_w + qkv_b            (1024 x 1536, K=512)
    gemm_kernel<0><<<dim3(1536/64, 1024/64), 256, 0, stream>>>(x, qkv_w, qkv_b, qkv, 1024, 1536, 512);
    // relb = 16*sigmoid(MLP(relation))   (B,H,A,A)
    relmlp_kernel<<<(2*512*512)/256, 256, 0, stream>>>(relation, rel_w1, rel_b1, rel_w2, relb);
    // S = Q@K^T + relb + mask  (in place over relb)
    sgemm_kernel<<<dim3(8, 8, 16), 256, 0, stream>>>(qkv, maskf, relb);
    // P = softmax(S) rows
    softmax_kernel<<<16*512, 256, 0, stream>>>(relb);
    // attnb = P @ V
    pv_kernel<<<dim3(8, 16), 256, 0, stream>>>(relb, qkv, attnb);
    // x1 = LN(attn + x)
    ln_kernel<<<1024, 256, 0, stream>>>(attnb, x, ln1_g, ln1_b, x1);
    // ffh = relu(x1 @ ff_w1 + ff_b1)     (1024 x 1536, K=512)
    gemm_kernel<1><<<dim3(1536/64, 1024/64), 256, 0, stream>>>(x1, ff_w1, ff_b1, ffh, 1024, 1536, 512);
    // ff2o = ffh @ ff_w2 + ff_b2         (1024 x 512, K=1536)
    gemm_kernel<0><<<dim3(512/64, 1024/64), 256, 0, stream>>>(ffh, ff_w2, ff_b2, ff2o, 1024, 512, 1536);
    // out = LN(ff2o + x1)
    ln_kernel<<<1024, 256, 0, stream>>>(ff2o, x1, ln2_g, ln2_b, out);
}

// Round 3
// 208.987 us; speedup vs baseline: 2.5634x; 1.6849x over previous
//
#include <hip/hip_runtime.h>
#include <hip/hip_bf16.h>

#define A_  512
#define D_  512
#define H_  8
#define HD_ 64
#define TD_ 1536   // 3*D
#define RH_ 512    // REL_HID

typedef __attribute__((ext_vector_type(8))) short short8v;
typedef __attribute__((ext_vector_type(4))) float f32x4;

__device__ __forceinline__ unsigned short f2bf(float f) {
    unsigned int u = __float_as_uint(f);
    u += 0x7FFFu + ((u >> 16) & 1u);
    return (unsigned short)(u >> 16);
}

// ---------------------------------------------------------------------------
// mask -> float bias (-1e9 / 0), with on-device bool/int32 layout detection.
// ---------------------------------------------------------------------------
__global__ __launch_bounds__(1024) void mask_kernel(const void* __restrict__ mraw,
                                                    float* __restrict__ maskf) {
    __shared__ int anyOdd;
    const int tid = threadIdx.x;          // 0..1023 == B*A
    if (tid == 0) anyOdd = 0;
    __syncthreads();
    const unsigned char* mb = (const unsigned char*)mraw;
    unsigned char v = mb[tid];
    if ((tid & 3) != 0 && v != 0) atomicOr(&anyOdd, 1);
    __syncthreads();
    const bool isByte = (anyOdd != 0);
    int set = isByte ? (mb[tid] != 0) : (((const int*)mraw)[tid] != 0);
    maskf[tid] = set ? -1e9f : 0.0f;
}

// ---------------------------------------------------------------------------
// Elementwise fp32 -> bf16 (8 elems/thread).
// ---------------------------------------------------------------------------
__global__ __launch_bounds__(256) void cvt_kernel(const float* __restrict__ in,
                                                  ushort* __restrict__ out) {
    const int i = (blockIdx.x * 256 + threadIdx.x) * 8;
    const float4 a = *(const float4*)&in[i];
    const float4 b = *(const float4*)&in[i + 4];
    uint4 o;
    o.x = f2bf(a.x) | ((unsigned)f2bf(a.y) << 16);
    o.y = f2bf(a.z) | ((unsigned)f2bf(a.w) << 16);
    o.z = f2bf(b.x) | ((unsigned)f2bf(b.y) << 16);
    o.w = f2bf(b.z) | ((unsigned)f2bf(b.w) << 16);
    *(uint4*)&out[i] = o;
}

// ---------------------------------------------------------------------------
// Transpose + cvt: in fp32 [R][C] -> out bf16 [C][R]. 64x64 tiles.
// ---------------------------------------------------------------------------
__global__ __launch_bounds__(256) void wt_kernel(const float* __restrict__ in,
                                                 ushort* __restrict__ out,
                                                 int R, int C) {
    __shared__ float ts[64][65];
    const int tid = threadIdx.x;
    const int r0 = blockIdx.y * 64, c0 = blockIdx.x * 64;
    const int r = tid >> 2, cb = (tid & 3) * 16;
    #pragma unroll
    for (int u = 0; u < 4; ++u) {
        const float4 v = *(const float4*)&in[(size_t)(r0 + r) * C + c0 + cb + u*4];
        ts[r][cb + u*4 + 0] = v.x;
        ts[r][cb + u*4 + 1] = v.y;
        ts[r][cb + u*4 + 2] = v.z;
        ts[r][cb + u*4 + 3] = v.w;
    }
    __syncthreads();
    const int oc = tid & 63;
    const int rb = (tid >> 6) * 16;
    unsigned pk[8];
    #pragma unroll
    for (int i = 0; i < 8; ++i) {
        const unsigned lo = f2bf(ts[rb + i*2][oc]);
        const unsigned hi = f2bf(ts[rb + i*2 + 1][oc]);
        pk[i] = lo | (hi << 16);
    }
    uint4* dst = (uint4*)&out[(size_t)(c0 + oc) * R + r0 + rb];
    dst[0] = make_uint4(pk[0], pk[1], pk[2], pk[3]);
    dst[1] = make_uint4(pk[4], pk[5], pk[6], pk[7]);
}

// ---------------------------------------------------------------------------
// bf16 MFMA GEMM: C[M,N] = op(A[M,K] @ B[K,N] + bias).
// A is [M][K] bf16, BT is [N][K] bf16 (both K-major). 64x64 tile, BK=64,
// 4 waves (2x2), each wave 32x32 via 16x16x32 MFMA. LDS slot-XOR swizzle.
// ---------------------------------------------------------------------------
template<int RELU, int OBF16>
__global__ __launch_bounds__(256) void mgemm_kernel(const ushort* __restrict__ A,
                                                    const ushort* __restrict__ BT,
                                                    const float* __restrict__ bias,
                                                    void* __restrict__ Cv,
                                                    int M, int N, int K) {
    __shared__ __align__(16) ushort As[64 * 64];
    __shared__ __align__(16) ushort Bs[64 * 64];
    const int tid = threadIdx.x;
    const int bm = blockIdx.y * 64, bn = blockIdx.x * 64;
    const int lane = tid & 63, wave = tid >> 6;
    const int wm = (wave >> 1) * 32, wn = (wave & 1) * 32;
    f32x4 acc[2][2];
    #pragma unroll
    for (int i = 0; i < 2; ++i)
        #pragma unroll
        for (int j = 0; j < 2; ++j) acc[i][j] = (f32x4){0.f, 0.f, 0.f, 0.f};

    const int s0  = tid * 2;
    const int rs  = s0 >> 3;        // staging row (same for both slots: s0 even)
    const int sl0 = s0 & 7;
    for (int k0 = 0; k0 < K; k0 += 64) {
        #pragma unroll
        for (int u = 0; u < 2; ++u) {
            const int sl = sl0 + u;
            const uint4 va = *(const uint4*)&A[(size_t)(bm + rs) * K + k0 + sl*8];
            *(uint4*)((char*)As + rs*128 + ((sl ^ (rs & 7)) << 4)) = va;
            const uint4 vb = *(const uint4*)&BT[(size_t)(bn + rs) * K + k0 + sl*8];
            *(uint4*)((char*)Bs + rs*128 + ((sl ^ (rs & 7)) << 4)) = vb;
        }
        __syncthreads();
        #pragma unroll
        for (int kk = 0; kk < 2; ++kk) {
            short8v af[2], bfv[2];
            #pragma unroll
            for (int mf = 0; mf < 2; ++mf) {
                const int row = wm + mf*16 + (lane & 15);
                const int slot = (kk*4 + (lane >> 4)) ^ (row & 7);
                af[mf] = *(const short8v*)((const char*)As + row*128 + (slot << 4));
            }
            #pragma unroll
            for (int nf = 0; nf < 2; ++nf) {
                const int row = wn + nf*16 + (lane & 15);
                const int slot = (kk*4 + (lane >> 4)) ^ (row & 7);
                bfv[nf] = *(const short8v*)((const char*)Bs + row*128 + (slot << 4));
            }
            #pragma unroll
            for (int mf = 0; mf < 2; ++mf)
                #pragma unroll
                for (int nf = 0; nf < 2; ++nf)
                    acc[mf][nf] = __builtin_amdgcn_mfma_f32_16x16x32_bf16(af[mf], bfv[nf], acc[mf][nf], 0, 0, 0);
        }
        __syncthreads();
    }
    #pragma unroll
    for (int nf = 0; nf < 2; ++nf) {
        const int col = bn + wn + nf*16 + (lane & 15);
        const float bv = bias[col];
        #pragma unroll
        for (int mf = 0; mf < 2; ++mf) {
            #pragma unroll
            for (int r = 0; r < 4; ++r) {
                const int row = bm + wm + mf*16 + (lane >> 4)*4 + r;
                float v = acc[mf][nf][r] + bv;
                if (RELU) v = fmaxf(v, 0.f);
                if (OBF16) ((ushort*)Cv)[(size_t)row * N + col] = f2bf(v);
                else       ((float*)Cv)[(size_t)row * N + col] = v;
            }
        }
    }
}

// ---------------------------------------------------------------------------
// Relation MLP: layer1 (K=4) in fp32 VALU, computed directly in MFMA A-frag
// layout; layer2 (K=512, N=8 pad 16) via 16x16x32 bf16 MFMA vs LDS-staged
// swizzled W2^T. 64 pairs/block, 16 pairs/wave.
// ---------------------------------------------------------------------------
__global__ __launch_bounds__(256) void relmlp_kernel(const float* __restrict__ rel,
                                                     const float* __restrict__ w1,
                                                     const float* __restrict__ b1,
                                                     const float* __restrict__ w2,
                                                     float* __restrict__ relb) {
    __shared__ __align__(16) float w1s[4 * RH_];
    __shared__ __align__(16) float b1s[RH_];
    __shared__ __align__(16) ushort w2ts[16 * RH_];
    const int tid = threadIdx.x;
    {
        *(float4*)&w1s[tid*8]     = *(const float4*)&w1[tid*8];
        *(float4*)&w1s[tid*8 + 4] = *(const float4*)&w1[tid*8 + 4];
        *(float2*)&b1s[tid*2]     = *(const float2*)&b1[tid*2];
        #pragma unroll
        for (int u = 0; u < 2; ++u) {
            const int k = tid + u*256;
            const float4 wlo = *(const float4*)&w2[k*8];
            const float4 whi = *(const float4*)&w2[k*8 + 4];
            const float wv[8] = {wlo.x, wlo.y, wlo.z, wlo.w, whi.x, whi.y, whi.z, whi.w};
            #pragma unroll
            for (int h = 0; h < 16; ++h) {
                const unsigned short val = (h < 8) ? f2bf(wv[h]) : (unsigned short)0;
                *(ushort*)((char*)w2ts + h*1024 + ((k*2) ^ ((h & 7) << 4))) = val;
            }
        }
    }
    __syncthreads();
    const int lane = tid & 63;
    const int prow = lane & 15, g = lane >> 4;
    const int pbase = blockIdx.x * 64 + (tid >> 6) * 16;
    const float4 r4 = *(const float4*)&rel[(size_t)(pbase + prow) * 4];
    f32x4 acc = {0.f, 0.f, 0.f, 0.f};
    for (int c = 0; c < 16; ++c) {
        const int k8 = c*32 + g*8;
        float4 h0 = *(const float4*)&b1s[k8];
        float4 h1 = *(const float4*)&b1s[k8 + 4];
        #pragma unroll
        for (int d = 0; d < 4; ++d) {
            const float rv = (d == 0) ? r4.x : (d == 1) ? r4.y : (d == 2) ? r4.z : r4.w;
            const float4 wlo = *(const float4*)&w1s[d*RH_ + k8];
            const float4 whi = *(const float4*)&w1s[d*RH_ + k8 + 4];
            h0.x += rv*wlo.x; h0.y += rv*wlo.y; h0.z += rv*wlo.z; h0.w += rv*wlo.w;
            h1.x += rv*whi.x; h1.y += rv*whi.y; h1.z += rv*whi.z; h1.w += rv*whi.w;
        }
        short8v a;
        a[0] = (short)f2bf(fmaxf(h0.x, 0.f));
        a[1] = (short)f2bf(fmaxf(h0.y, 0.f));
        a[2] = (short)f2bf(fmaxf(h0.z, 0.f));
        a[3] = (short)f2bf(fmaxf(h0.w, 0.f));
        a[4] = (short)f2bf(fmaxf(h1.x, 0.f));
        a[5] = (short)f2bf(fmaxf(h1.y, 0.f));
        a[6] = (short)f2bf(fmaxf(h1.z, 0.f));
        a[7] = (short)f2bf(fmaxf(h1.w, 0.f));
        const short8v bfr = *(const short8v*)((const char*)w2ts + prow*1024 + (((c*4 + g) ^ (prow & 7)) << 4));
        acc = __builtin_amdgcn_mfma_f32_16x16x32_bf16(a, bfr, acc, 0, 0, 0);
    }
    const int h = lane & 15;
    if (h < 8) {
        #pragma unroll
        for (int r = 0; r < 4; ++r) {
            const int pp = pbase + g*4 + r;
            const float s = 16.0f / (1.0f + __expf(-acc[r]));
            relb[((size_t)((pp >> 18) * 8 + h) << 18) + (pp & 262143)] = s;
        }
    }
}

// ---------------------------------------------------------------------------
// S = (Q*0.125) @ K^T + relb + maskbias   (in-place over relb) — fp32
// ---------------------------------------------------------------------------
__global__ __launch_bounds__(256) void sgemm_kernel(const float* __restrict__ qkv,
                                                    const float* __restrict__ maskf,
                                                    float* __restrict__ S) {
    const int bh = blockIdx.z;
    const int b = bh >> 3, h = bh & 7;
    const int bm = blockIdx.y * 64, bn = blockIdx.x * 64;
    const float* Qb = qkv + (size_t)b*A_*TD_ + h*HD_;
    const float* Kb = qkv + (size_t)b*A_*TD_ + D_ + h*HD_;
    __shared__ __align__(16) float Qs[64][17];
    __shared__ __align__(16) float Ks[64][68];
    const int tid = threadIdx.x;
    {
        const int r  = tid >> 2;
        const int c4 = (tid & 3) * 16;
        #pragma unroll
        for (int u = 0; u < 4; ++u) {
            float4 qv = *reinterpret_cast<const float4*>(&Qb[(size_t)(bm + r)*TD_ + c4 + u*4]);
            Qs[r][c4+u*4+0] = qv.x * 0.125f;
            Qs[r][c4+u*4+1] = qv.y * 0.125f;
            Qs[r][c4+u*4+2] = qv.z * 0.125f;
            Qs[r][c4+u*4+3] = qv.w * 0.125f;
            float4 kv = *reinterpret_cast<const float4*>(&Kb[(size_t)(bn + r)*TD_ + c4 + u*4]);
            Ks[c4+u*4+0][r] = kv.x;
            Ks[c4+u*4+1][r] = kv.y;
            Ks[c4+u*4+2][r] = kv.z;
            Ks[c4+u*4+3][r] = kv.w;
        }
    }
    __syncthreads();
    const int tn = tid & 15, tm = tid >> 4;
    float acc[4][4] = {};
    #pragma unroll 16
    for (int kk = 0; kk < 64; ++kk) {
        const float a0 = Qs[tm*4+0][kk];
        const float a1 = Qs[tm*4+1][kk];
        const float a2 = Qs[tm*4+2][kk];
        const float a3 = Qs[tm*4+3][kk];
        const float4 b4 = *reinterpret_cast<const float4*>(&Ks[kk][tn*4]);
        acc[0][0] += a0*b4.x; acc[0][1] += a0*b4.y; acc[0][2] += a0*b4.z; acc[0][3] += a0*b4.w;
        acc[1][0] += a1*b4.x; acc[1][1] += a1*b4.y; acc[1][2] += a1*b4.z; acc[1][3] += a1*b4.w;
        acc[2][0] += a2*b4.x; acc[2][1] += a2*b4.y; acc[2][2] += a2*b4.z; acc[2][3] += a2*b4.w;
        acc[3][0] += a3*b4.x; acc[3][1] += a3*b4.y; acc[3][2] += a3*b4.z; acc[3][3] += a3*b4.w;
    }
    float* Sb = S + (size_t)bh * A_ * A_;
    const int c0 = bn + tn*4;
    const float4 m4 = *reinterpret_cast<const float4*>(&maskf[b*A_ + c0]);
    #pragma unroll
    for (int r = 0; r < 4; ++r) {
        const int row = bm + tm*4 + r;
        float4 rb = *reinterpret_cast<const float4*>(&Sb[(size_t)row*A_ + c0]);
        float4 o;
        o.x = acc[r][0] + rb.x + m4.x;
        o.y = acc[r][1] + rb.y + m4.y;
        o.z = acc[r][2] + rb.z + m4.z;
        o.w = acc[r][3] + rb.w + m4.w;
        *reinterpret_cast<float4*>(&Sb[(size_t)row*A_ + c0]) = o;
    }
}

// ---------------------------------------------------------------------------
// Row softmax in-place (8192 rows x 512).
// ---------------------------------------------------------------------------
__global__ __launch_bounds__(256) void softmax_kernel(float* __restrict__ P) {
    const size_t base = (size_t)blockIdx.x * A_;
    const int tid = threadIdx.x;
    float2 v = *reinterpret_cast<const float2*>(&P[base + tid*2]);
    float m = fmaxf(v.x, v.y);
    #pragma unroll
    for (int o = 32; o > 0; o >>= 1) m = fmaxf(m, __shfl_xor(m, o));
    __shared__ float rm[4], rs[4];
    if ((tid & 63) == 0) rm[tid >> 6] = m;
    __syncthreads();
    const float M = fmaxf(fmaxf(rm[0], rm[1]), fmaxf(rm[2], rm[3]));
    const float e0 = __expf(v.x - M), e1 = __expf(v.y - M);
    float s = e0 + e1;
    #pragma unroll
    for (int o = 32; o > 0; o >>= 1) s += __shfl_xor(s, o);
    if ((tid & 63) == 0) rs[tid >> 6] = s;
    __syncthreads();
    const float inv = 1.0f / (rs[0] + rs[1] + rs[2] + rs[3]);
    float2 ov;
    ov.x = e0 * inv;
    ov.y = e1 * inv;
    *reinterpret_cast<float2*>(&P[base + tid*2]) = ov;
}

// ---------------------------------------------------------------------------
// O = P @ V per (b,h) — fp32.
// ---------------------------------------------------------------------------
__global__ __launch_bounds__(256) void pv_kernel(const float* __restrict__ P,
                                                 const float* __restrict__ qkv,
                                                 float* __restrict__ outb) {
    const int bh = blockIdx.y;
    const int b = bh >> 3, h = bh & 7;
    const int bm = blockIdx.x * 64;
    const float* Pb = P + (size_t)bh * A_ * A_;
    const float* Vb = qkv + (size_t)b*A_*TD_ + 2*D_ + h*HD_;
    __shared__ __align__(16) float As2[64][17];
    __shared__ __align__(16) float Bs2[16][68];
    const int tid = threadIdx.x;
    const int tn = tid & 15, tm = tid >> 4;
    const int ar = tid >> 2, ac = (tid & 3) << 2;
    const int br = tid >> 4, bc = (tid & 15) << 2;
    float acc[4][4] = {};
    for (int k0 = 0; k0 < A_; k0 += 16) {
        float4 av = *reinterpret_cast<const float4*>(&Pb[(size_t)(bm + ar)*A_ + k0 + ac]);
        float4 bv = *reinterpret_cast<const float4*>(&Vb[(size_t)(k0 + br)*TD_ + bc]);
        As2[ar][ac]   = av.x; As2[ar][ac+1] = av.y; As2[ar][ac+2] = av.z; As2[ar][ac+3] = av.w;
        Bs2[br][bc]   = bv.x; Bs2[br][bc+1] = bv.y; Bs2[br][bc+2] = bv.z; Bs2[br][bc+3] = bv.w;
        __syncthreads();
        #pragma unroll
        for (int kk = 0; kk < 16; ++kk) {
            const float a0 = As2[tm*4+0][kk];
            const float a1 = As2[tm*4+1][kk];
            const float a2 = As2[tm*4+2][kk];
            const float a3 = As2[tm*4+3][kk];
            const float4 b4 = *reinterpret_cast<const float4*>(&Bs2[kk][tn*4]);
            acc[0][0] += a0*b4.x; acc[0][1] += a0*b4.y; acc[0][2] += a0*b4.z; acc[0][3] += a0*b4.w;
            acc[1][0] += a1*b4.x; acc[1][1] += a1*b4.y; acc[1][2] += a1*b4.z; acc[1][3] += a1*b4.w;
            acc[2][0] += a2*b4.x; acc[2][1] += a2*b4.y; acc[2][2] += a2*b4.z; acc[2][3] += a2*b4.w;
            acc[3][0] += a3*b4.x; acc[3][1] += a3*b4.y; acc[3][2] += a3*b4.z; acc[3][3] += a3*b4.w;
        }
        __syncthreads();
    }
    float* Cb = outb + (size_t)(b*A_ + bm) * D_ + h*HD_;
    #pragma unroll
    for (int r = 0; r < 4; ++r) {
        float4 o;
        o.x = acc[r][0]; o.y = acc[r][1]; o.z = acc[r][2]; o.w = acc[r][3];
        *reinterpret_cast<float4*>(&Cb[(size_t)(tm*4 + r)*D_ + tn*4]) = o;
    }
}

// ---------------------------------------------------------------------------
// Fused residual + LayerNorm (512). Optional bf16 copy of the output.
// ---------------------------------------------------------------------------
template<int BF16OUT>
__global__ __launch_bounds__(256) void ln_kernel(const float* __restrict__ a,
                                                 const float* __restrict__ r,
                                                 const float* __restrict__ g,
                                                 const float* __restrict__ bb,
                                                 float* __restrict__ out,
                                                 ushort* __restrict__ outb) {
    const int row = blockIdx.x;
    const int tid = threadIdx.x;
    const size_t base = (size_t)row * D_ + tid * 2;
    const float2 a2 = *reinterpret_cast<const float2*>(&a[base]);
    const float2 r2 = *reinterpret_cast<const float2*>(&r[base]);
    const float e0 = a2.x + r2.x, e1 = a2.y + r2.y;
    float s = e0 + e1;
    float q = e0*e0 + e1*e1;
    #pragma unroll
    for (int o = 32; o > 0; o >>= 1) { s += __shfl_down(s, o); q += __shfl_down(q, o); }
    __shared__ float rs[4], rq[4];
    if ((tid & 63) == 0) { rs[tid >> 6] = s; rq[tid >> 6] = q; }
    __syncthreads();
    const float S = rs[0]+rs[1]+rs[2]+rs[3];
    const float Q = rq[0]+rq[1]+rq[2]+rq[3];
    const float mean = S * (1.0f/512.0f);
    const float var  = Q * (1.0f/512.0f) - mean*mean;
    const float rstd = rsqrtf(var + 1e-5f);
    const int c = tid*2;
    float2 ov;
    ov.x = (e0 - mean)*rstd*g[c]   + bb[c];
    ov.y = (e1 - mean)*rstd*g[c+1] + bb[c+1];
    *reinterpret_cast<float2*>(&out[base]) = ov;
    if (BF16OUT) {
        const unsigned pk = f2bf(ov.x) | ((unsigned)f2bf(ov.y) << 16);
        *(unsigned*)&outb[base] = pk;
    }
}

// ---------------------------------------------------------------------------
extern "C" void kernel_launch(void* const* d_in, const int* in_sizes, int n_in,
                              void* d_out, int out_size, void* d_ws, size_t ws_size,
                              hipStream_t stream) {
    const float* x        = (const float*)d_in[0];
    const void*  mask     = d_in[1];
    const float* relation = (const float*)d_in[2];
    const float* qkv_w    = (const float*)d_in[3];
    const float* qkv_b    = (const float*)d_in[4];
    const float* rel_w1   = (const float*)d_in[5];
    const float* rel_b1   = (const float*)d_in[6];
    const float* rel_w2   = (const float*)d_in[7];
    const float* ff_w1    = (const float*)d_in[8];
    const float* ff_b1    = (const float*)d_in[9];
    const float* ff_w2    = (const float*)d_in[10];
    const float* ff_b2    = (const float*)d_in[11];
    const float* ln1_g    = (const float*)d_in[12];
    const float* ln1_b    = (const float*)d_in[13];
    const float* ln2_g    = (const float*)d_in[14];
    const float* ln2_b    = (const float*)d_in[15];
    float* out = (float*)d_out;

    float* ws     = (float*)d_ws;
    float*  qkv   = ws;                           // 1,572,864 f
    float*  relb  = qkv   + 1572864;              // 4,194,304 f  (relb -> S -> P)
    float*  maskf = relb  + 4194304;              // 1,024 f
    float*  attnb = maskf + 1024;                 // 524,288 f
    float*  x1    = attnb + 524288;               // 524,288 f
    ushort* wtb   = (ushort*)(x1 + 524288);       // 786,432 ush (reused 3x)
    ushort* xb    = wtb + 786432;                 // 524,288 ush (reused as x1b)
    ushort* ffhb  = xb  + 524288;                 // 1,572,864 ush
    float*  ff2o  = qkv;                          // reuse: qkv dead after attention
    ushort* x1b   = xb;                           // reuse: xb dead after qkv gemm

    mask_kernel<<<1, 1024, 0, stream>>>(mask, maskf);
    cvt_kernel<<<256, 256, 0, stream>>>(x, xb);                         // x -> bf16
    wt_kernel<<<dim3(24, 8), 256, 0, stream>>>(qkv_w, wtb, 512, 1536);  // qkv_w^T bf16
    mgemm_kernel<0,0><<<dim3(24, 16), 256, 0, stream>>>(xb, wtb, qkv_b, qkv, 1024, 1536, 512);
    relmlp_kernel<<<8192, 256, 0, stream>>>(relation, rel_w1, rel_b1, rel_w2, relb);
    sgemm_kernel<<<dim3(8, 8, 16), 256, 0, stream>>>(qkv, maskf, relb);
    softmax_kernel<<<16*512, 256, 0, stream>>>(relb);
    pv_kernel<<<dim3(8, 16), 256, 0, stream>>>(relb, qkv, attnb);
    ln_kernel<1><<<1024, 256, 0, stream>>>(attnb, x, ln1_g, ln1_b, x1, x1b);
    wt_kernel<<<dim3(24, 8), 256, 0, stream>>>(ff_w1, wtb, 512, 1536);  // ff_w1^T bf16
    mgemm_kernel<1,1><<<dim3(24, 16), 256, 0, stream>>>(x1b, wtb, ff_b1, ffhb, 1024, 1536, 512);
    wt_kernel<<<dim3(8, 24), 256, 0, stream>>>(ff_w2, wtb, 1536, 512);  // ff_w2^T bf16
    mgemm_kernel<0,0><<<dim3(8, 16), 256, 0, stream>>>(ffhb, wtb, ff_b2, ff2o, 1024, 512, 1536);
    ln_kernel<0><<<1024, 256, 0, stream>>>(ff2o, x1, ln2_g, ln2_b, out, nullptr);
}

// Round 4
// 187.535 us; speedup vs baseline: 2.8566x; 1.1144x over previous
//
#include <hip/hip_runtime.h>
#include <hip/hip_bf16.h>

#define A_  512
#define D_  512
#define H_  8
#define HD_ 64
#define TD_ 1536   // 3*D
#define RH_ 512    // REL_HID

typedef __attribute__((ext_vector_type(8))) short short8v;
typedef __attribute__((ext_vector_type(4))) float f32x4;

__device__ __forceinline__ unsigned short f2bf(float f) {
    unsigned int u = __float_as_uint(f);
    u += 0x7FFFu + ((u >> 16) & 1u);
    return (unsigned short)(u >> 16);
}
__device__ __forceinline__ unsigned pk2r(float a, float b) {   // relu + pack 2 bf16
    return (unsigned)f2bf(fmaxf(a, 0.f)) | ((unsigned)f2bf(fmaxf(b, 0.f)) << 16);
}

// ---------------------------------------------------------------------------
// mask -> float bias (-1e9 / 0), with on-device bool/int32 layout detection.
// ---------------------------------------------------------------------------
__global__ __launch_bounds__(1024) void mask_kernel(const void* __restrict__ mraw,
                                                    float* __restrict__ maskf) {
    __shared__ int anyOdd;
    const int tid = threadIdx.x;          // 0..1023 == B*A
    if (tid == 0) anyOdd = 0;
    __syncthreads();
    const unsigned char* mb = (const unsigned char*)mraw;
    unsigned char v = mb[tid];
    if ((tid & 3) != 0 && v != 0) atomicOr(&anyOdd, 1);
    __syncthreads();
    const bool isByte = (anyOdd != 0);
    int set = isByte ? (mb[tid] != 0) : (((const int*)mraw)[tid] != 0);
    maskf[tid] = set ? -1e9f : 0.0f;
}

// ---------------------------------------------------------------------------
// Elementwise fp32 -> bf16 (8 elems/thread).
// ---------------------------------------------------------------------------
__global__ __launch_bounds__(256) void cvt_kernel(const float* __restrict__ in,
                                                  ushort* __restrict__ out) {
    const int i = (blockIdx.x * 256 + threadIdx.x) * 8;
    const float4 a = *(const float4*)&in[i];
    const float4 b = *(const float4*)&in[i + 4];
    uint4 o;
    o.x = f2bf(a.x) | ((unsigned)f2bf(a.y) << 16);
    o.y = f2bf(a.z) | ((unsigned)f2bf(a.w) << 16);
    o.z = f2bf(b.x) | ((unsigned)f2bf(b.y) << 16);
    o.w = f2bf(b.z) | ((unsigned)f2bf(b.w) << 16);
    *(uint4*)&out[i] = o;
}

// ---------------------------------------------------------------------------
// Transpose + cvt: in fp32 [R][C] -> out bf16 [C][R]. 64x64 tiles.
// ---------------------------------------------------------------------------
__global__ __launch_bounds__(256) void wt_kernel(const float* __restrict__ in,
                                                 ushort* __restrict__ out,
                                                 int R, int C) {
    __shared__ float ts[64][65];
    const int tid = threadIdx.x;
    const int r0 = blockIdx.y * 64, c0 = blockIdx.x * 64;
    const int r = tid >> 2, cb = (tid & 3) * 16;
    #pragma unroll
    for (int u = 0; u < 4; ++u) {
        const float4 v = *(const float4*)&in[(size_t)(r0 + r) * C + c0 + cb + u*4];
        ts[r][cb + u*4 + 0] = v.x;
        ts[r][cb + u*4 + 1] = v.y;
        ts[r][cb + u*4 + 2] = v.z;
        ts[r][cb + u*4 + 3] = v.w;
    }
    __syncthreads();
    const int oc = tid & 63;
    const int rb = (tid >> 6) * 16;
    unsigned pk[8];
    #pragma unroll
    for (int i = 0; i < 8; ++i) {
        const unsigned lo = f2bf(ts[rb + i*2][oc]);
        const unsigned hi = f2bf(ts[rb + i*2 + 1][oc]);
        pk[i] = lo | (hi << 16);
    }
    uint4* dst = (uint4*)&out[(size_t)(c0 + oc) * R + r0 + rb];
    dst[0] = make_uint4(pk[0], pk[1], pk[2], pk[3]);
    dst[1] = make_uint4(pk[4], pk[5], pk[6], pk[7]);
}

// ---------------------------------------------------------------------------
// bf16 MFMA GEMM: C[M,N] = op(A[M,K] @ B[K,N] + bias).
// A is [M][K] bf16, BT is [N][K] bf16 (both K-major). 64x64 tile, BK=64,
// 4 waves (2x2), each wave 32x32 via 16x16x32 MFMA. LDS slot-XOR swizzle.
// ---------------------------------------------------------------------------
template<int RELU, int OBF16>
__global__ __launch_bounds__(256) void mgemm_kernel(const ushort* __restrict__ A,
                                                    const ushort* __restrict__ BT,
                                                    const float* __restrict__ bias,
                                                    void* __restrict__ Cv,
                                                    int M, int N, int K) {
    __shared__ __align__(16) ushort As[64 * 64];
    __shared__ __align__(16) ushort Bs[64 * 64];
    const int tid = threadIdx.x;
    const int bm = blockIdx.y * 64, bn = blockIdx.x * 64;
    const int lane = tid & 63, wave = tid >> 6;
    const int wm = (wave >> 1) * 32, wn = (wave & 1) * 32;
    f32x4 acc[2][2];
    #pragma unroll
    for (int i = 0; i < 2; ++i)
        #pragma unroll
        for (int j = 0; j < 2; ++j) acc[i][j] = (f32x4){0.f, 0.f, 0.f, 0.f};

    const int s0  = tid * 2;
    const int rs  = s0 >> 3;
    const int sl0 = s0 & 7;
    for (int k0 = 0; k0 < K; k0 += 64) {
        #pragma unroll
        for (int u = 0; u < 2; ++u) {
            const int sl = sl0 + u;
            const uint4 va = *(const uint4*)&A[(size_t)(bm + rs) * K + k0 + sl*8];
            *(uint4*)((char*)As + rs*128 + ((sl ^ (rs & 7)) << 4)) = va;
            const uint4 vb = *(const uint4*)&BT[(size_t)(bn + rs) * K + k0 + sl*8];
            *(uint4*)((char*)Bs + rs*128 + ((sl ^ (rs & 7)) << 4)) = vb;
        }
        __syncthreads();
        #pragma unroll
        for (int kk = 0; kk < 2; ++kk) {
            short8v af[2], bfv[2];
            #pragma unroll
            for (int mf = 0; mf < 2; ++mf) {
                const int row = wm + mf*16 + (lane & 15);
                const int slot = (kk*4 + (lane >> 4)) ^ (row & 7);
                af[mf] = *(const short8v*)((const char*)As + row*128 + (slot << 4));
            }
            #pragma unroll
            for (int nf = 0; nf < 2; ++nf) {
                const int row = wn + nf*16 + (lane & 15);
                const int slot = (kk*4 + (lane >> 4)) ^ (row & 7);
                bfv[nf] = *(const short8v*)((const char*)Bs + row*128 + (slot << 4));
            }
            #pragma unroll
            for (int mf = 0; mf < 2; ++mf)
                #pragma unroll
                for (int nf = 0; nf < 2; ++nf)
                    acc[mf][nf] = __builtin_amdgcn_mfma_f32_16x16x32_bf16(af[mf], bfv[nf], acc[mf][nf], 0, 0, 0);
        }
        __syncthreads();
    }
    #pragma unroll
    for (int nf = 0; nf < 2; ++nf) {
        const int col = bn + wn + nf*16 + (lane & 15);
        const float bv = bias[col];
        #pragma unroll
        for (int mf = 0; mf < 2; ++mf) {
            #pragma unroll
            for (int r = 0; r < 4; ++r) {
                const int row = bm + wm + mf*16 + (lane >> 4)*4 + r;
                float v = acc[mf][nf][r] + bv;
                if (RELU) v = fmaxf(v, 0.f);
                if (OBF16) ((ushort*)Cv)[(size_t)row * N + col] = f2bf(v);
                else       ((float*)Cv)[(size_t)row * N + col] = v;
            }
        }
    }
}

// ---------------------------------------------------------------------------
// Fused relation MLP, both layers on MFMA (16x16x32 bf16).
// Layer1: hidden^T[n][pair] = w1^T @ rel^T, bias folded as K-element 4
//         (rel-frag k=4 holds 1.0, w1t[n][4] = b1[n]); K padded to 32 w/ zeros.
// hidden -> relu -> bf16 -> swizzled per-wave LDS hid[32 pair][128 n] chunks.
// Layer2: out^T[h][pair] = w2^T @ hidden^T accumulated over 16 K-chunks.
// 32 pairs/wave, 128 pairs/block, no __syncthreads in main loop.
// ---------------------------------------------------------------------------
__global__ __launch_bounds__(256) void relmlp_kernel(const float* __restrict__ rel,
                                                     const float* __restrict__ w1,
                                                     const float* __restrict__ b1,
                                                     const float* __restrict__ w2,
                                                     float* __restrict__ relb) {
    __shared__ __align__(16) ushort w1t[512 * 8];   // [n][8k]: w1[0..3][n], b1[n], 0,0,0
    __shared__ __align__(16) ushort w2t[8 * 512];   // [h][512 n], slot-XOR swizzled
    __shared__ __align__(16) ushort hid[4 * 4096];  // per wave [32 pair][128 n], swizzled
    const int tid = threadIdx.x;
    #pragma unroll
    for (int u = 0; u < 2; ++u) {
        const int n = tid + u*256;
        uint4 o;
        o.x = (unsigned)f2bf(w1[n])        | ((unsigned)f2bf(w1[512 + n])  << 16);
        o.y = (unsigned)f2bf(w1[1024 + n]) | ((unsigned)f2bf(w1[1536 + n]) << 16);
        o.z = (unsigned)f2bf(b1[n]);        // k=4 -> b1, k=5 -> 0
        o.w = 0;                            // k=6,7 -> 0
        *(uint4*)&w1t[n * 8] = o;
        const float4 wlo = *(const float4*)&w2[n*8];
        const float4 whi = *(const float4*)&w2[n*8 + 4];
        const float wvv[8] = {wlo.x, wlo.y, wlo.z, wlo.w, whi.x, whi.y, whi.z, whi.w};
        #pragma unroll
        for (int h = 0; h < 8; ++h) {
            *(ushort*)((char*)w2t + h*1024 + (((n >> 3) ^ h) << 4) + (n & 7)*2) = f2bf(wvv[h]);
        }
    }
    __syncthreads();

    const int lane = tid & 63, wvid = tid >> 6;
    const int g = lane >> 4, lr = lane & 15;
    char* hw = (char*)hid + wvid * 8192;
    const int pbase = blockIdx.x * 128 + wvid * 32;
    const int SW0 = lr;        // swizzle key for pair-tile 0 (pairs lr)
    const int SW1 = lr ^ 8;    // pair-tile 1 (pairs 16+lr)

    short8v rf0 = {0,0,0,0,0,0,0,0}, rf1 = {0,0,0,0,0,0,0,0};
    if (g == 0) {
        const float4 ra = *(const float4*)&rel[(size_t)(pbase + lr) * 4];
        const float4 rb = *(const float4*)&rel[(size_t)(pbase + 16 + lr) * 4];
        rf0[0] = (short)f2bf(ra.x); rf0[1] = (short)f2bf(ra.y);
        rf0[2] = (short)f2bf(ra.z); rf0[3] = (short)f2bf(ra.w);
        rf0[4] = (short)0x3F80;     // 1.0 -> multiplies b1 row
        rf1[0] = (short)f2bf(rb.x); rf1[1] = (short)f2bf(rb.y);
        rf1[2] = (short)f2bf(rb.z); rf1[3] = (short)f2bf(rb.w);
        rf1[4] = (short)0x3F80;
    }
    const f32x4 z4 = {0.f, 0.f, 0.f, 0.f};
    f32x4 acc0 = z4, acc1 = z4;

    for (int ch = 0; ch < 4; ++ch) {
        // ---- layer 1: 8 n-tiles of 16 (chunk = 128 n) ----
        #pragma unroll
        for (int t = 0; t < 8; ++t) {
            short8v af = {0,0,0,0,0,0,0,0};
            if (g == 0) af = *(const short8v*)&w1t[(ch*128 + t*16 + lr) * 8];
            const f32x4 c0 = __builtin_amdgcn_mfma_f32_16x16x32_bf16(af, rf0, z4, 0, 0, 0);
            const f32x4 c1 = __builtin_amdgcn_mfma_f32_16x16x32_bf16(af, rf1, z4, 0, 0, 0);
            // C: col = pair (lr), row = n = t*16 + g*4 + r  -> store to hid
            const int slot = t*2 + (g >> 1);
            const int off  = (g & 1) * 8;
            uint2 s0, s1;
            s0.x = pk2r(c0[0], c0[1]); s0.y = pk2r(c0[2], c0[3]);
            s1.x = pk2r(c1[0], c1[1]); s1.y = pk2r(c1[2], c1[3]);
            *(uint2*)(hw + lr*256        + ((slot ^ SW0) << 4) + off) = s0;
            *(uint2*)(hw + (16 + lr)*256 + ((slot ^ SW1) << 4) + off) = s1;
        }
        // ---- layer 2: 4 K-chunks of 32 ----
        #pragma unroll
        for (int kc = 0; kc < 4; ++kc) {
            const int slot = kc*4 + g;
            short8v a2 = {0,0,0,0,0,0,0,0};
            if (lr < 8) a2 = *(const short8v*)((const char*)w2t + lr*1024 + (((ch*16 + slot) ^ lr) << 4));
            const short8v bf0 = *(const short8v*)(hw + lr*256        + ((slot ^ SW0) << 4));
            const short8v bf1 = *(const short8v*)(hw + (16 + lr)*256 + ((slot ^ SW1) << 4));
            acc0 = __builtin_amdgcn_mfma_f32_16x16x32_bf16(a2, bf0, acc0, 0, 0, 0);
            acc1 = __builtin_amdgcn_mfma_f32_16x16x32_bf16(a2, bf1, acc1, 0, 0, 0);
        }
    }
    // ---- epilogue: C col = pair, row = h = g*4 + r (g<2 real) ----
    if (g < 2) {
        #pragma unroll
        for (int pt = 0; pt < 2; ++pt) {
            const f32x4 ac = pt ? acc1 : acc0;
            const int pair = pbase + pt*16 + lr;
            const int bb_  = pair >> 18;
            const int ij   = pair & 262143;
            float* dst = relb + (((size_t)(bb_ * 8)) << 18) + ij;
            #pragma unroll
            for (int r = 0; r < 4; ++r) {
                const int h = g*4 + r;
                dst[(size_t)h << 18] = 16.0f / (1.0f + __expf(-ac[r]));
            }
        }
    }
}

// ---------------------------------------------------------------------------
// S = (Q*0.125) @ K^T + relb + maskbias   (in-place over relb) — fp32
// ---------------------------------------------------------------------------
__global__ __launch_bounds__(256) void sgemm_kernel(const float* __restrict__ qkv,
                                                    const float* __restrict__ maskf,
                                                    float* __restrict__ S) {
    const int bh = blockIdx.z;
    const int b = bh >> 3, h = bh & 7;
    const int bm = blockIdx.y * 64, bn = blockIdx.x * 64;
    const float* Qb = qkv + (size_t)b*A_*TD_ + h*HD_;
    const float* Kb = qkv + (size_t)b*A_*TD_ + D_ + h*HD_;
    __shared__ __align__(16) float Qs[64][17];
    __shared__ __align__(16) float Ks[64][68];
    const int tid = threadIdx.x;
    {
        const int r  = tid >> 2;
        const int c4 = (tid & 3) * 16;
        #pragma unroll
        for (int u = 0; u < 4; ++u) {
            float4 qv = *reinterpret_cast<const float4*>(&Qb[(size_t)(bm + r)*TD_ + c4 + u*4]);
            Qs[r][c4+u*4+0] = qv.x * 0.125f;
            Qs[r][c4+u*4+1] = qv.y * 0.125f;
            Qs[r][c4+u*4+2] = qv.z * 0.125f;
            Qs[r][c4+u*4+3] = qv.w * 0.125f;
            float4 kv = *reinterpret_cast<const float4*>(&Kb[(size_t)(bn + r)*TD_ + c4 + u*4]);
            Ks[c4+u*4+0][r] = kv.x;
            Ks[c4+u*4+1][r] = kv.y;
            Ks[c4+u*4+2][r] = kv.z;
            Ks[c4+u*4+3][r] = kv.w;
        }
    }
    __syncthreads();
    const int tn = tid & 15, tm = tid >> 4;
    float acc[4][4] = {};
    #pragma unroll 16
    for (int kk = 0; kk < 64; ++kk) {
        const float a0 = Qs[tm*4+0][kk];
        const float a1 = Qs[tm*4+1][kk];
        const float a2 = Qs[tm*4+2][kk];
        const float a3 = Qs[tm*4+3][kk];
        const float4 b4 = *reinterpret_cast<const float4*>(&Ks[kk][tn*4]);
        acc[0][0] += a0*b4.x; acc[0][1] += a0*b4.y; acc[0][2] += a0*b4.z; acc[0][3] += a0*b4.w;
        acc[1][0] += a1*b4.x; acc[1][1] += a1*b4.y; acc[1][2] += a1*b4.z; acc[1][3] += a1*b4.w;
        acc[2][0] += a2*b4.x; acc[2][1] += a2*b4.y; acc[2][2] += a2*b4.z; acc[2][3] += a2*b4.w;
        acc[3][0] += a3*b4.x; acc[3][1] += a3*b4.y; acc[3][2] += a3*b4.z; acc[3][3] += a3*b4.w;
    }
    float* Sb = S + (size_t)bh * A_ * A_;
    const int c0 = bn + tn*4;
    const float4 m4 = *reinterpret_cast<const float4*>(&maskf[b*A_ + c0]);
    #pragma unroll
    for (int r = 0; r < 4; ++r) {
        const int row = bm + tm*4 + r;
        float4 rb = *reinterpret_cast<const float4*>(&Sb[(size_t)row*A_ + c0]);
        float4 o;
        o.x = acc[r][0] + rb.x + m4.x;
        o.y = acc[r][1] + rb.y + m4.y;
        o.z = acc[r][2] + rb.z + m4.z;
        o.w = acc[r][3] + rb.w + m4.w;
        *reinterpret_cast<float4*>(&Sb[(size_t)row*A_ + c0]) = o;
    }
}

// ---------------------------------------------------------------------------
// Row softmax in-place (8192 rows x 512).
// ---------------------------------------------------------------------------
__global__ __launch_bounds__(256) void softmax_kernel(float* __restrict__ P) {
    const size_t base = (size_t)blockIdx.x * A_;
    const int tid = threadIdx.x;
    float2 v = *reinterpret_cast<const float2*>(&P[base + tid*2]);
    float m = fmaxf(v.x, v.y);
    #pragma unroll
    for (int o = 32; o > 0; o >>= 1) m = fmaxf(m, __shfl_xor(m, o));
    __shared__ float rm[4], rs[4];
    if ((tid & 63) == 0) rm[tid >> 6] = m;
    __syncthreads();
    const float M = fmaxf(fmaxf(rm[0], rm[1]), fmaxf(rm[2], rm[3]));
    const float e0 = __expf(v.x - M), e1 = __expf(v.y - M);
    float s = e0 + e1;
    #pragma unroll
    for (int o = 32; o > 0; o >>= 1) s += __shfl_xor(s, o);
    if ((tid & 63) == 0) rs[tid >> 6] = s;
    __syncthreads();
    const float inv = 1.0f / (rs[0] + rs[1] + rs[2] + rs[3]);
    float2 ov;
    ov.x = e0 * inv;
    ov.y = e1 * inv;
    *reinterpret_cast<float2*>(&P[base + tid*2]) = ov;
}

// ---------------------------------------------------------------------------
// O = P @ V per (b,h) — fp32.
// ---------------------------------------------------------------------------
__global__ __launch_bounds__(256) void pv_kernel(const float* __restrict__ P,
                                                 const float* __restrict__ qkv,
                                                 float* __restrict__ outb) {
    const int bh = blockIdx.y;
    const int b = bh >> 3, h = bh & 7;
    const int bm = blockIdx.x * 64;
    const float* Pb = P + (size_t)bh * A_ * A_;
    const float* Vb = qkv + (size_t)b*A_*TD_ + 2*D_ + h*HD_;
    __shared__ __align__(16) float As2[64][17];
    __shared__ __align__(16) float Bs2[16][68];
    const int tid = threadIdx.x;
    const int tn = tid & 15, tm = tid >> 4;
    const int ar = tid >> 2, ac = (tid & 3) << 2;
    const int br = tid >> 4, bc = (tid & 15) << 2;
    float acc[4][4] = {};
    for (int k0 = 0; k0 < A_; k0 += 16) {
        float4 av = *reinterpret_cast<const float4*>(&Pb[(size_t)(bm + ar)*A_ + k0 + ac]);
        float4 bv = *reinterpret_cast<const float4*>(&Vb[(size_t)(k0 + br)*TD_ + bc]);
        As2[ar][ac]   = av.x; As2[ar][ac+1] = av.y; As2[ar][ac+2] = av.z; As2[ar][ac+3] = av.w;
        Bs2[br][bc]   = bv.x; Bs2[br][bc+1] = bv.y; Bs2[br][bc+2] = bv.z; Bs2[br][bc+3] = bv.w;
        __syncthreads();
        #pragma unroll
        for (int kk = 0; kk < 16; ++kk) {
            const float a0 = As2[tm*4+0][kk];
            const float a1 = As2[tm*4+1][kk];
            const float a2 = As2[tm*4+2][kk];
            const float a3 = As2[tm*4+3][kk];
            const float4 b4 = *reinterpret_cast<const float4*>(&Bs2[kk][tn*4]);
            acc[0][0] += a0*b4.x; acc[0][1] += a0*b4.y; acc[0][2] += a0*b4.z; acc[0][3] += a0*b4.w;
            acc[1][0] += a1*b4.x; acc[1][1] += a1*b4.y; acc[1][2] += a1*b4.z; acc[1][3] += a1*b4.w;
            acc[2][0] += a2*b4.x; acc[2][1] += a2*b4.y; acc[2][2] += a2*b4.z; acc[2][3] += a2*b4.w;
            acc[3][0] += a3*b4.x; acc[3][1] += a3*b4.y; acc[3][2] += a3*b4.z; acc[3][3] += a3*b4.w;
        }
        __syncthreads();
    }
    float* Cb = outb + (size_t)(b*A_ + bm) * D_ + h*HD_;
    #pragma unroll
    for (int r = 0; r < 4; ++r) {
        float4 o;
        o.x = acc[r][0]; o.y = acc[r][1]; o.z = acc[r][2]; o.w = acc[r][3];
        *reinterpret_cast<float4*>(&Cb[(size_t)(tm*4 + r)*D_ + tn*4]) = o;
    }
}

// ---------------------------------------------------------------------------
// Fused residual + LayerNorm (512). Optional bf16 copy of the output.
// ---------------------------------------------------------------------------
template<int BF16OUT>
__global__ __launch_bounds__(256) void ln_kernel(const float* __restrict__ a,
                                                 const float* __restrict__ r,
                                                 const float* __restrict__ g,
                                                 const float* __restrict__ bb,
                                                 float* __restrict__ out,
                                                 ushort* __restrict__ outb) {
    const int row = blockIdx.x;
    const int tid = threadIdx.x;
    const size_t base = (size_t)row * D_ + tid * 2;
    const float2 a2 = *reinterpret_cast<const float2*>(&a[base]);
    const float2 r2 = *reinterpret_cast<const float2*>(&r[base]);
    const float e0 = a2.x + r2.x, e1 = a2.y + r2.y;
    float s = e0 + e1;
    float q = e0*e0 + e1*e1;
    #pragma unroll
    for (int o = 32; o > 0; o >>= 1) { s += __shfl_down(s, o); q += __shfl_down(q, o); }
    __shared__ float rs[4], rq[4];
    if ((tid & 63) == 0) { rs[tid >> 6] = s; rq[tid >> 6] = q; }
    __syncthreads();
    const float S = rs[0]+rs[1]+rs[2]+rs[3];
    const float Q = rq[0]+rq[1]+rq[2]+rq[3];
    const float mean = S * (1.0f/512.0f);
    const float var  = Q * (1.0f/512.0f) - mean*mean;
    const float rstd = rsqrtf(var + 1e-5f);
    const int c = tid*2;
    float2 ov;
    ov.x = (e0 - mean)*rstd*g[c]   + bb[c];
    ov.y = (e1 - mean)*rstd*g[c+1] + bb[c+1];
    *reinterpret_cast<float2*>(&out[base]) = ov;
    if (BF16OUT) {
        const unsigned pk = f2bf(ov.x) | ((unsigned)f2bf(ov.y) << 16);
        *(unsigned*)&outb[base] = pk;
    }
}

// ---------------------------------------------------------------------------
extern "C" void kernel_launch(void* const* d_in, const int* in_sizes, int n_in,
                              void* d_out, int out_size, void* d_ws, size_t ws_size,
                              hipStream_t stream) {
    const float* x        = (const float*)d_in[0];
    const void*  mask     = d_in[1];
    const float* relation = (const float*)d_in[2];
    const float* qkv_w    = (const float*)d_in[3];
    const float* qkv_b    = (const float*)d_in[4];
    const float* rel_w1   = (const float*)d_in[5];
    const float* rel_b1   = (const float*)d_in[6];
    const float* rel_w2   = (const float*)d_in[7];
    const float* ff_w1    = (const float*)d_in[8];
    const float* ff_b1    = (const float*)d_in[9];
    const float* ff_w2    = (const float*)d_in[10];
    const float* ff_b2    = (const float*)d_in[11];
    const float* ln1_g    = (const float*)d_in[12];
    const float* ln1_b    = (const float*)d_in[13];
    const float* ln2_g    = (const float*)d_in[14];
    const float* ln2_b    = (const float*)d_in[15];
    float* out = (float*)d_out;

    float* ws     = (float*)d_ws;
    float*  qkv   = ws;                           // 1,572,864 f
    float*  relb  = qkv   + 1572864;              // 4,194,304 f  (relb -> S -> P)
    float*  maskf = relb  + 4194304;              // 1,024 f
    float*  attnb = maskf + 1024;                 // 524,288 f
    float*  x1    = attnb + 524288;               // 524,288 f
    ushort* wtb   = (ushort*)(x1 + 524288);       // 786,432 ush (reused 3x)
    ushort* xb    = wtb + 786432;                 // 524,288 ush (reused as x1b)
    ushort* ffhb  = xb  + 524288;                 // 1,572,864 ush
    float*  ff2o  = qkv;                          // reuse: qkv dead after attention
    ushort* x1b   = xb;                           // reuse: xb dead after qkv gemm

    mask_kernel<<<1, 1024, 0, stream>>>(mask, maskf);
    cvt_kernel<<<256, 256, 0, stream>>>(x, xb);                         // x -> bf16
    wt_kernel<<<dim3(24, 8), 256, 0, stream>>>(qkv_w, wtb, 512, 1536);  // qkv_w^T bf16
    mgemm_kernel<0,0><<<dim3(24, 16), 256, 0, stream>>>(xb, wtb, qkv_b, qkv, 1024, 1536, 512);
    relmlp_kernel<<<4096, 256, 0, stream>>>(relation, rel_w1, rel_b1, rel_w2, relb);
    sgemm_kernel<<<dim3(8, 8, 16), 256, 0, stream>>>(qkv, maskf, relb);
    softmax_kernel<<<16*512, 256, 0, stream>>>(relb);
    pv_kernel<<<dim3(8, 16), 256, 0, stream>>>(relb, qkv, attnb);
    ln_kernel<1><<<1024, 256, 0, stream>>>(attnb, x, ln1_g, ln1_b, x1, x1b);
    wt_kernel<<<dim3(24, 8), 256, 0, stream>>>(ff_w1, wtb, 512, 1536);  // ff_w1^T bf16
    mgemm_kernel<1,1><<<dim3(24, 16), 256, 0, stream>>>(x1b, wtb, ff_b1, ffhb, 1024, 1536, 512);
    wt_kernel<<<dim3(8, 24), 256, 0, stream>>>(ff_w2, wtb, 1536, 512);  // ff_w2^T bf16
    mgemm_kernel<0,0><<<dim3(8, 16), 256, 0, stream>>>(ffhb, wtb, ff_b2, ff2o, 1024, 512, 1536);
    ln_kernel<0><<<1024, 256, 0, stream>>>(ff2o, x1, ln2_g, ln2_b, out, nullptr);
}

// Round 6
// 170.410 us; speedup vs baseline: 3.1436x; 1.1005x over previous
//
#include <hip/hip_runtime.h>
#include <hip/hip_bf16.h>

#define A_  512
#define D_  512
#define H_  8
#define HD_ 64
#define TD_ 1536   // 3*D
#define RH_ 512    // REL_HID

typedef __attribute__((ext_vector_type(8))) short short8v;
typedef __attribute__((ext_vector_type(4))) float f32x4;

__device__ __forceinline__ unsigned short f2bf(float f) {
    unsigned int u = __float_as_uint(f);
    u += 0x7FFFu + ((u >> 16) & 1u);
    return (unsigned short)(u >> 16);
}
// relu + pack 2 f32 -> 2 bf16 in one v_cvt_pk_bf16_f32 (no builtin on gfx950)
__device__ __forceinline__ unsigned pk2r(float a, float b) {
    unsigned r;
    asm("v_cvt_pk_bf16_f32 %0, %1, %2" : "=v"(r) : "v"(fmaxf(a, 0.f)), "v"(fmaxf(b, 0.f)));
    return r;
}

// ---------------------------------------------------------------------------
// mask -> float bias (-1e9 / 0), with on-device bool/int32 layout detection.
// ---------------------------------------------------------------------------
__global__ __launch_bounds__(1024) void mask_kernel(const void* __restrict__ mraw,
                                                    float* __restrict__ maskf) {
    __shared__ int anyOdd;
    const int tid = threadIdx.x;          // 0..1023 == B*A
    if (tid == 0) anyOdd = 0;
    __syncthreads();
    const unsigned char* mb = (const unsigned char*)mraw;
    unsigned char v = mb[tid];
    if ((tid & 3) != 0 && v != 0) atomicOr(&anyOdd, 1);
    __syncthreads();
    const bool isByte = (anyOdd != 0);
    int set = isByte ? (mb[tid] != 0) : (((const int*)mraw)[tid] != 0);
    maskf[tid] = set ? -1e9f : 0.0f;
}

// ---------------------------------------------------------------------------
// Elementwise fp32 -> bf16 (8 elems/thread).
// ---------------------------------------------------------------------------
__global__ __launch_bounds__(256) void cvt_kernel(const float* __restrict__ in,
                                                  ushort* __restrict__ out) {
    const int i = (blockIdx.x * 256 + threadIdx.x) * 8;
    const float4 a = *(const float4*)&in[i];
    const float4 b = *(const float4*)&in[i + 4];
    uint4 o;
    o.x = f2bf(a.x) | ((unsigned)f2bf(a.y) << 16);
    o.y = f2bf(a.z) | ((unsigned)f2bf(a.w) << 16);
    o.z = f2bf(b.x) | ((unsigned)f2bf(b.y) << 16);
    o.w = f2bf(b.z) | ((unsigned)f2bf(b.w) << 16);
    *(uint4*)&out[i] = o;
}

// ---------------------------------------------------------------------------
// Transpose + cvt: in fp32 [R][C] -> out bf16 [C][R]. 64x64 tiles.
// ---------------------------------------------------------------------------
__global__ __launch_bounds__(256) void wt_kernel(const float* __restrict__ in,
                                                 ushort* __restrict__ out,
                                                 int R, int C) {
    __shared__ float ts[64][65];
    const int tid = threadIdx.x;
    const int r0 = blockIdx.y * 64, c0 = blockIdx.x * 64;
    const int r = tid >> 2, cb = (tid & 3) * 16;
    #pragma unroll
    for (int u = 0; u < 4; ++u) {
        const float4 v = *(const float4*)&in[(size_t)(r0 + r) * C + c0 + cb + u*4];
        ts[r][cb + u*4 + 0] = v.x;
        ts[r][cb + u*4 + 1] = v.y;
        ts[r][cb + u*4 + 2] = v.z;
        ts[r][cb + u*4 + 3] = v.w;
    }
    __syncthreads();
    const int oc = tid & 63;
    const int rb = (tid >> 6) * 16;
    unsigned pk[8];
    #pragma unroll
    for (int i = 0; i < 8; ++i) {
        const unsigned lo = f2bf(ts[rb + i*2][oc]);
        const unsigned hi = f2bf(ts[rb + i*2 + 1][oc]);
        pk[i] = lo | (hi << 16);
    }
    uint4* dst = (uint4*)&out[(size_t)(c0 + oc) * R + r0 + rb];
    dst[0] = make_uint4(pk[0], pk[1], pk[2], pk[3]);
    dst[1] = make_uint4(pk[4], pk[5], pk[6], pk[7]);
}

// ---------------------------------------------------------------------------
// bf16 MFMA GEMM: C[M,N] = op(A[M,K] @ B[K,N] + bias).
// A is [M][K] bf16, BT is [N][K] bf16 (both K-major). 64x64 tile, BK=64,
// 4 waves (2x2), each wave 32x32 via 16x16x32 MFMA. LDS slot-XOR swizzle.
// ---------------------------------------------------------------------------
template<int RELU, int OBF16>
__global__ __launch_bounds__(256) void mgemm_kernel(const ushort* __restrict__ A,
                                                    const ushort* __restrict__ BT,
                                                    const float* __restrict__ bias,
                                                    void* __restrict__ Cv,
                                                    int M, int N, int K) {
    __shared__ __align__(16) ushort As[64 * 64];
    __shared__ __align__(16) ushort Bs[64 * 64];
    const int tid = threadIdx.x;
    const int bm = blockIdx.y * 64, bn = blockIdx.x * 64;
    const int lane = tid & 63, wave = tid >> 6;
    const int wm = (wave >> 1) * 32, wn = (wave & 1) * 32;
    f32x4 acc[2][2];
    #pragma unroll
    for (int i = 0; i < 2; ++i)
        #pragma unroll
        for (int j = 0; j < 2; ++j) acc[i][j] = (f32x4){0.f, 0.f, 0.f, 0.f};

    const int s0  = tid * 2;
    const int rs  = s0 >> 3;
    const int sl0 = s0 & 7;
    for (int k0 = 0; k0 < K; k0 += 64) {
        #pragma unroll
        for (int u = 0; u < 2; ++u) {
            const int sl = sl0 + u;
            const uint4 va = *(const uint4*)&A[(size_t)(bm + rs) * K + k0 + sl*8];
            *(uint4*)((char*)As + rs*128 + ((sl ^ (rs & 7)) << 4)) = va;
            const uint4 vb = *(const uint4*)&BT[(size_t)(bn + rs) * K + k0 + sl*8];
            *(uint4*)((char*)Bs + rs*128 + ((sl ^ (rs & 7)) << 4)) = vb;
        }
        __syncthreads();
        #pragma unroll
        for (int kk = 0; kk < 2; ++kk) {
            short8v af[2], bfv[2];
            #pragma unroll
            for (int mf = 0; mf < 2; ++mf) {
                const int row = wm + mf*16 + (lane & 15);
                const int slot = (kk*4 + (lane >> 4)) ^ (row & 7);
                af[mf] = *(const short8v*)((const char*)As + row*128 + (slot << 4));
            }
            #pragma unroll
            for (int nf = 0; nf < 2; ++nf) {
                const int row = wn + nf*16 + (lane & 15);
                const int slot = (kk*4 + (lane >> 4)) ^ (row & 7);
                bfv[nf] = *(const short8v*)((const char*)Bs + row*128 + (slot << 4));
            }
            #pragma unroll
            for (int mf = 0; mf < 2; ++mf)
                #pragma unroll
                for (int nf = 0; nf < 2; ++nf)
                    acc[mf][nf] = __builtin_amdgcn_mfma_f32_16x16x32_bf16(af[mf], bfv[nf], acc[mf][nf], 0, 0, 0);
        }
        __syncthreads();
    }
    #pragma unroll
    for (int nf = 0; nf < 2; ++nf) {
        const int col = bn + wn + nf*16 + (lane & 15);
        const float bv = bias[col];
        #pragma unroll
        for (int mf = 0; mf < 2; ++mf) {
            #pragma unroll
            for (int r = 0; r < 4; ++r) {
                const int row = bm + wm + mf*16 + (lane >> 4)*4 + r;
                float v = acc[mf][nf][r] + bv;
                if (RELU) v = fmaxf(v, 0.f);
                if (OBF16) ((ushort*)Cv)[(size_t)row * N + col] = f2bf(v);
                else       ((float*)Cv)[(size_t)row * N + col] = v;
            }
        }
    }
}

// ---------------------------------------------------------------------------
// Fused relation MLP, both layers on MFMA (16x16x32 bf16).
// Layer1: hidden^T[n][pair] = w1^T @ rel^T, bias folded at K-elem 4.
// hidden -> relu -> cvt_pk bf16 -> per-wave swizzled LDS hid[32 pair][64 n].
// Layer2: out^T[h][pair] = w2^T @ hidden^T over 16 K-chunks of 32.
// 32 pairs/wave, 128/block; chunk = 64 n -> LDS 32 KB total (5 blocks/CU).
// No __syncthreads in main loop (hid is wave-private).
// ---------------------------------------------------------------------------
__global__ __launch_bounds__(256) void relmlp_kernel(const float* __restrict__ rel,
                                                     const float* __restrict__ w1,
                                                     const float* __restrict__ b1,
                                                     const float* __restrict__ w2,
                                                     float* __restrict__ relb) {
    __shared__ __align__(16) ushort w1t[512 * 8];   // [n][8k]: w1[0..3][n], b1[n], 0,0,0
    __shared__ __align__(16) ushort w2t[8 * 512];   // [h][512 n], slot-XOR swizzled
    __shared__ __align__(16) ushort hid[4 * 2048];  // per wave [32 pair][64 n], swizzled
    const int tid = threadIdx.x;
    #pragma unroll
    for (int u = 0; u < 2; ++u) {
        const int n = tid + u*256;
        uint4 o;
        o.x = (unsigned)f2bf(w1[n])        | ((unsigned)f2bf(w1[512 + n])  << 16);
        o.y = (unsigned)f2bf(w1[1024 + n]) | ((unsigned)f2bf(w1[1536 + n]) << 16);
        o.z = (unsigned)f2bf(b1[n]);        // k=4 -> b1, k=5 -> 0
        o.w = 0;                            // k=6,7 -> 0
        *(uint4*)&w1t[n * 8] = o;
        const float4 wlo = *(const float4*)&w2[n*8];
        const float4 whi = *(const float4*)&w2[n*8 + 4];
        const float wvv[8] = {wlo.x, wlo.y, wlo.z, wlo.w, whi.x, whi.y, whi.z, whi.w};
        #pragma unroll
        for (int h = 0; h < 8; ++h) {
            *(ushort*)((char*)w2t + h*1024 + (((n >> 3) ^ h) << 4) + (n & 7)*2) = f2bf(wvv[h]);
        }
    }
    __syncthreads();

    const int lane = tid & 63, wvid = tid >> 6;
    const int g = lane >> 4, lr = lane & 15;
    char* hw = (char*)hid + wvid * 4096;
    const int pbase = blockIdx.x * 128 + wvid * 32;
    const int SW = lr & 7;               // 3-bit swizzle key (8 slots/row)

    short8v rf0 = {0,0,0,0,0,0,0,0}, rf1 = {0,0,0,0,0,0,0,0};
    if (g == 0) {
        const float4 ra = *(const float4*)&rel[(size_t)(pbase + lr) * 4];
        const float4 rb = *(const float4*)&rel[(size_t)(pbase + 16 + lr) * 4];
        rf0[0] = (short)f2bf(ra.x); rf0[1] = (short)f2bf(ra.y);
        rf0[2] = (short)f2bf(ra.z); rf0[3] = (short)f2bf(ra.w);
        rf0[4] = (short)0x3F80;     // 1.0 -> multiplies b1 row
        rf1[0] = (short)f2bf(rb.x); rf1[1] = (short)f2bf(rb.y);
        rf1[2] = (short)f2bf(rb.z); rf1[3] = (short)f2bf(rb.w);
        rf1[4] = (short)0x3F80;
    }
    const f32x4 z4 = {0.f, 0.f, 0.f, 0.f};
    f32x4 acc0 = z4, acc1 = z4;

    for (int ch = 0; ch < 8; ++ch) {
        // ---- layer 1: 4 n-tiles of 16 (chunk = 64 n) ----
        #pragma unroll
        for (int t = 0; t < 4; ++t) {
            short8v af = {0,0,0,0,0,0,0,0};
            if (g == 0) af = *(const short8v*)&w1t[(ch*64 + t*16 + lr) * 8];
            const f32x4 c0 = __builtin_amdgcn_mfma_f32_16x16x32_bf16(af, rf0, z4, 0, 0, 0);
            const f32x4 c1 = __builtin_amdgcn_mfma_f32_16x16x32_bf16(af, rf1, z4, 0, 0, 0);
            // C: col = pair (lr), row = n = t*16 + g*4 + r  -> store to hid
            const int slot = t*2 + (g >> 1);
            const int off  = (g & 1) * 8;
            uint2 s0, s1;
            s0.x = pk2r(c0[0], c0[1]); s0.y = pk2r(c0[2], c0[3]);
            s1.x = pk2r(c1[0], c1[1]); s1.y = pk2r(c1[2], c1[3]);
            *(uint2*)(hw + lr*128        + ((slot ^ SW) << 4) + off) = s0;
            *(uint2*)(hw + (16 + lr)*128 + ((slot ^ SW) << 4) + off) = s1;
        }
        // ---- layer 2: 2 K-chunks of 32 ----
        #pragma unroll
        for (int kc = 0; kc < 2; ++kc) {
            const int slot = kc*4 + g;
            short8v a2 = {0,0,0,0,0,0,0,0};
            if (lr < 8) a2 = *(const short8v*)((const char*)w2t + lr*1024 + (((ch*8 + slot) ^ lr) << 4));
            const short8v bf0 = *(const short8v*)(hw + lr*128        + ((slot ^ SW) << 4));
            const short8v bf1 = *(const short8v*)(hw + (16 + lr)*128 + ((slot ^ SW) << 4));
            acc0 = __builtin_amdgcn_mfma_f32_16x16x32_bf16(a2, bf0, acc0, 0, 0, 0);
            acc1 = __builtin_amdgcn_mfma_f32_16x16x32_bf16(a2, bf1, acc1, 0, 0, 0);
        }
    }
    // ---- epilogue: C col = pair, row = h = g*4 + r (g<2 real) ----
    if (g < 2) {
        #pragma unroll
        for (int pt = 0; pt < 2; ++pt) {
            const f32x4 ac = pt ? acc1 : acc0;
            const int pair = pbase + pt*16 + lr;
            const int bb_  = pair >> 18;
            const int ij   = pair & 262143;
            float* dst = relb + (((size_t)(bb_ * 8)) << 18) + ij;
            #pragma unroll
            for (int r = 0; r < 4; ++r) {
                const int h = g*4 + r;
                dst[(size_t)h << 18] = 16.0f / (1.0f + __expf(-ac[r]));
            }
        }
    }
}

// ---------------------------------------------------------------------------
// S = (Q*0.125) @ K^T + relb + maskbias   (in-place over relb) — fp32
// ---------------------------------------------------------------------------
__global__ __launch_bounds__(256) void sgemm_kernel(const float* __restrict__ qkv,
                                                    const float* __restrict__ maskf,
                                                    float* __restrict__ S) {
    const int bh = blockIdx.z;
    const int b = bh >> 3, h = bh & 7;
    const int bm = blockIdx.y * 64, bn = blockIdx.x * 64;
    const float* Qb = qkv + (size_t)b*A_*TD_ + h*HD_;
    const float* Kb = qkv + (size_t)b*A_*TD_ + D_ + h*HD_;
    __shared__ __align__(16) float Qs[64][17];
    __shared__ __align__(16) float Ks[64][68];
    const int tid = threadIdx.x;
    {
        const int r  = tid >> 2;
        const int c4 = (tid & 3) * 16;
        #pragma unroll
        for (int u = 0; u < 4; ++u) {
            float4 qv = *reinterpret_cast<const float4*>(&Qb[(size_t)(bm + r)*TD_ + c4 + u*4]);
            Qs[r][c4+u*4+0] = qv.x * 0.125f;
            Qs[r][c4+u*4+1] = qv.y * 0.125f;
            Qs[r][c4+u*4+2] = qv.z * 0.125f;
            Qs[r][c4+u*4+3] = qv.w * 0.125f;
            float4 kv = *reinterpret_cast<const float4*>(&Kb[(size_t)(bn + r)*TD_ + c4 + u*4]);
            Ks[c4+u*4+0][r] = kv.x;
            Ks[c4+u*4+1][r] = kv.y;
            Ks[c4+u*4+2][r] = kv.z;
            Ks[c4+u*4+3][r] = kv.w;
        }
    }
    __syncthreads();
    const int tn = tid & 15, tm = tid >> 4;
    float acc[4][4] = {};
    #pragma unroll 16
    for (int kk = 0; kk < 64; ++kk) {
        const float a0 = Qs[tm*4+0][kk];
        const float a1 = Qs[tm*4+1][kk];
        const float a2 = Qs[tm*4+2][kk];
        const float a3 = Qs[tm*4+3][kk];
        const float4 b4 = *reinterpret_cast<const float4*>(&Ks[kk][tn*4]);
        acc[0][0] += a0*b4.x; acc[0][1] += a0*b4.y; acc[0][2] += a0*b4.z; acc[0][3] += a0*b4.w;
        acc[1][0] += a1*b4.x; acc[1][1] += a1*b4.y; acc[1][2] += a1*b4.z; acc[1][3] += a1*b4.w;
        acc[2][0] += a2*b4.x; acc[2][1] += a2*b4.y; acc[2][2] += a2*b4.z; acc[2][3] += a2*b4.w;
        acc[3][0] += a3*b4.x; acc[3][1] += a3*b4.y; acc[3][2] += a3*b4.z; acc[3][3] += a3*b4.w;
    }
    float* Sb = S + (size_t)bh * A_ * A_;
    const int c0 = bn + tn*4;
    const float4 m4 = *reinterpret_cast<const float4*>(&maskf[b*A_ + c0]);
    #pragma unroll
    for (int r = 0; r < 4; ++r) {
        const int row = bm + tm*4 + r;
        float4 rb = *reinterpret_cast<const float4*>(&Sb[(size_t)row*A_ + c0]);
        float4 o;
        o.x = acc[r][0] + rb.x + m4.x;
        o.y = acc[r][1] + rb.y + m4.y;
        o.z = acc[r][2] + rb.z + m4.z;
        o.w = acc[r][3] + rb.w + m4.w;
        *reinterpret_cast<float4*>(&Sb[(size_t)row*A_ + c0]) = o;
    }
}

// ---------------------------------------------------------------------------
// Row softmax in-place (8192 rows x 512).
// ---------------------------------------------------------------------------
__global__ __launch_bounds__(256) void softmax_kernel(float* __restrict__ P) {
    const size_t base = (size_t)blockIdx.x * A_;
    const int tid = threadIdx.x;
    float2 v = *reinterpret_cast<const float2*>(&P[base + tid*2]);
    float m = fmaxf(v.x, v.y);
    #pragma unroll
    for (int o = 32; o > 0; o >>= 1) m = fmaxf(m, __shfl_xor(m, o));
    __shared__ float rm[4], rs[4];
    if ((tid & 63) == 0) rm[tid >> 6] = m;
    __syncthreads();
    const float M = fmaxf(fmaxf(rm[0], rm[1]), fmaxf(rm[2], rm[3]));
    const float e0 = __expf(v.x - M), e1 = __expf(v.y - M);
    float s = e0 + e1;
    #pragma unroll
    for (int o = 32; o > 0; o >>= 1) s += __shfl_xor(s, o);
    if ((tid & 63) == 0) rs[tid >> 6] = s;
    __syncthreads();
    const float inv = 1.0f / (rs[0] + rs[1] + rs[2] + rs[3]);
    float2 ov;
    ov.x = e0 * inv;
    ov.y = e1 * inv;
    *reinterpret_cast<float2*>(&P[base + tid*2]) = ov;
}

// ---------------------------------------------------------------------------
// O = P @ V per (b,h) — fp32.
// ---------------------------------------------------------------------------
__global__ __launch_bounds__(256) void pv_kernel(const float* __restrict__ P,
                                                 const float* __restrict__ qkv,
                                                 float* __restrict__ outb) {
    const int bh = blockIdx.y;
    const int b = bh >> 3, h = bh & 7;
    const int bm = blockIdx.x * 64;
    const float* Pb = P + (size_t)bh * A_ * A_;
    const float* Vb = qkv + (size_t)b*A_*TD_ + 2*D_ + h*HD_;
    __shared__ __align__(16) float As2[64][17];
    __shared__ __align__(16) float Bs2[16][68];
    const int tid = threadIdx.x;
    const int tn = tid & 15, tm = tid >> 4;
    const int ar = tid >> 2, ac = (tid & 3) << 2;
    const int br = tid >> 4, bc = (tid & 15) << 2;
    float acc[4][4] = {};
    for (int k0 = 0; k0 < A_; k0 += 16) {
        float4 av = *reinterpret_cast<const float4*>(&Pb[(size_t)(bm + ar)*A_ + k0 + ac]);
        float4 bv = *reinterpret_cast<const float4*>(&Vb[(size_t)(k0 + br)*TD_ + bc]);
        As2[ar][ac]   = av.x; As2[ar][ac+1] = av.y; As2[ar][ac+2] = av.z; As2[ar][ac+3] = av.w;
        Bs2[br][bc]   = bv.x; Bs2[br][bc+1] = bv.y; Bs2[br][bc+2] = bv.z; Bs2[br][bc+3] = bv.w;
        __syncthreads();
        #pragma unroll
        for (int kk = 0; kk < 16; ++kk) {
            const float a0 = As2[tm*4+0][kk];
            const float a1 = As2[tm*4+1][kk];
            const float a2 = As2[tm*4+2][kk];
            const float a3 = As2[tm*4+3][kk];
            const float4 b4 = *reinterpret_cast<const float4*>(&Bs2[kk][tn*4]);
            acc[0][0] += a0*b4.x; acc[0][1] += a0*b4.y; acc[0][2] += a0*b4.z; acc[0][3] += a0*b4.w;
            acc[1][0] += a1*b4.x; acc[1][1] += a1*b4.y; acc[1][2] += a1*b4.z; acc[1][3] += a1*b4.w;
            acc[2][0] += a2*b4.x; acc[2][1] += a2*b4.y; acc[2][2] += a2*b4.z; acc[2][3] += a2*b4.w;
            acc[3][0] += a3*b4.x; acc[3][1] += a3*b4.y; acc[3][2] += a3*b4.z; acc[3][3] += a3*b4.w;
        }
        __syncthreads();
    }
    float* Cb = outb + (size_t)(b*A_ + bm) * D_ + h*HD_;
    #pragma unroll
    for (int r = 0; r < 4; ++r) {
        float4 o;
        o.x = acc[r][0]; o.y = acc[r][1]; o.z = acc[r][2]; o.w = acc[r][3];
        *reinterpret_cast<float4*>(&Cb[(size_t)(tm*4 + r)*D_ + tn*4]) = o;
    }
}

// ---------------------------------------------------------------------------
// Fused residual + LayerNorm (512). Optional bf16 copy of the output.
// ---------------------------------------------------------------------------
template<int BF16OUT>
__global__ __launch_bounds__(256) void ln_kernel(const float* __restrict__ a,
                                                 const float* __restrict__ r,
                                                 const float* __restrict__ g,
                                                 const float* __restrict__ bb,
                                                 float* __restrict__ out,
                                                 ushort* __restrict__ outb) {
    const int row = blockIdx.x;
    const int tid = threadIdx.x;
    const size_t base = (size_t)row * D_ + tid * 2;
    const float2 a2 = *reinterpret_cast<const float2*>(&a[base]);
    const float2 r2 = *reinterpret_cast<const float2*>(&r[base]);
    const float e0 = a2.x + r2.x, e1 = a2.y + r2.y;
    float s = e0 + e1;
    float q = e0*e0 + e1*e1;
    #pragma unroll
    for (int o = 32; o > 0; o >>= 1) { s += __shfl_down(s, o); q += __shfl_down(q, o); }
    __shared__ float rs[4], rq[4];
    if ((tid & 63) == 0) { rs[tid >> 6] = s; rq[tid >> 6] = q; }
    __syncthreads();
    const float S = rs[0]+rs[1]+rs[2]+rs[3];
    const float Q = rq[0]+rq[1]+rq[2]+rq[3];
    const float mean = S * (1.0f/512.0f);
    const float var  = Q * (1.0f/512.0f) - mean*mean;
    const float rstd = rsqrtf(var + 1e-5f);
    const int c = tid*2;
    float2 ov;
    ov.x = (e0 - mean)*rstd*g[c]   + bb[c];
    ov.y = (e1 - mean)*rstd*g[c+1] + bb[c+1];
    *reinterpret_cast<float2*>(&out[base]) = ov;
    if (BF16OUT) {
        const unsigned pk = f2bf(ov.x) | ((unsigned)f2bf(ov.y) << 16);
        *(unsigned*)&outb[base] = pk;
    }
}

// ---------------------------------------------------------------------------
extern "C" void kernel_launch(void* const* d_in, const int* in_sizes, int n_in,
                              void* d_out, int out_size, void* d_ws, size_t ws_size,
                              hipStream_t stream) {
    const float* x        = (const float*)d_in[0];
    const void*  mask     = d_in[1];
    const float* relation = (const float*)d_in[2];
    const float* qkv_w    = (const float*)d_in[3];
    const float* qkv_b    = (const float*)d_in[4];
    const float* rel_w1   = (const float*)d_in[5];
    const float* rel_b1   = (const float*)d_in[6];
    const float* rel_w2   = (const float*)d_in[7];
    const float* ff_w1    = (const float*)d_in[8];
    const float* ff_b1    = (const float*)d_in[9];
    const float* ff_w2    = (const float*)d_in[10];
    const float* ff_b2    = (const float*)d_in[11];
    const float* ln1_g    = (const float*)d_in[12];
    const float* ln1_b    = (const float*)d_in[13];
    const float* ln2_g    = (const float*)d_in[14];
    const float* ln2_b    = (const float*)d_in[15];
    float* out = (float*)d_out;

    float* ws     = (float*)d_ws;
    float*  qkv   = ws;                           // 1,572,864 f
    float*  relb  = qkv   + 1572864;              // 4,194,304 f  (relb -> S -> P)
    float*  maskf = relb  + 4194304;              // 1,024 f
    float*  attnb = maskf + 1024;                 // 524,288 f
    float*  x1    = attnb + 524288;               // 524,288 f
    ushort* wtb   = (ushort*)(x1 + 524288);       // 786,432 ush (reused 3x)
    ushort* xb    = wtb + 786432;                 // 524,288 ush (reused as x1b)
    ushort* ffhb  = xb  + 524288;                 // 1,572,864 ush
    float*  ff2o  = qkv;                          // reuse: qkv dead after attention
    ushort* x1b   = xb;                           // reuse: xb dead after qkv gemm

    mask_kernel<<<1, 1024, 0, stream>>>(mask, maskf);
    cvt_kernel<<<256, 256, 0, stream>>>(x, xb);                         // x -> bf16
    wt_kernel<<<dim3(24, 8), 256, 0, stream>>>(qkv_w, wtb, 512, 1536);  // qkv_w^T bf16
    mgemm_kernel<0,0><<<dim3(24, 16), 256, 0, stream>>>(xb, wtb, qkv_b, qkv, 1024, 1536, 512);
    relmlp_kernel<<<4096, 256, 0, stream>>>(relation, rel_w1, rel_b1, rel_w2, relb);
    sgemm_kernel<<<dim3(8, 8, 16), 256, 0, stream>>>(qkv, maskf, relb);
    softmax_kernel<<<16*512, 256, 0, stream>>>(relb);
    pv_kernel<<<dim3(8, 16), 256, 0, stream>>>(relb, qkv, attnb);
    ln_kernel<1><<<1024, 256, 0, stream>>>(attnb, x, ln1_g, ln1_b, x1, x1b);
    wt_kernel<<<dim3(24, 8), 256, 0, stream>>>(ff_w1, wtb, 512, 1536);  // ff_w1^T bf16
    mgemm_kernel<1,1><<<dim3(24, 16), 256, 0, stream>>>(x1b, wtb, ff_b1, ffhb, 1024, 1536, 512);
    wt_kernel<<<dim3(8, 24), 256, 0, stream>>>(ff_w2, wtb, 1536, 512);  // ff_w2^T bf16
    mgemm_kernel<0,0><<<dim3(8, 16), 256, 0, stream>>>(ffhb, wtb, ff_b2, ff2o, 1024, 512, 1536);
    ln_kernel<0><<<1024, 256, 0, stream>>>(ff2o, x1, ln2_g, ln2_b, out, nullptr);
}

// Round 7
// 136.532 us; speedup vs baseline: 3.9237x; 1.2481x over previous
//
#include <hip/hip_runtime.h>
#include <hip/hip_bf16.h>

#define A_  512
#define D_  512
#define H_  8
#define HD_ 64
#define TD_ 1536   // 3*D
#define RH_ 512    // REL_HID

typedef __attribute__((ext_vector_type(8))) short short8v;
typedef __attribute__((ext_vector_type(4))) float f32x4;

__device__ __forceinline__ unsigned short f2bf(float f) {
    unsigned int u = __float_as_uint(f);
    u += 0x7FFFu + ((u >> 16) & 1u);
    return (unsigned short)(u >> 16);
}
// pack 2 f32 -> 2 bf16 in one v_cvt_pk_bf16_f32 (no builtin on gfx950)
__device__ __forceinline__ unsigned pk2(float a, float b) {
    unsigned r;
    asm("v_cvt_pk_bf16_f32 %0, %1, %2" : "=v"(r) : "v"(a), "v"(b));
    return r;
}
// relu + pack
__device__ __forceinline__ unsigned pk2r(float a, float b) {
    return pk2(fmaxf(a, 0.f), fmaxf(b, 0.f));
}

// ---------------------------------------------------------------------------
// mask -> float bias (-1e9 / 0), with on-device bool/int32 layout detection.
// ---------------------------------------------------------------------------
__global__ __launch_bounds__(1024) void mask_kernel(const void* __restrict__ mraw,
                                                    float* __restrict__ maskf) {
    __shared__ int anyOdd;
    const int tid = threadIdx.x;          // 0..1023 == B*A
    if (tid == 0) anyOdd = 0;
    __syncthreads();
    const unsigned char* mb = (const unsigned char*)mraw;
    unsigned char v = mb[tid];
    if ((tid & 3) != 0 && v != 0) atomicOr(&anyOdd, 1);
    __syncthreads();
    const bool isByte = (anyOdd != 0);
    int set = isByte ? (mb[tid] != 0) : (((const int*)mraw)[tid] != 0);
    maskf[tid] = set ? -1e9f : 0.0f;
}

// ---------------------------------------------------------------------------
// Elementwise fp32 -> bf16 (8 elems/thread).
// ---------------------------------------------------------------------------
__global__ __launch_bounds__(256) void cvt_kernel(const float* __restrict__ in,
                                                  ushort* __restrict__ out) {
    const int i = (blockIdx.x * 256 + threadIdx.x) * 8;
    const float4 a = *(const float4*)&in[i];
    const float4 b = *(const float4*)&in[i + 4];
    uint4 o;
    o.x = pk2(a.x, a.y);
    o.y = pk2(a.z, a.w);
    o.z = pk2(b.x, b.y);
    o.w = pk2(b.z, b.w);
    *(uint4*)&out[i] = o;
}

// ---------------------------------------------------------------------------
// Transpose + cvt: in fp32 [R][C] -> out bf16 [C][R]. 64x64 tiles.
// ---------------------------------------------------------------------------
__global__ __launch_bounds__(256) void wt_kernel(const float* __restrict__ in,
                                                 ushort* __restrict__ out,
                                                 int R, int C) {
    __shared__ float ts[64][65];
    const int tid = threadIdx.x;
    const int r0 = blockIdx.y * 64, c0 = blockIdx.x * 64;
    const int r = tid >> 2, cb = (tid & 3) * 16;
    #pragma unroll
    for (int u = 0; u < 4; ++u) {
        const float4 v = *(const float4*)&in[(size_t)(r0 + r) * C + c0 + cb + u*4];
        ts[r][cb + u*4 + 0] = v.x;
        ts[r][cb + u*4 + 1] = v.y;
        ts[r][cb + u*4 + 2] = v.z;
        ts[r][cb + u*4 + 3] = v.w;
    }
    __syncthreads();
    const int oc = tid & 63;
    const int rb = (tid >> 6) * 16;
    unsigned pk[8];
    #pragma unroll
    for (int i = 0; i < 8; ++i) {
        pk[i] = pk2(ts[rb + i*2][oc], ts[rb + i*2 + 1][oc]);
    }
    uint4* dst = (uint4*)&out[(size_t)(c0 + oc) * R + r0 + rb];
    dst[0] = make_uint4(pk[0], pk[1], pk[2], pk[3]);
    dst[1] = make_uint4(pk[4], pk[5], pk[6], pk[7]);
}

// ---------------------------------------------------------------------------
// bf16 MFMA GEMM: C[M,N] = op(A[M,K] @ B[K,N] + bias).
// A is [M][K] bf16, BT is [N][K] bf16 (both K-major). 64x64 tile, BK=64,
// 4 waves (2x2), each wave 32x32 via 16x16x32 MFMA. LDS slot-XOR swizzle.
// ---------------------------------------------------------------------------
template<int RELU, int OBF16>
__global__ __launch_bounds__(256) void mgemm_kernel(const ushort* __restrict__ A,
                                                    const ushort* __restrict__ BT,
                                                    const float* __restrict__ bias,
                                                    void* __restrict__ Cv,
                                                    int M, int N, int K) {
    __shared__ __align__(16) ushort As[64 * 64];
    __shared__ __align__(16) ushort Bs[64 * 64];
    const int tid = threadIdx.x;
    const int bm = blockIdx.y * 64, bn = blockIdx.x * 64;
    const int lane = tid & 63, wave = tid >> 6;
    const int wm = (wave >> 1) * 32, wn = (wave & 1) * 32;
    f32x4 acc[2][2];
    #pragma unroll
    for (int i = 0; i < 2; ++i)
        #pragma unroll
        for (int j = 0; j < 2; ++j) acc[i][j] = (f32x4){0.f, 0.f, 0.f, 0.f};

    const int s0  = tid * 2;
    const int rs  = s0 >> 3;
    const int sl0 = s0 & 7;
    for (int k0 = 0; k0 < K; k0 += 64) {
        #pragma unroll
        for (int u = 0; u < 2; ++u) {
            const int sl = sl0 + u;
            const uint4 va = *(const uint4*)&A[(size_t)(bm + rs) * K + k0 + sl*8];
            *(uint4*)((char*)As + rs*128 + ((sl ^ (rs & 7)) << 4)) = va;
            const uint4 vb = *(const uint4*)&BT[(size_t)(bn + rs) * K + k0 + sl*8];
            *(uint4*)((char*)Bs + rs*128 + ((sl ^ (rs & 7)) << 4)) = vb;
        }
        __syncthreads();
        #pragma unroll
        for (int kk = 0; kk < 2; ++kk) {
            short8v af[2], bfv[2];
            #pragma unroll
            for (int mf = 0; mf < 2; ++mf) {
                const int row = wm + mf*16 + (lane & 15);
                const int slot = (kk*4 + (lane >> 4)) ^ (row & 7);
                af[mf] = *(const short8v*)((const char*)As + row*128 + (slot << 4));
            }
            #pragma unroll
            for (int nf = 0; nf < 2; ++nf) {
                const int row = wn + nf*16 + (lane & 15);
                const int slot = (kk*4 + (lane >> 4)) ^ (row & 7);
                bfv[nf] = *(const short8v*)((const char*)Bs + row*128 + (slot << 4));
            }
            #pragma unroll
            for (int mf = 0; mf < 2; ++mf)
                #pragma unroll
                for (int nf = 0; nf < 2; ++nf)
                    acc[mf][nf] = __builtin_amdgcn_mfma_f32_16x16x32_bf16(af[mf], bfv[nf], acc[mf][nf], 0, 0, 0);
        }
        __syncthreads();
    }
    #pragma unroll
    for (int nf = 0; nf < 2; ++nf) {
        const int col = bn + wn + nf*16 + (lane & 15);
        const float bv = bias[col];
        #pragma unroll
        for (int mf = 0; mf < 2; ++mf) {
            #pragma unroll
            for (int r = 0; r < 4; ++r) {
                const int row = bm + wm + mf*16 + (lane >> 4)*4 + r;
                float v = acc[mf][nf][r] + bv;
                if (RELU) v = fmaxf(v, 0.f);
                if (OBF16) ((ushort*)Cv)[(size_t)row * N + col] = f2bf(v);
                else       ((float*)Cv)[(size_t)row * N + col] = v;
            }
        }
    }
}

// ---------------------------------------------------------------------------
// Fused relation MLP, both layers on MFMA (16x16x32 bf16).
// Grid 1024 blocks; each block loops 4 pair-groups reusing staged weights.
// ---------------------------------------------------------------------------
__global__ __launch_bounds__(256) void relmlp_kernel(const float* __restrict__ rel,
                                                     const float* __restrict__ w1,
                                                     const float* __restrict__ b1,
                                                     const float* __restrict__ w2,
                                                     float* __restrict__ relb) {
    __shared__ __align__(16) ushort w1t[512 * 8];   // [n][8k]: w1[0..3][n], b1[n], 0,0,0
    __shared__ __align__(16) ushort w2t[8 * 512];   // [h][512 n], slot-XOR swizzled
    __shared__ __align__(16) ushort hid[4 * 2048];  // per wave [32 pair][64 n], swizzled
    const int tid = threadIdx.x;
    #pragma unroll
    for (int u = 0; u < 2; ++u) {
        const int n = tid + u*256;
        uint4 o;
        o.x = (unsigned)f2bf(w1[n])        | ((unsigned)f2bf(w1[512 + n])  << 16);
        o.y = (unsigned)f2bf(w1[1024 + n]) | ((unsigned)f2bf(w1[1536 + n]) << 16);
        o.z = (unsigned)f2bf(b1[n]);        // k=4 -> b1, k=5 -> 0
        o.w = 0;                            // k=6,7 -> 0
        *(uint4*)&w1t[n * 8] = o;
        const float4 wlo = *(const float4*)&w2[n*8];
        const float4 whi = *(const float4*)&w2[n*8 + 4];
        const float wvv[8] = {wlo.x, wlo.y, wlo.z, wlo.w, whi.x, whi.y, whi.z, whi.w};
        #pragma unroll
        for (int h = 0; h < 8; ++h) {
            *(ushort*)((char*)w2t + h*1024 + (((n >> 3) ^ h) << 4) + (n & 7)*2) = f2bf(wvv[h]);
        }
    }
    __syncthreads();

    const int lane = tid & 63, wvid = tid >> 6;
    const int g = lane >> 4, lr = lane & 15;
    char* hw = (char*)hid + wvid * 4096;
    const int SW = lr & 7;               // 3-bit swizzle key (8 slots/row)
    const f32x4 z4 = {0.f, 0.f, 0.f, 0.f};

    for (int pg = 0; pg < 4; ++pg) {
        const int pbase = blockIdx.x * 512 + pg * 128 + wvid * 32;
        short8v rf0 = {0,0,0,0,0,0,0,0}, rf1 = {0,0,0,0,0,0,0,0};
        if (g == 0) {
            const float4 ra = *(const float4*)&rel[(size_t)(pbase + lr) * 4];
            const float4 rb = *(const float4*)&rel[(size_t)(pbase + 16 + lr) * 4];
            rf0[0] = (short)f2bf(ra.x); rf0[1] = (short)f2bf(ra.y);
            rf0[2] = (short)f2bf(ra.z); rf0[3] = (short)f2bf(ra.w);
            rf0[4] = (short)0x3F80;     // 1.0 -> multiplies b1 row
            rf1[0] = (short)f2bf(rb.x); rf1[1] = (short)f2bf(rb.y);
            rf1[2] = (short)f2bf(rb.z); rf1[3] = (short)f2bf(rb.w);
            rf1[4] = (short)0x3F80;
        }
        f32x4 acc0 = z4, acc1 = z4;

        for (int ch = 0; ch < 8; ++ch) {
            // ---- layer 1: 4 n-tiles of 16 (chunk = 64 n) ----
            #pragma unroll
            for (int t = 0; t < 4; ++t) {
                short8v af = {0,0,0,0,0,0,0,0};
                if (g == 0) af = *(const short8v*)&w1t[(ch*64 + t*16 + lr) * 8];
                const f32x4 c0 = __builtin_amdgcn_mfma_f32_16x16x32_bf16(af, rf0, z4, 0, 0, 0);
                const f32x4 c1 = __builtin_amdgcn_mfma_f32_16x16x32_bf16(af, rf1, z4, 0, 0, 0);
                const int slot = t*2 + (g >> 1);
                const int off  = (g & 1) * 8;
                uint2 s0, s1;
                s0.x = pk2r(c0[0], c0[1]); s0.y = pk2r(c0[2], c0[3]);
                s1.x = pk2r(c1[0], c1[1]); s1.y = pk2r(c1[2], c1[3]);
                *(uint2*)(hw + lr*128        + ((slot ^ SW) << 4) + off) = s0;
                *(uint2*)(hw + (16 + lr)*128 + ((slot ^ SW) << 4) + off) = s1;
            }
            // ---- layer 2: 2 K-chunks of 32 ----
            #pragma unroll
            for (int kc = 0; kc < 2; ++kc) {
                const int slot = kc*4 + g;
                short8v a2 = {0,0,0,0,0,0,0,0};
                if (lr < 8) a2 = *(const short8v*)((const char*)w2t + lr*1024 + (((ch*8 + slot) ^ lr) << 4));
                const short8v bf0 = *(const short8v*)(hw + lr*128        + ((slot ^ SW) << 4));
                const short8v bf1 = *(const short8v*)(hw + (16 + lr)*128 + ((slot ^ SW) << 4));
                acc0 = __builtin_amdgcn_mfma_f32_16x16x32_bf16(a2, bf0, acc0, 0, 0, 0);
                acc1 = __builtin_amdgcn_mfma_f32_16x16x32_bf16(a2, bf1, acc1, 0, 0, 0);
            }
        }
        // ---- epilogue: C col = pair, row = h = g*4 + r (g<2 real) ----
        if (g < 2) {
            #pragma unroll
            for (int pt = 0; pt < 2; ++pt) {
                const f32x4 ac = pt ? acc1 : acc0;
                const int pair = pbase + pt*16 + lr;
                const int bb_  = pair >> 18;
                const int ij   = pair & 262143;
                float* dst = relb + (((size_t)(bb_ * 8)) << 18) + ij;
                #pragma unroll
                for (int r = 0; r < 4; ++r) {
                    const int h = g*4 + r;
                    dst[(size_t)h << 18] = 16.0f / (1.0f + __expf(-ac[r]));
                }
            }
        }
    }
}

// ---------------------------------------------------------------------------
// S = 0.125*(Q @ K^T) + relb + maskbias   (in-place over relb) — bf16 MFMA.
// qkvb is [token][1536] bf16; K=64 (one k-step). 64x64 tile, 4 waves.
// ---------------------------------------------------------------------------
__global__ __launch_bounds__(256) void smfma_kernel(const ushort* __restrict__ qkvb,
                                                    const float* __restrict__ maskf,
                                                    float* __restrict__ S) {
    const int bh = blockIdx.z;
    const int b = bh >> 3, h = bh & 7;
    const int bm = blockIdx.y * 64, bn = blockIdx.x * 64;
    __shared__ __align__(16) ushort As[64 * 64];
    __shared__ __align__(16) ushort Bs[64 * 64];
    const int tid = threadIdx.x;
    const int lane = tid & 63, wave = tid >> 6;
    const int wm = (wave >> 1) * 32, wn = (wave & 1) * 32;
    const int rs = tid >> 2, sl0 = (tid * 2) & 7;
    const ushort* Qb = qkvb + (size_t)(b*A_ + bm + rs) * TD_ + h*HD_;
    const ushort* Kb = qkvb + (size_t)(b*A_ + bn + rs) * TD_ + D_ + h*HD_;
    #pragma unroll
    for (int u = 0; u < 2; ++u) {
        const int sl = sl0 + u;
        *(uint4*)((char*)As + rs*128 + ((sl ^ (rs & 7)) << 4)) = *(const uint4*)&Qb[sl*8];
        *(uint4*)((char*)Bs + rs*128 + ((sl ^ (rs & 7)) << 4)) = *(const uint4*)&Kb[sl*8];
    }
    __syncthreads();
    f32x4 acc[2][2];
    #pragma unroll
    for (int i = 0; i < 2; ++i)
        #pragma unroll
        for (int j = 0; j < 2; ++j) acc[i][j] = (f32x4){0.f, 0.f, 0.f, 0.f};
    #pragma unroll
    for (int kk = 0; kk < 2; ++kk) {
        short8v af[2], bfv[2];
        #pragma unroll
        for (int mf = 0; mf < 2; ++mf) {
            const int row = wm + mf*16 + (lane & 15);
            const int slot = (kk*4 + (lane >> 4)) ^ (row & 7);
            af[mf] = *(const short8v*)((const char*)As + row*128 + (slot << 4));
        }
        #pragma unroll
        for (int nf = 0; nf < 2; ++nf) {
            const int row = wn + nf*16 + (lane & 15);
            const int slot = (kk*4 + (lane >> 4)) ^ (row & 7);
            bfv[nf] = *(const short8v*)((const char*)Bs + row*128 + (slot << 4));
        }
        #pragma unroll
        for (int mf = 0; mf < 2; ++mf)
            #pragma unroll
            for (int nf = 0; nf < 2; ++nf)
                acc[mf][nf] = __builtin_amdgcn_mfma_f32_16x16x32_bf16(af[mf], bfv[nf], acc[mf][nf], 0, 0, 0);
    }
    float* Sb = S + (size_t)bh * (A_ * A_);
    #pragma unroll
    for (int nf = 0; nf < 2; ++nf) {
        const int j = bn + wn + nf*16 + (lane & 15);
        const float mv = maskf[b*A_ + j];
        #pragma unroll
        for (int mf = 0; mf < 2; ++mf) {
            #pragma unroll
            for (int r = 0; r < 4; ++r) {
                const int i = bm + wm + mf*16 + (lane >> 4)*4 + r;
                const size_t idx = (size_t)i * A_ + j;
                Sb[idx] = acc[mf][nf][r] * 0.125f + Sb[idx] + mv;
            }
        }
    }
}

// ---------------------------------------------------------------------------
// Row softmax: read fp32 S, write bf16 P (8192 rows x 512).
// ---------------------------------------------------------------------------
__global__ __launch_bounds__(256) void softmax_kernel(const float* __restrict__ S,
                                                      ushort* __restrict__ P) {
    const size_t base = (size_t)blockIdx.x * A_;
    const int tid = threadIdx.x;
    float2 v = *reinterpret_cast<const float2*>(&S[base + tid*2]);
    float m = fmaxf(v.x, v.y);
    #pragma unroll
    for (int o = 32; o > 0; o >>= 1) m = fmaxf(m, __shfl_xor(m, o));
    __shared__ float rm[4], rs[4];
    if ((tid & 63) == 0) rm[tid >> 6] = m;
    __syncthreads();
    const float M = fmaxf(fmaxf(rm[0], rm[1]), fmaxf(rm[2], rm[3]));
    const float e0 = __expf(v.x - M), e1 = __expf(v.y - M);
    float s = e0 + e1;
    #pragma unroll
    for (int o = 32; o > 0; o >>= 1) s += __shfl_xor(s, o);
    if ((tid & 63) == 0) rs[tid >> 6] = s;
    __syncthreads();
    const float inv = 1.0f / (rs[0] + rs[1] + rs[2] + rs[3]);
    *(unsigned*)&P[base + tid*2] = pk2(e0 * inv, e1 * inv);
}

// ---------------------------------------------------------------------------
// VT[bh][d 0..63][j 0..511] bf16 <- V rows in qkvb. 64x64 tiles.
// ---------------------------------------------------------------------------
__global__ __launch_bounds__(256) void vt_kernel(const ushort* __restrict__ qkvb,
                                                 ushort* __restrict__ VT) {
    const int bh = blockIdx.y, jt = blockIdx.x;
    const int b = bh >> 3, h = bh & 7;
    __shared__ ushort ts[64][72];
    const int tid = threadIdx.x;
    const int r = tid >> 2, c16 = (tid & 3) * 16;
    const ushort* src = qkvb + (size_t)(b*A_ + jt*64 + r) * TD_ + 2*D_ + h*HD_ + c16;
    *(uint4*)&ts[r][c16]     = *(const uint4*)&src[0];
    *(uint4*)&ts[r][c16 + 8] = *(const uint4*)&src[8];
    __syncthreads();
    const int d = tid >> 2, jb = (tid & 3) * 16;
    unsigned pk[8];
    #pragma unroll
    for (int i = 0; i < 8; ++i)
        pk[i] = (unsigned)ts[jb + i*2][d] | ((unsigned)ts[jb + i*2 + 1][d] << 16);
    uint4* dst = (uint4*)&VT[(size_t)(bh*64 + d) * A_ + jt*64 + jb];
    dst[0] = make_uint4(pk[0], pk[1], pk[2], pk[3]);
    dst[1] = make_uint4(pk[4], pk[5], pk[6], pk[7]);
}

// ---------------------------------------------------------------------------
// O = P @ V via bf16 MFMA: A = P [i][j], BT = VT [d][j], K=512.
// Output scattered into attnb[(b*A + i)*D + h*64 + d].
// ---------------------------------------------------------------------------
__global__ __launch_bounds__(256) void pvmfma_kernel(const ushort* __restrict__ P,
                                                     const ushort* __restrict__ VT,
                                                     float* __restrict__ outb) {
    const int bh = blockIdx.y;
    const int b = bh >> 3, h = bh & 7;
    const int bm = blockIdx.x * 64;
    __shared__ __align__(16) ushort As[64 * 64];
    __shared__ __align__(16) ushort Bs[64 * 64];
    const int tid = threadIdx.x;
    const int lane = tid & 63, wave = tid >> 6;
    const int wm = (wave >> 1) * 32, wn = (wave & 1) * 32;
    const int rs = tid >> 2, sl0 = (tid * 2) & 7;
    const ushort* Pb = P + (size_t)(bh*A_ + bm + rs) * A_;
    const ushort* Vb = VT + (size_t)(bh*64 + rs) * A_;
    f32x4 acc[2][2];
    #pragma unroll
    for (int i = 0; i < 2; ++i)
        #pragma unroll
        for (int j = 0; j < 2; ++j) acc[i][j] = (f32x4){0.f, 0.f, 0.f, 0.f};
    for (int k0 = 0; k0 < A_; k0 += 64) {
        #pragma unroll
        for (int u = 0; u < 2; ++u) {
            const int sl = sl0 + u;
            *(uint4*)((char*)As + rs*128 + ((sl ^ (rs & 7)) << 4)) = *(const uint4*)&Pb[k0 + sl*8];
            *(uint4*)((char*)Bs + rs*128 + ((sl ^ (rs & 7)) << 4)) = *(const uint4*)&Vb[k0 + sl*8];
        }
        __syncthreads();
        #pragma unroll
        for (int kk = 0; kk < 2; ++kk) {
            short8v af[2], bfv[2];
            #pragma unroll
            for (int mf = 0; mf < 2; ++mf) {
                const int row = wm + mf*16 + (lane & 15);
                const int slot = (kk*4 + (lane >> 4)) ^ (row & 7);
                af[mf] = *(const short8v*)((const char*)As + row*128 + (slot << 4));
            }
            #pragma unroll
            for (int nf = 0; nf < 2; ++nf) {
                const int row = wn + nf*16 + (lane & 15);
                const int slot = (kk*4 + (lane >> 4)) ^ (row & 7);
                bfv[nf] = *(const short8v*)((const char*)Bs + row*128 + (slot << 4));
            }
            #pragma unroll
            for (int mf = 0; mf < 2; ++mf)
                #pragma unroll
                for (int nf = 0; nf < 2; ++nf)
                    acc[mf][nf] = __builtin_amdgcn_mfma_f32_16x16x32_bf16(af[mf], bfv[nf], acc[mf][nf], 0, 0, 0);
        }
        __syncthreads();
    }
    #pragma unroll
    for (int nf = 0; nf < 2; ++nf) {
        const int dc = wn + nf*16 + (lane & 15);
        #pragma unroll
        for (int mf = 0; mf < 2; ++mf) {
            #pragma unroll
            for (int r = 0; r < 4; ++r) {
                const int i = bm + wm + mf*16 + (lane >> 4)*4 + r;
                outb[(size_t)(b*A_ + i) * D_ + h*HD_ + dc] = acc[mf][nf][r];
            }
        }
    }
}

// ---------------------------------------------------------------------------
// Fused residual + LayerNorm (512). Optional bf16 copy of the output.
// ---------------------------------------------------------------------------
template<int BF16OUT>
__global__ __launch_bounds__(256) void ln_kernel(const float* __restrict__ a,
                                                 const float* __restrict__ r,
                                                 const float* __restrict__ g,
                                                 const float* __restrict__ bb,
                                                 float* __restrict__ out,
                                                 ushort* __restrict__ outb) {
    const int row = blockIdx.x;
    const int tid = threadIdx.x;
    const size_t base = (size_t)row * D_ + tid * 2;
    const float2 a2 = *reinterpret_cast<const float2*>(&a[base]);
    const float2 r2 = *reinterpret_cast<const float2*>(&r[base]);
    const float e0 = a2.x + r2.x, e1 = a2.y + r2.y;
    float s = e0 + e1;
    float q = e0*e0 + e1*e1;
    #pragma unroll
    for (int o = 32; o > 0; o >>= 1) { s += __shfl_down(s, o); q += __shfl_down(q, o); }
    __shared__ float rs[4], rq[4];
    if ((tid & 63) == 0) { rs[tid >> 6] = s; rq[tid >> 6] = q; }
    __syncthreads();
    const float S = rs[0]+rs[1]+rs[2]+rs[3];
    const float Q = rq[0]+rq[1]+rq[2]+rq[3];
    const float mean = S * (1.0f/512.0f);
    const float var  = Q * (1.0f/512.0f) - mean*mean;
    const float rstd = rsqrtf(var + 1e-5f);
    const int c = tid*2;
    float2 ov;
    ov.x = (e0 - mean)*rstd*g[c]   + bb[c];
    ov.y = (e1 - mean)*rstd*g[c+1] + bb[c+1];
    *reinterpret_cast<float2*>(&out[base]) = ov;
    if (BF16OUT) {
        *(unsigned*)&outb[base] = pk2(ov.x, ov.y);
    }
}

// ---------------------------------------------------------------------------
extern "C" void kernel_launch(void* const* d_in, const int* in_sizes, int n_in,
                              void* d_out, int out_size, void* d_ws, size_t ws_size,
                              hipStream_t stream) {
    const float* x        = (const float*)d_in[0];
    const void*  mask     = d_in[1];
    const float* relation = (const float*)d_in[2];
    const float* qkv_w    = (const float*)d_in[3];
    const float* qkv_b    = (const float*)d_in[4];
    const float* rel_w1   = (const float*)d_in[5];
    const float* rel_b1   = (const float*)d_in[6];
    const float* rel_w2   = (const float*)d_in[7];
    const float* ff_w1    = (const float*)d_in[8];
    const float* ff_b1    = (const float*)d_in[9];
    const float* ff_w2    = (const float*)d_in[10];
    const float* ff_b2    = (const float*)d_in[11];
    const float* ln1_g    = (const float*)d_in[12];
    const float* ln1_b    = (const float*)d_in[13];
    const float* ln2_g    = (const float*)d_in[14];
    const float* ln2_b    = (const float*)d_in[15];
    float* out = (float*)d_out;

    float* ws     = (float*)d_ws;
    float*  relb  = ws;                            // 4,194,304 f (relb -> S)
    float*  maskf = relb  + 4194304;               // 1,024 f
    float*  attnb = maskf + 1024;                  // 524,288 f
    float*  x1    = attnb + 524288;                // 524,288 f
    ushort* wtb   = (ushort*)(x1 + 524288);        // 786,432 ush (reused 3x)
    ushort* xb    = wtb + 786432;                  // 524,288 ush (reused as x1b)
    ushort* ffhb  = xb  + 524288;                  // 1,572,864 ush
    ushort* qkvb  = ffhb + 1572864;                // 1,572,864 ush (bf16 qkv)
    ushort* pb    = qkvb + 1572864;                // 4,194,304 ush (bf16 P)
    ushort* vtb   = pb + 4194304;                  // 524,288 ush (V^T)
    float*  ff2o  = (float*)qkvb;                  // reuse: qkvb dead after attention
    ushort* x1b   = xb;                            // reuse: xb dead after qkv gemm

    mask_kernel<<<1, 1024, 0, stream>>>(mask, maskf);
    cvt_kernel<<<256, 256, 0, stream>>>(x, xb);                         // x -> bf16
    wt_kernel<<<dim3(24, 8), 256, 0, stream>>>(qkv_w, wtb, 512, 1536);  // qkv_w^T bf16
    // qkvb = bf16(x @ qkv_w + qkv_b)
    mgemm_kernel<0,1><<<dim3(24, 16), 256, 0, stream>>>(xb, wtb, qkv_b, qkvb, 1024, 1536, 512);
    relmlp_kernel<<<1024, 256, 0, stream>>>(relation, rel_w1, rel_b1, rel_w2, relb);
    vt_kernel<<<dim3(8, 16), 256, 0, stream>>>(qkvb, vtb);
    // S = 0.125*Q@K^T + relb + mask (in place)
    smfma_kernel<<<dim3(8, 8, 16), 256, 0, stream>>>(qkvb, maskf, relb);
    // P = softmax(S) rows -> bf16
    softmax_kernel<<<16*512, 256, 0, stream>>>(relb, pb);
    // attnb = P @ V
    pvmfma_kernel<<<dim3(8, 16), 256, 0, stream>>>(pb, vtb, attnb);
    // x1 = LN(attn + x)
    ln_kernel<1><<<1024, 256, 0, stream>>>(attnb, x, ln1_g, ln1_b, x1, x1b);
    wt_kernel<<<dim3(24, 8), 256, 0, stream>>>(ff_w1, wtb, 512, 1536);  // ff_w1^T bf16
    mgemm_kernel<1,1><<<dim3(24, 16), 256, 0, stream>>>(x1b, wtb, ff_b1, ffhb, 1024, 1536, 512);
    wt_kernel<<<dim3(8, 24), 256, 0, stream>>>(ff_w2, wtb, 1536, 512);  // ff_w2^T bf16
    mgemm_kernel<0,0><<<dim3(8, 16), 256, 0, stream>>>(ffhb, wtb, ff_b2, ff2o, 1024, 512, 1536);
    ln_kernel<0><<<1024, 256, 0, stream>>>(ff2o, x1, ln2_g, ln2_b, out, nullptr);
}

// Round 8
// 130.913 us; speedup vs baseline: 4.0921x; 1.0429x over previous
//
#include <hip/hip_runtime.h>
#include <hip/hip_bf16.h>

#define A_  512
#define D_  512
#define H_  8
#define HD_ 64
#define TD_ 1536   // 3*D
#define RH_ 512    // REL_HID

typedef __attribute__((ext_vector_type(8))) short short8v;
typedef __attribute__((ext_vector_type(4))) float f32x4;
typedef __attribute__((ext_vector_type(4))) unsigned int u32x4;
union V8 { u32x4 u; short8v s; };

__device__ __forceinline__ unsigned short f2bf(float f) {
    unsigned int u = __float_as_uint(f);
    u += 0x7FFFu + ((u >> 16) & 1u);
    return (unsigned short)(u >> 16);
}
// pack 2 f32 -> 2 bf16 in one v_cvt_pk_bf16_f32 (no builtin on gfx950)
__device__ __forceinline__ unsigned pk2(float a, float b) {
    unsigned r;
    asm("v_cvt_pk_bf16_f32 %0, %1, %2" : "=v"(r) : "v"(a), "v"(b));
    return r;
}
// relu + pack
__device__ __forceinline__ unsigned pk2r(float a, float b) {
    return pk2(fmaxf(a, 0.f), fmaxf(b, 0.f));
}

// ---------------------------------------------------------------------------
// mask -> float bias (-1e9 / 0), with on-device bool/int32 layout detection.
// ---------------------------------------------------------------------------
__global__ __launch_bounds__(1024) void mask_kernel(const void* __restrict__ mraw,
                                                    float* __restrict__ maskf) {
    __shared__ int anyOdd;
    const int tid = threadIdx.x;          // 0..1023 == B*A
    if (tid == 0) anyOdd = 0;
    __syncthreads();
    const unsigned char* mb = (const unsigned char*)mraw;
    unsigned char v = mb[tid];
    if ((tid & 3) != 0 && v != 0) atomicOr(&anyOdd, 1);
    __syncthreads();
    const bool isByte = (anyOdd != 0);
    int set = isByte ? (mb[tid] != 0) : (((const int*)mraw)[tid] != 0);
    maskf[tid] = set ? -1e9f : 0.0f;
}

// ---------------------------------------------------------------------------
// Elementwise fp32 -> bf16 (8 elems/thread).
// ---------------------------------------------------------------------------
__global__ __launch_bounds__(256) void cvt_kernel(const float* __restrict__ in,
                                                  ushort* __restrict__ out) {
    const int i = (blockIdx.x * 256 + threadIdx.x) * 8;
    const float4 a = *(const float4*)&in[i];
    const float4 b = *(const float4*)&in[i + 4];
    uint4 o;
    o.x = pk2(a.x, a.y);
    o.y = pk2(a.z, a.w);
    o.z = pk2(b.x, b.y);
    o.w = pk2(b.z, b.w);
    *(uint4*)&out[i] = o;
}

// ---------------------------------------------------------------------------
// Transpose + cvt: in fp32 [R][C] -> out bf16 [C][R]. 64x64 tiles.
// ---------------------------------------------------------------------------
__global__ __launch_bounds__(256) void wt_kernel(const float* __restrict__ in,
                                                 ushort* __restrict__ out,
                                                 int R, int C) {
    __shared__ float ts[64][65];
    const int tid = threadIdx.x;
    const int r0 = blockIdx.y * 64, c0 = blockIdx.x * 64;
    const int r = tid >> 2, cb = (tid & 3) * 16;
    #pragma unroll
    for (int u = 0; u < 4; ++u) {
        const float4 v = *(const float4*)&in[(size_t)(r0 + r) * C + c0 + cb + u*4];
        ts[r][cb + u*4 + 0] = v.x;
        ts[r][cb + u*4 + 1] = v.y;
        ts[r][cb + u*4 + 2] = v.z;
        ts[r][cb + u*4 + 3] = v.w;
    }
    __syncthreads();
    const int oc = tid & 63;
    const int rb = (tid >> 6) * 16;
    unsigned pk[8];
    #pragma unroll
    for (int i = 0; i < 8; ++i) {
        pk[i] = pk2(ts[rb + i*2][oc], ts[rb + i*2 + 1][oc]);
    }
    uint4* dst = (uint4*)&out[(size_t)(c0 + oc) * R + r0 + rb];
    dst[0] = make_uint4(pk[0], pk[1], pk[2], pk[3]);
    dst[1] = make_uint4(pk[4], pk[5], pk[6], pk[7]);
}

// ---------------------------------------------------------------------------
// bf16 MFMA GEMM: C[M,N] = op(A[M,K] @ B[K,N] + bias).
// A is [M][K] bf16, BT is [N][K] bf16 (both K-major). 64x64 tile, BK=64,
// 4 waves (2x2), each wave 32x32 via 16x16x32 MFMA. LDS slot-XOR swizzle.
// ---------------------------------------------------------------------------
template<int RELU, int OBF16>
__global__ __launch_bounds__(256) void mgemm_kernel(const ushort* __restrict__ A,
                                                    const ushort* __restrict__ BT,
                                                    const float* __restrict__ bias,
                                                    void* __restrict__ Cv,
                                                    int M, int N, int K) {
    __shared__ __align__(16) ushort As[64 * 64];
    __shared__ __align__(16) ushort Bs[64 * 64];
    const int tid = threadIdx.x;
    const int bm = blockIdx.y * 64, bn = blockIdx.x * 64;
    const int lane = tid & 63, wave = tid >> 6;
    const int wm = (wave >> 1) * 32, wn = (wave & 1) * 32;
    f32x4 acc[2][2];
    #pragma unroll
    for (int i = 0; i < 2; ++i)
        #pragma unroll
        for (int j = 0; j < 2; ++j) acc[i][j] = (f32x4){0.f, 0.f, 0.f, 0.f};

    const int s0  = tid * 2;
    const int rs  = s0 >> 3;
    const int sl0 = s0 & 7;
    for (int k0 = 0; k0 < K; k0 += 64) {
        #pragma unroll
        for (int u = 0; u < 2; ++u) {
            const int sl = sl0 + u;
            const uint4 va = *(const uint4*)&A[(size_t)(bm + rs) * K + k0 + sl*8];
            *(uint4*)((char*)As + rs*128 + ((sl ^ (rs & 7)) << 4)) = va;
            const uint4 vb = *(const uint4*)&BT[(size_t)(bn + rs) * K + k0 + sl*8];
            *(uint4*)((char*)Bs + rs*128 + ((sl ^ (rs & 7)) << 4)) = vb;
        }
        __syncthreads();
        #pragma unroll
        for (int kk = 0; kk < 2; ++kk) {
            short8v af[2], bfv[2];
            #pragma unroll
            for (int mf = 0; mf < 2; ++mf) {
                const int row = wm + mf*16 + (lane & 15);
                const int slot = (kk*4 + (lane >> 4)) ^ (row & 7);
                af[mf] = *(const short8v*)((const char*)As + row*128 + (slot << 4));
            }
            #pragma unroll
            for (int nf = 0; nf < 2; ++nf) {
                const int row = wn + nf*16 + (lane & 15);
                const int slot = (kk*4 + (lane >> 4)) ^ (row & 7);
                bfv[nf] = *(const short8v*)((const char*)Bs + row*128 + (slot << 4));
            }
            #pragma unroll
            for (int mf = 0; mf < 2; ++mf)
                #pragma unroll
                for (int nf = 0; nf < 2; ++nf)
                    acc[mf][nf] = __builtin_amdgcn_mfma_f32_16x16x32_bf16(af[mf], bfv[nf], acc[mf][nf], 0, 0, 0);
        }
        __syncthreads();
    }
    #pragma unroll
    for (int nf = 0; nf < 2; ++nf) {
        const int col = bn + wn + nf*16 + (lane & 15);
        const float bv = bias[col];
        #pragma unroll
        for (int mf = 0; mf < 2; ++mf) {
            #pragma unroll
            for (int r = 0; r < 4; ++r) {
                const int row = bm + wm + mf*16 + (lane >> 4)*4 + r;
                float v = acc[mf][nf][r] + bv;
                if (RELU) v = fmaxf(v, 0.f);
                if (OBF16) ((ushort*)Cv)[(size_t)row * N + col] = f2bf(v);
                else       ((float*)Cv)[(size_t)row * N + col] = v;
            }
        }
    }
}

// ---------------------------------------------------------------------------
// Fused relation MLP, both layers on MFMA (16x16x32 bf16), ZERO intermediate
// data movement: w2's n-rows are permuted at staging so that layer-1's C
// fragments (relu'd + cvt_pk'd in-register) ARE layer-2's B fragments.
//   layer-1: per 32-n chunk, 2 tiles t0/t1: C rows n = t*16 + g*4 + r
//   layer-2: B frag k-slot s = g*8 + j. Permutation: n=(ch,w): t=w>>4, i=w&15,
//            s = (i>>2)*8 + t*4 + (i&3); kpos = ch*32 + s. (bijective)
// LDS = w1t 8 KB + w2t 8 KB = 16 KB -> 8 blocks/CU. No hid buffer.
// ---------------------------------------------------------------------------
__global__ __launch_bounds__(256) void relmlp_kernel(const float* __restrict__ rel,
                                                     const float* __restrict__ w1,
                                                     const float* __restrict__ b1,
                                                     const float* __restrict__ w2,
                                                     float* __restrict__ relb) {
    __shared__ __align__(16) ushort w1t[512 * 8];   // [n][8k]: w1[0..3][n], b1[n], 0,0,0
    __shared__ __align__(16) ushort w2t[8 * 512];   // [h][kpos], swizzled + n-permuted
    const int tid = threadIdx.x;
    #pragma unroll
    for (int u = 0; u < 2; ++u) {
        const int n = tid + u*256;
        uint4 o;
        o.x = (unsigned)f2bf(w1[n])        | ((unsigned)f2bf(w1[512 + n])  << 16);
        o.y = (unsigned)f2bf(w1[1024 + n]) | ((unsigned)f2bf(w1[1536 + n]) << 16);
        o.z = (unsigned)f2bf(b1[n]);        // k=4 -> b1, k=5 -> 0
        o.w = 0;                            // k=6,7 -> 0
        *(uint4*)&w1t[n * 8] = o;
        // permuted k-position for layer-2 contraction order
        const int ch = n >> 5, w = n & 31, t = w >> 4, i = w & 15;
        const int s = ((i >> 2) << 3) + (t << 2) + (i & 3);
        const int kpos = ch * 32 + s;
        const float4 wlo = *(const float4*)&w2[n*8];
        const float4 whi = *(const float4*)&w2[n*8 + 4];
        const float wvv[8] = {wlo.x, wlo.y, wlo.z, wlo.w, whi.x, whi.y, whi.z, whi.w};
        #pragma unroll
        for (int h = 0; h < 8; ++h) {
            *(ushort*)((char*)w2t + h*1024 + (((kpos >> 3) ^ h) << 4) + (kpos & 7)*2) = f2bf(wvv[h]);
        }
    }
    __syncthreads();

    const int lane = tid & 63, wvid = tid >> 6;
    const int g = lane >> 4, lr = lane & 15;
    const f32x4 z4 = {0.f, 0.f, 0.f, 0.f};

    for (int pg = 0; pg < 2; ++pg) {
        const int pbase = blockIdx.x * 256 + pg * 128 + wvid * 32;
        short8v rf0 = {0,0,0,0,0,0,0,0}, rf1 = {0,0,0,0,0,0,0,0};
        if (g == 0) {
            const float4 ra = *(const float4*)&rel[(size_t)(pbase + lr) * 4];
            const float4 rb = *(const float4*)&rel[(size_t)(pbase + 16 + lr) * 4];
            rf0[0] = (short)f2bf(ra.x); rf0[1] = (short)f2bf(ra.y);
            rf0[2] = (short)f2bf(ra.z); rf0[3] = (short)f2bf(ra.w);
            rf0[4] = (short)0x3F80;     // 1.0 -> multiplies b1 row
            rf1[0] = (short)f2bf(rb.x); rf1[1] = (short)f2bf(rb.y);
            rf1[2] = (short)f2bf(rb.z); rf1[3] = (short)f2bf(rb.w);
            rf1[4] = (short)0x3F80;
        }
        f32x4 acc0 = z4, acc1 = z4;

        #pragma unroll 4
        for (int ch = 0; ch < 16; ++ch) {
            // ---- layer-2 A operand (w2 frag), independent -> issues early ----
            short8v a2 = {0,0,0,0,0,0,0,0};
            if (lr < 8) a2 = *(const short8v*)((const char*)w2t + lr*1024 + (((ch*4 + g) ^ lr) << 4));
            // ---- layer 1: two 16-n tiles of chunk ch ----
            short8v af0 = {0,0,0,0,0,0,0,0}, af1 = {0,0,0,0,0,0,0,0};
            if (g == 0) {
                af0 = *(const short8v*)&w1t[(ch*32 + lr) * 8];
                af1 = *(const short8v*)&w1t[(ch*32 + 16 + lr) * 8];
            }
            const f32x4 c00 = __builtin_amdgcn_mfma_f32_16x16x32_bf16(af0, rf0, z4, 0, 0, 0);
            const f32x4 c10 = __builtin_amdgcn_mfma_f32_16x16x32_bf16(af1, rf0, z4, 0, 0, 0);
            const f32x4 c01 = __builtin_amdgcn_mfma_f32_16x16x32_bf16(af0, rf1, z4, 0, 0, 0);
            const f32x4 c11 = __builtin_amdgcn_mfma_f32_16x16x32_bf16(af1, rf1, z4, 0, 0, 0);
            // ---- relu + pack: registers ARE the layer-2 B fragments ----
            V8 b0, b1v;
            b0.u.x  = pk2r(c00[0], c00[1]); b0.u.y  = pk2r(c00[2], c00[3]);
            b0.u.z  = pk2r(c10[0], c10[1]); b0.u.w  = pk2r(c10[2], c10[3]);
            b1v.u.x = pk2r(c01[0], c01[1]); b1v.u.y = pk2r(c01[2], c01[3]);
            b1v.u.z = pk2r(c11[0], c11[1]); b1v.u.w = pk2r(c11[2], c11[3]);
            // ---- layer 2 ----
            acc0 = __builtin_amdgcn_mfma_f32_16x16x32_bf16(a2, b0.s,  acc0, 0, 0, 0);
            acc1 = __builtin_amdgcn_mfma_f32_16x16x32_bf16(a2, b1v.s, acc1, 0, 0, 0);
        }
        // ---- epilogue: C col = pair, row = h = g*4 + r (g<2 real) ----
        if (g < 2) {
            #pragma unroll
            for (int pt = 0; pt < 2; ++pt) {
                const f32x4 ac = pt ? acc1 : acc0;
                const int pair = pbase + pt*16 + lr;
                const int bb_  = pair >> 18;
                const int ij   = pair & 262143;
                float* dst = relb + (((size_t)(bb_ * 8)) << 18) + ij;
                #pragma unroll
                for (int r = 0; r < 4; ++r) {
                    const int h = g*4 + r;
                    dst[(size_t)h << 18] = 16.0f / (1.0f + __expf(-ac[r]));
                }
            }
        }
    }
}

// ---------------------------------------------------------------------------
// S = 0.125*(Q @ K^T) + relb + maskbias   (in-place over relb) — bf16 MFMA.
// qkvb is [token][1536] bf16; K=64 (one k-step). 64x64 tile, 4 waves.
// ---------------------------------------------------------------------------
__global__ __launch_bounds__(256) void smfma_kernel(const ushort* __restrict__ qkvb,
                                                    const float* __restrict__ maskf,
                                                    float* __restrict__ S) {
    const int bh = blockIdx.z;
    const int b = bh >> 3, h = bh & 7;
    const int bm = blockIdx.y * 64, bn = blockIdx.x * 64;
    __shared__ __align__(16) ushort As[64 * 64];
    __shared__ __align__(16) ushort Bs[64 * 64];
    const int tid = threadIdx.x;
    const int lane = tid & 63, wave = tid >> 6;
    const int wm = (wave >> 1) * 32, wn = (wave & 1) * 32;
    const int rs = tid >> 2, sl0 = (tid * 2) & 7;
    const ushort* Qb = qkvb + (size_t)(b*A_ + bm + rs) * TD_ + h*HD_;
    const ushort* Kb = qkvb + (size_t)(b*A_ + bn + rs) * TD_ + D_ + h*HD_;
    #pragma unroll
    for (int u = 0; u < 2; ++u) {
        const int sl = sl0 + u;
        *(uint4*)((char*)As + rs*128 + ((sl ^ (rs & 7)) << 4)) = *(const uint4*)&Qb[sl*8];
        *(uint4*)((char*)Bs + rs*128 + ((sl ^ (rs & 7)) << 4)) = *(const uint4*)&Kb[sl*8];
    }
    __syncthreads();
    f32x4 acc[2][2];
    #pragma unroll
    for (int i = 0; i < 2; ++i)
        #pragma unroll
        for (int j = 0; j < 2; ++j) acc[i][j] = (f32x4){0.f, 0.f, 0.f, 0.f};
    #pragma unroll
    for (int kk = 0; kk < 2; ++kk) {
        short8v af[2], bfv[2];
        #pragma unroll
        for (int mf = 0; mf < 2; ++mf) {
            const int row = wm + mf*16 + (lane & 15);
            const int slot = (kk*4 + (lane >> 4)) ^ (row & 7);
            af[mf] = *(const short8v*)((const char*)As + row*128 + (slot << 4));
        }
        #pragma unroll
        for (int nf = 0; nf < 2; ++nf) {
            const int row = wn + nf*16 + (lane & 15);
            const int slot = (kk*4 + (lane >> 4)) ^ (row & 7);
            bfv[nf] = *(const short8v*)((const char*)Bs + row*128 + (slot << 4));
        }
        #pragma unroll
        for (int mf = 0; mf < 2; ++mf)
            #pragma unroll
            for (int nf = 0; nf < 2; ++nf)
                acc[mf][nf] = __builtin_amdgcn_mfma_f32_16x16x32_bf16(af[mf], bfv[nf], acc[mf][nf], 0, 0, 0);
    }
    float* Sb = S + (size_t)bh * (A_ * A_);
    #pragma unroll
    for (int nf = 0; nf < 2; ++nf) {
        const int j = bn + wn + nf*16 + (lane & 15);
        const float mv = maskf[b*A_ + j];
        #pragma unroll
        for (int mf = 0; mf < 2; ++mf) {
            #pragma unroll
            for (int r = 0; r < 4; ++r) {
                const int i = bm + wm + mf*16 + (lane >> 4)*4 + r;
                const size_t idx = (size_t)i * A_ + j;
                Sb[idx] = acc[mf][nf][r] * 0.125f + Sb[idx] + mv;
            }
        }
    }
}

// ---------------------------------------------------------------------------
// Row softmax: read fp32 S, write bf16 P (8192 rows x 512).
// ---------------------------------------------------------------------------
__global__ __launch_bounds__(256) void softmax_kernel(const float* __restrict__ S,
                                                      ushort* __restrict__ P) {
    const size_t base = (size_t)blockIdx.x * A_;
    const int tid = threadIdx.x;
    float2 v = *reinterpret_cast<const float2*>(&S[base + tid*2]);
    float m = fmaxf(v.x, v.y);
    #pragma unroll
    for (int o = 32; o > 0; o >>= 1) m = fmaxf(m, __shfl_xor(m, o));
    __shared__ float rm[4], rs[4];
    if ((tid & 63) == 0) rm[tid >> 6] = m;
    __syncthreads();
    const float M = fmaxf(fmaxf(rm[0], rm[1]), fmaxf(rm[2], rm[3]));
    const float e0 = __expf(v.x - M), e1 = __expf(v.y - M);
    float s = e0 + e1;
    #pragma unroll
    for (int o = 32; o > 0; o >>= 1) s += __shfl_xor(s, o);
    if ((tid & 63) == 0) rs[tid >> 6] = s;
    __syncthreads();
    const float inv = 1.0f / (rs[0] + rs[1] + rs[2] + rs[3]);
    *(unsigned*)&P[base + tid*2] = pk2(e0 * inv, e1 * inv);
}

// ---------------------------------------------------------------------------
// VT[bh][d 0..63][j 0..511] bf16 <- V rows in qkvb. 64x64 tiles.
// ---------------------------------------------------------------------------
__global__ __launch_bounds__(256) void vt_kernel(const ushort* __restrict__ qkvb,
                                                 ushort* __restrict__ VT) {
    const int bh = blockIdx.y, jt = blockIdx.x;
    const int b = bh >> 3, h = bh & 7;
    __shared__ ushort ts[64][72];
    const int tid = threadIdx.x;
    const int r = tid >> 2, c16 = (tid & 3) * 16;
    const ushort* src = qkvb + (size_t)(b*A_ + jt*64 + r) * TD_ + 2*D_ + h*HD_ + c16;
    *(uint4*)&ts[r][c16]     = *(const uint4*)&src[0];
    *(uint4*)&ts[r][c16 + 8] = *(const uint4*)&src[8];
    __syncthreads();
    const int d = tid >> 2, jb = (tid & 3) * 16;
    unsigned pk[8];
    #pragma unroll
    for (int i = 0; i < 8; ++i)
        pk[i] = (unsigned)ts[jb + i*2][d] | ((unsigned)ts[jb + i*2 + 1][d] << 16);
    uint4* dst = (uint4*)&VT[(size_t)(bh*64 + d) * A_ + jt*64 + jb];
    dst[0] = make_uint4(pk[0], pk[1], pk[2], pk[3]);
    dst[1] = make_uint4(pk[4], pk[5], pk[6], pk[7]);
}

// ---------------------------------------------------------------------------
// O = P @ V via bf16 MFMA: A = P [i][j], BT = VT [d][j], K=512.
// Output scattered into attnb[(b*A + i)*D + h*64 + d].
// ---------------------------------------------------------------------------
__global__ __launch_bounds__(256) void pvmfma_kernel(const ushort* __restrict__ P,
                                                     const ushort* __restrict__ VT,
                                                     float* __restrict__ outb) {
    const int bh = blockIdx.y;
    const int b = bh >> 3, h = bh & 7;
    const int bm = blockIdx.x * 64;
    __shared__ __align__(16) ushort As[64 * 64];
    __shared__ __align__(16) ushort Bs[64 * 64];
    const int tid = threadIdx.x;
    const int lane = tid & 63, wave = tid >> 6;
    const int wm = (wave >> 1) * 32, wn = (wave & 1) * 32;
    const int rs = tid >> 2, sl0 = (tid * 2) & 7;
    const ushort* Pb = P + (size_t)(bh*A_ + bm + rs) * A_;
    const ushort* Vb = VT + (size_t)(bh*64 + rs) * A_;
    f32x4 acc[2][2];
    #pragma unroll
    for (int i = 0; i < 2; ++i)
        #pragma unroll
        for (int j = 0; j < 2; ++j) acc[i][j] = (f32x4){0.f, 0.f, 0.f, 0.f};
    for (int k0 = 0; k0 < A_; k0 += 64) {
        #pragma unroll
        for (int u = 0; u < 2; ++u) {
            const int sl = sl0 + u;
            *(uint4*)((char*)As + rs*128 + ((sl ^ (rs & 7)) << 4)) = *(const uint4*)&Pb[k0 + sl*8];
            *(uint4*)((char*)Bs + rs*128 + ((sl ^ (rs & 7)) << 4)) = *(const uint4*)&Vb[k0 + sl*8];
        }
        __syncthreads();
        #pragma unroll
        for (int kk = 0; kk < 2; ++kk) {
            short8v af[2], bfv[2];
            #pragma unroll
            for (int mf = 0; mf < 2; ++mf) {
                const int row = wm + mf*16 + (lane & 15);
                const int slot = (kk*4 + (lane >> 4)) ^ (row & 7);
                af[mf] = *(const short8v*)((const char*)As + row*128 + (slot << 4));
            }
            #pragma unroll
            for (int nf = 0; nf < 2; ++nf) {
                const int row = wn + nf*16 + (lane & 15);
                const int slot = (kk*4 + (lane >> 4)) ^ (row & 7);
                bfv[nf] = *(const short8v*)((const char*)Bs + row*128 + (slot << 4));
            }
            #pragma unroll
            for (int mf = 0; mf < 2; ++mf)
                #pragma unroll
                for (int nf = 0; nf < 2; ++nf)
                    acc[mf][nf] = __builtin_amdgcn_mfma_f32_16x16x32_bf16(af[mf], bfv[nf], acc[mf][nf], 0, 0, 0);
        }
        __syncthreads();
    }
    #pragma unroll
    for (int nf = 0; nf < 2; ++nf) {
        const int dc = wn + nf*16 + (lane & 15);
        #pragma unroll
        for (int mf = 0; mf < 2; ++mf) {
            #pragma unroll
            for (int r = 0; r < 4; ++r) {
                const int i = bm + wm + mf*16 + (lane >> 4)*4 + r;
                outb[(size_t)(b*A_ + i) * D_ + h*HD_ + dc] = acc[mf][nf][r];
            }
        }
    }
}

// ---------------------------------------------------------------------------
// Fused residual + LayerNorm (512). Optional bf16 copy of the output.
// ---------------------------------------------------------------------------
template<int BF16OUT>
__global__ __launch_bounds__(256) void ln_kernel(const float* __restrict__ a,
                                                 const float* __restrict__ r,
                                                 const float* __restrict__ g,
                                                 const float* __restrict__ bb,
                                                 float* __restrict__ out,
                                                 ushort* __restrict__ outb) {
    const int row = blockIdx.x;
    const int tid = threadIdx.x;
    const size_t base = (size_t)row * D_ + tid * 2;
    const float2 a2 = *reinterpret_cast<const float2*>(&a[base]);
    const float2 r2 = *reinterpret_cast<const float2*>(&r[base]);
    const float e0 = a2.x + r2.x, e1 = a2.y + r2.y;
    float s = e0 + e1;
    float q = e0*e0 + e1*e1;
    #pragma unroll
    for (int o = 32; o > 0; o >>= 1) { s += __shfl_down(s, o); q += __shfl_down(q, o); }
    __shared__ float rs[4], rq[4];
    if ((tid & 63) == 0) { rs[tid >> 6] = s; rq[tid >> 6] = q; }
    __syncthreads();
    const float S = rs[0]+rs[1]+rs[2]+rs[3];
    const float Q = rq[0]+rq[1]+rq[2]+rq[3];
    const float mean = S * (1.0f/512.0f);
    const float var  = Q * (1.0f/512.0f) - mean*mean;
    const float rstd = rsqrtf(var + 1e-5f);
    const int c = tid*2;
    float2 ov;
    ov.x = (e0 - mean)*rstd*g[c]   + bb[c];
    ov.y = (e1 - mean)*rstd*g[c+1] + bb[c+1];
    *reinterpret_cast<float2*>(&out[base]) = ov;
    if (BF16OUT) {
        *(unsigned*)&outb[base] = pk2(ov.x, ov.y);
    }
}

// ---------------------------------------------------------------------------
extern "C" void kernel_launch(void* const* d_in, const int* in_sizes, int n_in,
                              void* d_out, int out_size, void* d_ws, size_t ws_size,
                              hipStream_t stream) {
    const float* x        = (const float*)d_in[0];
    const void*  mask     = d_in[1];
    const float* relation = (const float*)d_in[2];
    const float* qkv_w    = (const float*)d_in[3];
    const float* qkv_b    = (const float*)d_in[4];
    const float* rel_w1   = (const float*)d_in[5];
    const float* rel_b1   = (const float*)d_in[6];
    const float* rel_w2   = (const float*)d_in[7];
    const float* ff_w1    = (const float*)d_in[8];
    const float* ff_b1    = (const float*)d_in[9];
    const float* ff_w2    = (const float*)d_in[10];
    const float* ff_b2    = (const float*)d_in[11];
    const float* ln1_g    = (const float*)d_in[12];
    const float* ln1_b    = (const float*)d_in[13];
    const float* ln2_g    = (const float*)d_in[14];
    const float* ln2_b    = (const float*)d_in[15];
    float* out = (float*)d_out;

    float* ws     = (float*)d_ws;
    float*  relb  = ws;                            // 4,194,304 f (relb -> S)
    float*  maskf = relb  + 4194304;               // 1,024 f
    float*  attnb = maskf + 1024;                  // 524,288 f
    float*  x1    = attnb + 524288;                // 524,288 f
    ushort* wtb   = (ushort*)(x1 + 524288);        // 786,432 ush (reused 3x)
    ushort* xb    = wtb + 786432;                  // 524,288 ush (reused as x1b)
    ushort* ffhb  = xb  + 524288;                  // 1,572,864 ush
    ushort* qkvb  = ffhb + 1572864;                // 1,572,864 ush (bf16 qkv)
    ushort* pb    = qkvb + 1572864;                // 4,194,304 ush (bf16 P)
    ushort* vtb   = pb + 4194304;                  // 524,288 ush (V^T)
    float*  ff2o  = (float*)qkvb;                  // reuse: qkvb dead after attention
    ushort* x1b   = xb;                            // reuse: xb dead after qkv gemm

    mask_kernel<<<1, 1024, 0, stream>>>(mask, maskf);
    cvt_kernel<<<256, 256, 0, stream>>>(x, xb);                         // x -> bf16
    wt_kernel<<<dim3(24, 8), 256, 0, stream>>>(qkv_w, wtb, 512, 1536);  // qkv_w^T bf16
    // qkvb = bf16(x @ qkv_w + qkv_b)
    mgemm_kernel<0,1><<<dim3(24, 16), 256, 0, stream>>>(xb, wtb, qkv_b, qkvb, 1024, 1536, 512);
    relmlp_kernel<<<2048, 256, 0, stream>>>(relation, rel_w1, rel_b1, rel_w2, relb);
    vt_kernel<<<dim3(8, 16), 256, 0, stream>>>(qkvb, vtb);
    // S = 0.125*Q@K^T + relb + mask (in place)
    smfma_kernel<<<dim3(8, 8, 16), 256, 0, stream>>>(qkvb, maskf, relb);
    // P = softmax(S) rows -> bf16
    softmax_kernel<<<16*512, 256, 0, stream>>>(relb, pb);
    // attnb = P @ V
    pvmfma_kernel<<<dim3(8, 16), 256, 0, stream>>>(pb, vtb, attnb);
    // x1 = LN(attn + x)
    ln_kernel<1><<<1024, 256, 0, stream>>>(attnb, x, ln1_g, ln1_b, x1, x1b);
    wt_kernel<<<dim3(24, 8), 256, 0, stream>>>(ff_w1, wtb, 512, 1536);  // ff_w1^T bf16
    mgemm_kernel<1,1><<<dim3(24, 16), 256, 0, stream>>>(x1b, wtb, ff_b1, ffhb, 1024, 1536, 512);
    wt_kernel<<<dim3(8, 24), 256, 0, stream>>>(ff_w2, wtb, 1536, 512);  // ff_w2^T bf16
    mgemm_kernel<0,0><<<dim3(8, 16), 256, 0, stream>>>(ffhb, wtb, ff_b2, ff2o, 1024, 512, 1536);
    ln_kernel<0><<<1024, 256, 0, stream>>>(ff2o, x1, ln2_g, ln2_b, out, nullptr);
}

// Round 9
// 124.411 us; speedup vs baseline: 4.3060x; 1.0523x over previous
//
#include <hip/hip_runtime.h>
#include <hip/hip_bf16.h>

#define A_  512
#define D_  512
#define H_  8
#define HD_ 64
#define TD_ 1536   // 3*D
#define RH_ 512    // REL_HID

typedef __attribute__((ext_vector_type(8))) short short8v;
typedef __attribute__((ext_vector_type(4))) float f32x4;
typedef __attribute__((ext_vector_type(4))) unsigned int u32x4;
union V8 { u32x4 u; short8v s; };

__device__ __forceinline__ unsigned short f2bf(float f) {
    unsigned int u = __float_as_uint(f);
    u += 0x7FFFu + ((u >> 16) & 1u);
    return (unsigned short)(u >> 16);
}
// pack 2 f32 -> 2 bf16 in one v_cvt_pk_bf16_f32 (no builtin on gfx950)
__device__ __forceinline__ unsigned pk2(float a, float b) {
    unsigned r;
    asm("v_cvt_pk_bf16_f32 %0, %1, %2" : "=v"(r) : "v"(a), "v"(b));
    return r;
}
// relu + pack
__device__ __forceinline__ unsigned pk2r(float a, float b) {
    return pk2(fmaxf(a, 0.f), fmaxf(b, 0.f));
}

// ---------------------------------------------------------------------------
// prep: block 256 -> mask bias (-1e9/0, bool/int32 layout autodetect);
//       blocks 0..255 -> x fp32 -> bf16.
// ---------------------------------------------------------------------------
__global__ __launch_bounds__(256) void prep_kernel(const float* __restrict__ x,
                                                   const void* __restrict__ mraw,
                                                   ushort* __restrict__ xb,
                                                   float* __restrict__ maskf) {
    const int tid = threadIdx.x;
    if (blockIdx.x == 256) {
        __shared__ int anyOdd;
        if (tid == 0) anyOdd = 0;
        __syncthreads();
        const unsigned char* mb = (const unsigned char*)mraw;
        int local = 0;
        #pragma unroll
        for (int u = 0; u < 4; ++u) {
            const int i = tid * 4 + u;
            if ((i & 3) != 0 && mb[i] != 0) local = 1;
        }
        if (local) atomicOr(&anyOdd, 1);
        __syncthreads();
        const bool isByte = (anyOdd != 0);
        #pragma unroll
        for (int u = 0; u < 4; ++u) {
            const int i = tid * 4 + u;
            int set = isByte ? (mb[i] != 0) : (((const int*)mraw)[i] != 0);
            maskf[i] = set ? -1e9f : 0.0f;
        }
        return;
    }
    const int i = (blockIdx.x * 256 + tid) * 8;
    const float4 a = *(const float4*)&x[i];
    const float4 b = *(const float4*)&x[i + 4];
    uint4 o;
    o.x = pk2(a.x, a.y);
    o.y = pk2(a.z, a.w);
    o.z = pk2(b.x, b.y);
    o.w = pk2(b.z, b.w);
    *(uint4*)&xb[i] = o;
}

// ---------------------------------------------------------------------------
// Transpose + cvt device body: in fp32 [R][C] -> out bf16 [C][R], 64x64 tile.
// ---------------------------------------------------------------------------
__device__ __forceinline__ void wt_body(const float* __restrict__ in,
                                        ushort* __restrict__ out,
                                        int R, int C, int bx, int by) {
    __shared__ float ts[64][65];
    const int tid = threadIdx.x;
    const int r0 = by * 64, c0 = bx * 64;
    const int r = tid >> 2, cb = (tid & 3) * 16;
    #pragma unroll
    for (int u = 0; u < 4; ++u) {
        const float4 v = *(const float4*)&in[(size_t)(r0 + r) * C + c0 + cb + u*4];
        ts[r][cb + u*4 + 0] = v.x;
        ts[r][cb + u*4 + 1] = v.y;
        ts[r][cb + u*4 + 2] = v.z;
        ts[r][cb + u*4 + 3] = v.w;
    }
    __syncthreads();
    const int oc = tid & 63;
    const int rb = (tid >> 6) * 16;
    unsigned pk[8];
    #pragma unroll
    for (int i = 0; i < 8; ++i) {
        pk[i] = pk2(ts[rb + i*2][oc], ts[rb + i*2 + 1][oc]);
    }
    uint4* dst = (uint4*)&out[(size_t)(c0 + oc) * R + r0 + rb];
    dst[0] = make_uint4(pk[0], pk[1], pk[2], pk[3]);
    dst[1] = make_uint4(pk[4], pk[5], pk[6], pk[7]);
}

// All three weight transposes in one launch: 0..191 qkv_w, 192..383 ff_w1
// (both 512x1536, 24x8 tiles), 384..575 ff_w2 (1536x512, 8x24 tiles).
__global__ __launch_bounds__(256) void wt3_kernel(const float* __restrict__ qkv_w,
                                                  const float* __restrict__ ff_w1,
                                                  const float* __restrict__ ff_w2,
                                                  ushort* __restrict__ wtb1,
                                                  ushort* __restrict__ wtb2,
                                                  ushort* __restrict__ wtb3) {
    const int bid = blockIdx.x;
    if (bid < 192) {
        wt_body(qkv_w, wtb1, 512, 1536, bid % 24, bid / 24);
    } else if (bid < 384) {
        const int i = bid - 192;
        wt_body(ff_w1, wtb2, 512, 1536, i % 24, i / 24);
    } else {
        const int i = bid - 384;
        wt_body(ff_w2, wtb3, 1536, 512, i % 8, i / 8);
    }
}

// ---------------------------------------------------------------------------
// bf16 MFMA GEMM: C[M,N] = op(A[M,K] @ B[K,N] + bias).
// A is [M][K] bf16, BT is [N][K] bf16 (both K-major). 64x64 tile, BK=64,
// 4 waves (2x2), each wave 32x32 via 16x16x32 MFMA. LDS slot-XOR swizzle.
// ---------------------------------------------------------------------------
template<int RELU, int OBF16>
__global__ __launch_bounds__(256) void mgemm_kernel(const ushort* __restrict__ A,
                                                    const ushort* __restrict__ BT,
                                                    const float* __restrict__ bias,
                                                    void* __restrict__ Cv,
                                                    int M, int N, int K) {
    __shared__ __align__(16) ushort As[64 * 64];
    __shared__ __align__(16) ushort Bs[64 * 64];
    const int tid = threadIdx.x;
    const int bm = blockIdx.y * 64, bn = blockIdx.x * 64;
    const int lane = tid & 63, wave = tid >> 6;
    const int wm = (wave >> 1) * 32, wn = (wave & 1) * 32;
    f32x4 acc[2][2];
    #pragma unroll
    for (int i = 0; i < 2; ++i)
        #pragma unroll
        for (int j = 0; j < 2; ++j) acc[i][j] = (f32x4){0.f, 0.f, 0.f, 0.f};

    const int s0  = tid * 2;
    const int rs  = s0 >> 3;
    const int sl0 = s0 & 7;
    for (int k0 = 0; k0 < K; k0 += 64) {
        #pragma unroll
        for (int u = 0; u < 2; ++u) {
            const int sl = sl0 + u;
            const uint4 va = *(const uint4*)&A[(size_t)(bm + rs) * K + k0 + sl*8];
            *(uint4*)((char*)As + rs*128 + ((sl ^ (rs & 7)) << 4)) = va;
            const uint4 vb = *(const uint4*)&BT[(size_t)(bn + rs) * K + k0 + sl*8];
            *(uint4*)((char*)Bs + rs*128 + ((sl ^ (rs & 7)) << 4)) = vb;
        }
        __syncthreads();
        #pragma unroll
        for (int kk = 0; kk < 2; ++kk) {
            short8v af[2], bfv[2];
            #pragma unroll
            for (int mf = 0; mf < 2; ++mf) {
                const int row = wm + mf*16 + (lane & 15);
                const int slot = (kk*4 + (lane >> 4)) ^ (row & 7);
                af[mf] = *(const short8v*)((const char*)As + row*128 + (slot << 4));
            }
            #pragma unroll
            for (int nf = 0; nf < 2; ++nf) {
                const int row = wn + nf*16 + (lane & 15);
                const int slot = (kk*4 + (lane >> 4)) ^ (row & 7);
                bfv[nf] = *(const short8v*)((const char*)Bs + row*128 + (slot << 4));
            }
            #pragma unroll
            for (int mf = 0; mf < 2; ++mf)
                #pragma unroll
                for (int nf = 0; nf < 2; ++nf)
                    acc[mf][nf] = __builtin_amdgcn_mfma_f32_16x16x32_bf16(af[mf], bfv[nf], acc[mf][nf], 0, 0, 0);
        }
        __syncthreads();
    }
    #pragma unroll
    for (int nf = 0; nf < 2; ++nf) {
        const int col = bn + wn + nf*16 + (lane & 15);
        const float bv = bias[col];
        #pragma unroll
        for (int mf = 0; mf < 2; ++mf) {
            #pragma unroll
            for (int r = 0; r < 4; ++r) {
                const int row = bm + wm + mf*16 + (lane >> 4)*4 + r;
                float v = acc[mf][nf][r] + bv;
                if (RELU) v = fmaxf(v, 0.f);
                if (OBF16) ((ushort*)Cv)[(size_t)row * N + col] = f2bf(v);
                else       ((float*)Cv)[(size_t)row * N + col] = v;
            }
        }
    }
}

// ---------------------------------------------------------------------------
// Fused relation MLP, both layers on MFMA, zero intermediate data movement
// (w2 k-permutation makes layer-1 C frags == layer-2 B frags in-register).
// This round: 64 pairs/wave (4 tiles) share the per-chunk weight ds_reads
// 4-ways and give 4 independent MFMA dependency chains for latency hiding.
// LDS = w1t 8 KB + w2t 8 KB.
// ---------------------------------------------------------------------------
__global__ __launch_bounds__(256) void relmlp_kernel(const float* __restrict__ rel,
                                                     const float* __restrict__ w1,
                                                     const float* __restrict__ b1,
                                                     const float* __restrict__ w2,
                                                     float* __restrict__ relb) {
    __shared__ __align__(16) ushort w1t[512 * 8];   // [n][8k]: w1[0..3][n], b1[n], 0,0,0
    __shared__ __align__(16) ushort w2t[8 * 512];   // [h][kpos], swizzled + n-permuted
    const int tid = threadIdx.x;
    #pragma unroll
    for (int u = 0; u < 2; ++u) {
        const int n = tid + u*256;
        uint4 o;
        o.x = (unsigned)f2bf(w1[n])        | ((unsigned)f2bf(w1[512 + n])  << 16);
        o.y = (unsigned)f2bf(w1[1024 + n]) | ((unsigned)f2bf(w1[1536 + n]) << 16);
        o.z = (unsigned)f2bf(b1[n]);        // k=4 -> b1, k=5 -> 0
        o.w = 0;                            // k=6,7 -> 0
        *(uint4*)&w1t[n * 8] = o;
        // permuted k-position for layer-2 contraction order
        const int ch = n >> 5, w = n & 31, t = w >> 4, i = w & 15;
        const int s = ((i >> 2) << 3) + (t << 2) + (i & 3);
        const int kpos = ch * 32 + s;
        const float4 wlo = *(const float4*)&w2[n*8];
        const float4 whi = *(const float4*)&w2[n*8 + 4];
        const float wvv[8] = {wlo.x, wlo.y, wlo.z, wlo.w, whi.x, whi.y, whi.z, whi.w};
        #pragma unroll
        for (int h = 0; h < 8; ++h) {
            *(ushort*)((char*)w2t + h*1024 + (((kpos >> 3) ^ h) << 4) + (kpos & 7)*2) = f2bf(wvv[h]);
        }
    }
    __syncthreads();

    const int lane = tid & 63, wvid = tid >> 6;
    const int g = lane >> 4, lr = lane & 15;
    const f32x4 z4 = {0.f, 0.f, 0.f, 0.f};
    const int pbase = blockIdx.x * 256 + wvid * 64;   // 64 pairs per wave

    short8v rf[4];
    #pragma unroll
    for (int pt = 0; pt < 4; ++pt) {
        short8v r8 = {0,0,0,0,0,0,0,0};
        if (g == 0) {
            const float4 ra = *(const float4*)&rel[(size_t)(pbase + pt*16 + lr) * 4];
            r8[0] = (short)f2bf(ra.x); r8[1] = (short)f2bf(ra.y);
            r8[2] = (short)f2bf(ra.z); r8[3] = (short)f2bf(ra.w);
            r8[4] = (short)0x3F80;     // 1.0 -> multiplies b1 row
        }
        rf[pt] = r8;
    }
    f32x4 acc[4];
    #pragma unroll
    for (int pt = 0; pt < 4; ++pt) acc[pt] = z4;

    #pragma unroll 2
    for (int ch = 0; ch < 16; ++ch) {
        // shared weight fragments for this chunk (3 ds_reads, reused by 4 tiles)
        short8v a2 = {0,0,0,0,0,0,0,0};
        if (lr < 8) a2 = *(const short8v*)((const char*)w2t + lr*1024 + (((ch*4 + g) ^ lr) << 4));
        short8v af0 = {0,0,0,0,0,0,0,0}, af1 = {0,0,0,0,0,0,0,0};
        if (g == 0) {
            af0 = *(const short8v*)&w1t[(ch*32 + lr) * 8];
            af1 = *(const short8v*)&w1t[(ch*32 + 16 + lr) * 8];
        }
        #pragma unroll
        for (int pt = 0; pt < 4; ++pt) {
            const f32x4 c0 = __builtin_amdgcn_mfma_f32_16x16x32_bf16(af0, rf[pt], z4, 0, 0, 0);
            const f32x4 c1 = __builtin_amdgcn_mfma_f32_16x16x32_bf16(af1, rf[pt], z4, 0, 0, 0);
            V8 bfrag;
            bfrag.u.x = pk2r(c0[0], c0[1]); bfrag.u.y = pk2r(c0[2], c0[3]);
            bfrag.u.z = pk2r(c1[0], c1[1]); bfrag.u.w = pk2r(c1[2], c1[3]);
            acc[pt] = __builtin_amdgcn_mfma_f32_16x16x32_bf16(a2, bfrag.s, acc[pt], 0, 0, 0);
        }
    }
    // ---- epilogue: C col = pair, row = h = g*4 + r (g<2 real) ----
    if (g < 2) {
        #pragma unroll
        for (int pt = 0; pt < 4; ++pt) {
            const int pair = pbase + pt*16 + lr;
            const int bb_  = pair >> 18;
            const int ij   = pair & 262143;
            float* dst = relb + (((size_t)(bb_ * 8)) << 18) + ij;
            #pragma unroll
            for (int r = 0; r < 4; ++r) {
                const int h = g*4 + r;
                dst[(size_t)h << 18] = 16.0f / (1.0f + __expf(-acc[pt][r]));
            }
        }
    }
}

// ---------------------------------------------------------------------------
// S = 0.125*(Q @ K^T) + relb + maskbias   (in-place over relb) — bf16 MFMA.
// ---------------------------------------------------------------------------
__global__ __launch_bounds__(256) void smfma_kernel(const ushort* __restrict__ qkvb,
                                                    const float* __restrict__ maskf,
                                                    float* __restrict__ S) {
    const int bh = blockIdx.z;
    const int b = bh >> 3, h = bh & 7;
    const int bm = blockIdx.y * 64, bn = blockIdx.x * 64;
    __shared__ __align__(16) ushort As[64 * 64];
    __shared__ __align__(16) ushort Bs[64 * 64];
    const int tid = threadIdx.x;
    const int lane = tid & 63, wave = tid >> 6;
    const int wm = (wave >> 1) * 32, wn = (wave & 1) * 32;
    const int rs = tid >> 2, sl0 = (tid * 2) & 7;
    const ushort* Qb = qkvb + (size_t)(b*A_ + bm + rs) * TD_ + h*HD_;
    const ushort* Kb = qkvb + (size_t)(b*A_ + bn + rs) * TD_ + D_ + h*HD_;
    #pragma unroll
    for (int u = 0; u < 2; ++u) {
        const int sl = sl0 + u;
        *(uint4*)((char*)As + rs*128 + ((sl ^ (rs & 7)) << 4)) = *(const uint4*)&Qb[sl*8];
        *(uint4*)((char*)Bs + rs*128 + ((sl ^ (rs & 7)) << 4)) = *(const uint4*)&Kb[sl*8];
    }
    __syncthreads();
    f32x4 acc[2][2];
    #pragma unroll
    for (int i = 0; i < 2; ++i)
        #pragma unroll
        for (int j = 0; j < 2; ++j) acc[i][j] = (f32x4){0.f, 0.f, 0.f, 0.f};
    #pragma unroll
    for (int kk = 0; kk < 2; ++kk) {
        short8v af[2], bfv[2];
        #pragma unroll
        for (int mf = 0; mf < 2; ++mf) {
            const int row = wm + mf*16 + (lane & 15);
            const int slot = (kk*4 + (lane >> 4)) ^ (row & 7);
            af[mf] = *(const short8v*)((const char*)As + row*128 + (slot << 4));
        }
        #pragma unroll
        for (int nf = 0; nf < 2; ++nf) {
            const int row = wn + nf*16 + (lane & 15);
            const int slot = (kk*4 + (lane >> 4)) ^ (row & 7);
            bfv[nf] = *(const short8v*)((const char*)Bs + row*128 + (slot << 4));
        }
        #pragma unroll
        for (int mf = 0; mf < 2; ++mf)
            #pragma unroll
            for (int nf = 0; nf < 2; ++nf)
                acc[mf][nf] = __builtin_amdgcn_mfma_f32_16x16x32_bf16(af[mf], bfv[nf], acc[mf][nf], 0, 0, 0);
    }
    float* Sb = S + (size_t)bh * (A_ * A_);
    #pragma unroll
    for (int nf = 0; nf < 2; ++nf) {
        const int j = bn + wn + nf*16 + (lane & 15);
        const float mv = maskf[b*A_ + j];
        #pragma unroll
        for (int mf = 0; mf < 2; ++mf) {
            #pragma unroll
            for (int r = 0; r < 4; ++r) {
                const int i = bm + wm + mf*16 + (lane >> 4)*4 + r;
                const size_t idx = (size_t)i * A_ + j;
                Sb[idx] = acc[mf][nf][r] * 0.125f + Sb[idx] + mv;
            }
        }
    }
}

// ---------------------------------------------------------------------------
// Row softmax: read fp32 S, write bf16 P (8192 rows x 512).
// ---------------------------------------------------------------------------
__global__ __launch_bounds__(256) void softmax_kernel(const float* __restrict__ S,
                                                      ushort* __restrict__ P) {
    const size_t base = (size_t)blockIdx.x * A_;
    const int tid = threadIdx.x;
    float2 v = *reinterpret_cast<const float2*>(&S[base + tid*2]);
    float m = fmaxf(v.x, v.y);
    #pragma unroll
    for (int o = 32; o > 0; o >>= 1) m = fmaxf(m, __shfl_xor(m, o));
    __shared__ float rm[4], rs[4];
    if ((tid & 63) == 0) rm[tid >> 6] = m;
    __syncthreads();
    const float M = fmaxf(fmaxf(rm[0], rm[1]), fmaxf(rm[2], rm[3]));
    const float e0 = __expf(v.x - M), e1 = __expf(v.y - M);
    float s = e0 + e1;
    #pragma unroll
    for (int o = 32; o > 0; o >>= 1) s += __shfl_xor(s, o);
    if ((tid & 63) == 0) rs[tid >> 6] = s;
    __syncthreads();
    const float inv = 1.0f / (rs[0] + rs[1] + rs[2] + rs[3]);
    *(unsigned*)&P[base + tid*2] = pk2(e0 * inv, e1 * inv);
}

// ---------------------------------------------------------------------------
// VT[bh][d 0..63][j 0..511] bf16 <- V rows in qkvb. 64x64 tiles.
// ---------------------------------------------------------------------------
__global__ __launch_bounds__(256) void vt_kernel(const ushort* __restrict__ qkvb,
                                                 ushort* __restrict__ VT) {
    const int bh = blockIdx.y, jt = blockIdx.x;
    const int b = bh >> 3, h = bh & 7;
    __shared__ ushort ts[64][72];
    const int tid = threadIdx.x;
    const int r = tid >> 2, c16 = (tid & 3) * 16;
    const ushort* src = qkvb + (size_t)(b*A_ + jt*64 + r) * TD_ + 2*D_ + h*HD_ + c16;
    *(uint4*)&ts[r][c16]     = *(const uint4*)&src[0];
    *(uint4*)&ts[r][c16 + 8] = *(const uint4*)&src[8];
    __syncthreads();
    const int d = tid >> 2, jb = (tid & 3) * 16;
    unsigned pk[8];
    #pragma unroll
    for (int i = 0; i < 8; ++i)
        pk[i] = (unsigned)ts[jb + i*2][d] | ((unsigned)ts[jb + i*2 + 1][d] << 16);
    uint4* dst = (uint4*)&VT[(size_t)(bh*64 + d) * A_ + jt*64 + jb];
    dst[0] = make_uint4(pk[0], pk[1], pk[2], pk[3]);
    dst[1] = make_uint4(pk[4], pk[5], pk[6], pk[7]);
}

// ---------------------------------------------------------------------------
// O = P @ V via bf16 MFMA: A = P [i][j], BT = VT [d][j], K=512.
// ---------------------------------------------------------------------------
__global__ __launch_bounds__(256) void pvmfma_kernel(const ushort* __restrict__ P,
                                                     const ushort* __restrict__ VT,
                                                     float* __restrict__ outb) {
    const int bh = blockIdx.y;
    const int b = bh >> 3, h = bh & 7;
    const int bm = blockIdx.x * 64;
    __shared__ __align__(16) ushort As[64 * 64];
    __shared__ __align__(16) ushort Bs[64 * 64];
    const int tid = threadIdx.x;
    const int lane = tid & 63, wave = tid >> 6;
    const int wm = (wave >> 1) * 32, wn = (wave & 1) * 32;
    const int rs = tid >> 2, sl0 = (tid * 2) & 7;
    const ushort* Pb = P + (size_t)(bh*A_ + bm + rs) * A_;
    const ushort* Vb = VT + (size_t)(bh*64 + rs) * A_;
    f32x4 acc[2][2];
    #pragma unroll
    for (int i = 0; i < 2; ++i)
        #pragma unroll
        for (int j = 0; j < 2; ++j) acc[i][j] = (f32x4){0.f, 0.f, 0.f, 0.f};
    for (int k0 = 0; k0 < A_; k0 += 64) {
        #pragma unroll
        for (int u = 0; u < 2; ++u) {
            const int sl = sl0 + u;
            *(uint4*)((char*)As + rs*128 + ((sl ^ (rs & 7)) << 4)) = *(const uint4*)&Pb[k0 + sl*8];
            *(uint4*)((char*)Bs + rs*128 + ((sl ^ (rs & 7)) << 4)) = *(const uint4*)&Vb[k0 + sl*8];
        }
        __syncthreads();
        #pragma unroll
        for (int kk = 0; kk < 2; ++kk) {
            short8v af[2], bfv[2];
            #pragma unroll
            for (int mf = 0; mf < 2; ++mf) {
                const int row = wm + mf*16 + (lane & 15);
                const int slot = (kk*4 + (lane >> 4)) ^ (row & 7);
                af[mf] = *(const short8v*)((const char*)As + row*128 + (slot << 4));
            }
            #pragma unroll
            for (int nf = 0; nf < 2; ++nf) {
                const int row = wn + nf*16 + (lane & 15);
                const int slot = (kk*4 + (lane >> 4)) ^ (row & 7);
                bfv[nf] = *(const short8v*)((const char*)Bs + row*128 + (slot << 4));
            }
            #pragma unroll
            for (int mf = 0; mf < 2; ++mf)
                #pragma unroll
                for (int nf = 0; nf < 2; ++nf)
                    acc[mf][nf] = __builtin_amdgcn_mfma_f32_16x16x32_bf16(af[mf], bfv[nf], acc[mf][nf], 0, 0, 0);
        }
        __syncthreads();
    }
    #pragma unroll
    for (int nf = 0; nf < 2; ++nf) {
        const int dc = wn + nf*16 + (lane & 15);
        #pragma unroll
        for (int mf = 0; mf < 2; ++mf) {
            #pragma unroll
            for (int r = 0; r < 4; ++r) {
                const int i = bm + wm + mf*16 + (lane >> 4)*4 + r;
                outb[(size_t)(b*A_ + i) * D_ + h*HD_ + dc] = acc[mf][nf][r];
            }
        }
    }
}

// ---------------------------------------------------------------------------
// Fused residual + LayerNorm (512). Optional bf16 copy of the output.
// ---------------------------------------------------------------------------
template<int BF16OUT>
__global__ __launch_bounds__(256) void ln_kernel(const float* __restrict__ a,
                                                 const float* __restrict__ r,
                                                 const float* __restrict__ g,
                                                 const float* __restrict__ bb,
                                                 float* __restrict__ out,
                                                 ushort* __restrict__ outb) {
    const int row = blockIdx.x;
    const int tid = threadIdx.x;
    const size_t base = (size_t)row * D_ + tid * 2;
    const float2 a2 = *reinterpret_cast<const float2*>(&a[base]);
    const float2 r2 = *reinterpret_cast<const float2*>(&r[base]);
    const float e0 = a2.x + r2.x, e1 = a2.y + r2.y;
    float s = e0 + e1;
    float q = e0*e0 + e1*e1;
    #pragma unroll
    for (int o = 32; o > 0; o >>= 1) { s += __shfl_down(s, o); q += __shfl_down(q, o); }
    __shared__ float rs[4], rq[4];
    if ((tid & 63) == 0) { rs[tid >> 6] = s; rq[tid >> 6] = q; }
    __syncthreads();
    const float S = rs[0]+rs[1]+rs[2]+rs[3];
    const float Q = rq[0]+rq[1]+rq[2]+rq[3];
    const float mean = S * (1.0f/512.0f);
    const float var  = Q * (1.0f/512.0f) - mean*mean;
    const float rstd = rsqrtf(var + 1e-5f);
    const int c = tid*2;
    float2 ov;
    ov.x = (e0 - mean)*rstd*g[c]   + bb[c];
    ov.y = (e1 - mean)*rstd*g[c+1] + bb[c+1];
    *reinterpret_cast<float2*>(&out[base]) = ov;
    if (BF16OUT) {
        *(unsigned*)&outb[base] = pk2(ov.x, ov.y);
    }
}

// ---------------------------------------------------------------------------
extern "C" void kernel_launch(void* const* d_in, const int* in_sizes, int n_in,
                              void* d_out, int out_size, void* d_ws, size_t ws_size,
                              hipStream_t stream) {
    const float* x        = (const float*)d_in[0];
    const void*  mask     = d_in[1];
    const float* relation = (const float*)d_in[2];
    const float* qkv_w    = (const float*)d_in[3];
    const float* qkv_b    = (const float*)d_in[4];
    const float* rel_w1   = (const float*)d_in[5];
    const float* rel_b1   = (const float*)d_in[6];
    const float* rel_w2   = (const float*)d_in[7];
    const float* ff_w1    = (const float*)d_in[8];
    const float* ff_b1    = (const float*)d_in[9];
    const float* ff_w2    = (const float*)d_in[10];
    const float* ff_b2    = (const float*)d_in[11];
    const float* ln1_g    = (const float*)d_in[12];
    const float* ln1_b    = (const float*)d_in[13];
    const float* ln2_g    = (const float*)d_in[14];
    const float* ln2_b    = (const float*)d_in[15];
    float* out = (float*)d_out;

    float* ws     = (float*)d_ws;
    float*  relb  = ws;                            // 4,194,304 f (relb -> S)
    float*  maskf = relb  + 4194304;               // 1,024 f
    float*  attnb = maskf + 1024;                  // 524,288 f
    float*  x1    = attnb + 524288;                // 524,288 f
    ushort* wtb1  = (ushort*)(x1 + 524288);        // 786,432 ush (qkv_w^T)
    ushort* wtb2  = wtb1 + 786432;                 // 786,432 ush (ff_w1^T)
    ushort* wtb3  = wtb2 + 786432;                 // 786,432 ush (ff_w2^T)
    ushort* xb    = wtb3 + 786432;                 // 524,288 ush
    ushort* ffhb  = xb  + 524288;                  // 1,572,864 ush
    ushort* qkvb  = ffhb + 1572864;                // 1,572,864 ush (bf16 qkv)
    ushort* pb    = qkvb + 1572864;                // 4,194,304 ush (bf16 P)
    ushort* vtb   = pb + 4194304;                  // 524,288 ush (V^T)
    float*  ff2o  = (float*)qkvb;                  // reuse: qkvb dead after smfma
    ushort* x1b   = xb;                            // reuse: xb dead after qkv gemm

    // prep: mask bias + x->bf16, and all 3 weight transposes, up front
    prep_kernel<<<257, 256, 0, stream>>>(x, mask, xb, maskf);
    wt3_kernel<<<576, 256, 0, stream>>>(qkv_w, ff_w1, ff_w2, wtb1, wtb2, wtb3);
    // qkvb = bf16(x @ qkv_w + qkv_b)
    mgemm_kernel<0,1><<<dim3(24, 16), 256, 0, stream>>>(xb, wtb1, qkv_b, qkvb, 1024, 1536, 512);
    relmlp_kernel<<<2048, 256, 0, stream>>>(relation, rel_w1, rel_b1, rel_w2, relb);
    vt_kernel<<<dim3(8, 16), 256, 0, stream>>>(qkvb, vtb);
    // S = 0.125*Q@K^T + relb + mask (in place)
    smfma_kernel<<<dim3(8, 8, 16), 256, 0, stream>>>(qkvb, maskf, relb);
    // P = softmax(S) rows -> bf16
    softmax_kernel<<<16*512, 256, 0, stream>>>(relb, pb);
    // attnb = P @ V
    pvmfma_kernel<<<dim3(8, 16), 256, 0, stream>>>(pb, vtb, attnb);
    // x1 = LN(attn + x)
    ln_kernel<1><<<1024, 256, 0, stream>>>(attnb, x, ln1_g, ln1_b, x1, x1b);
    mgemm_kernel<1,1><<<dim3(24, 16), 256, 0, stream>>>(x1b, wtb2, ff_b1, ffhb, 1024, 1536, 512);
    mgemm_kernel<0,0><<<dim3(8, 16), 256, 0, stream>>>(ffhb, wtb3, ff_b2, ff2o, 1024, 512, 1536);
    ln_kernel<0><<<1024, 256, 0, stream>>>(ff2o, x1, ln2_g, ln2_b, out, nullptr);
}

// Round 10
// 115.777 us; speedup vs baseline: 4.6271x; 1.0746x over previous
//
#include <hip/hip_runtime.h>
#include <hip/hip_bf16.h>

#define A_  512
#define D_  512
#define H_  8
#define HD_ 64
#define TD_ 1536   // 3*D
#define RH_ 512    // REL_HID

typedef __attribute__((ext_vector_type(8))) short short8v;
typedef __attribute__((ext_vector_type(4))) float f32x4;
typedef __attribute__((ext_vector_type(4))) unsigned int u32x4;
union V8 { u32x4 u; short8v s; };

__device__ __forceinline__ unsigned short f2bf(float f) {
    unsigned int u = __float_as_uint(f);
    u += 0x7FFFu + ((u >> 16) & 1u);
    return (unsigned short)(u >> 16);
}
__device__ __forceinline__ float bf2f(unsigned short v) {
    return __uint_as_float((unsigned)v << 16);
}
// pack 2 f32 -> 2 bf16 in one v_cvt_pk_bf16_f32 (no builtin on gfx950)
__device__ __forceinline__ unsigned pk2(float a, float b) {
    unsigned r;
    asm("v_cvt_pk_bf16_f32 %0, %1, %2" : "=v"(r) : "v"(a), "v"(b));
    return r;
}
// relu + pack
__device__ __forceinline__ unsigned pk2r(float a, float b) {
    return pk2(fmaxf(a, 0.f), fmaxf(b, 0.f));
}

// ---------------------------------------------------------------------------
// prep: block 256 -> mask bias; blocks 0..255 -> x fp32 -> bf16.
// ---------------------------------------------------------------------------
__global__ __launch_bounds__(256) void prep_kernel(const float* __restrict__ x,
                                                   const void* __restrict__ mraw,
                                                   ushort* __restrict__ xb,
                                                   float* __restrict__ maskf) {
    const int tid = threadIdx.x;
    if (blockIdx.x == 256) {
        __shared__ int anyOdd;
        if (tid == 0) anyOdd = 0;
        __syncthreads();
        const unsigned char* mb = (const unsigned char*)mraw;
        int local = 0;
        #pragma unroll
        for (int u = 0; u < 4; ++u) {
            const int i = tid * 4 + u;
            if ((i & 3) != 0 && mb[i] != 0) local = 1;
        }
        if (local) atomicOr(&anyOdd, 1);
        __syncthreads();
        const bool isByte = (anyOdd != 0);
        #pragma unroll
        for (int u = 0; u < 4; ++u) {
            const int i = tid * 4 + u;
            int set = isByte ? (mb[i] != 0) : (((const int*)mraw)[i] != 0);
            maskf[i] = set ? -1e9f : 0.0f;
        }
        return;
    }
    const int i = (blockIdx.x * 256 + tid) * 8;
    const float4 a = *(const float4*)&x[i];
    const float4 b = *(const float4*)&x[i + 4];
    uint4 o;
    o.x = pk2(a.x, a.y);
    o.y = pk2(a.z, a.w);
    o.z = pk2(b.x, b.y);
    o.w = pk2(b.z, b.w);
    *(uint4*)&xb[i] = o;
}

// ---------------------------------------------------------------------------
// Transpose + cvt body: fp32 [R][C] -> bf16 [C][R], 64x64 tile.
// ---------------------------------------------------------------------------
__device__ __forceinline__ void wt_body(const float* __restrict__ in,
                                        ushort* __restrict__ out,
                                        int R, int C, int bx, int by) {
    __shared__ float ts[64][65];
    const int tid = threadIdx.x;
    const int r0 = by * 64, c0 = bx * 64;
    const int r = tid >> 2, cb = (tid & 3) * 16;
    #pragma unroll
    for (int u = 0; u < 4; ++u) {
        const float4 v = *(const float4*)&in[(size_t)(r0 + r) * C + c0 + cb + u*4];
        ts[r][cb + u*4 + 0] = v.x;
        ts[r][cb + u*4 + 1] = v.y;
        ts[r][cb + u*4 + 2] = v.z;
        ts[r][cb + u*4 + 3] = v.w;
    }
    __syncthreads();
    const int oc = tid & 63;
    const int rb = (tid >> 6) * 16;
    unsigned pk[8];
    #pragma unroll
    for (int i = 0; i < 8; ++i) {
        pk[i] = pk2(ts[rb + i*2][oc], ts[rb + i*2 + 1][oc]);
    }
    uint4* dst = (uint4*)&out[(size_t)(c0 + oc) * R + r0 + rb];
    dst[0] = make_uint4(pk[0], pk[1], pk[2], pk[3]);
    dst[1] = make_uint4(pk[4], pk[5], pk[6], pk[7]);
}

__global__ __launch_bounds__(256) void wt3_kernel(const float* __restrict__ qkv_w,
                                                  const float* __restrict__ ff_w1,
                                                  const float* __restrict__ ff_w2,
                                                  ushort* __restrict__ wtb1,
                                                  ushort* __restrict__ wtb2,
                                                  ushort* __restrict__ wtb3) {
    const int bid = blockIdx.x;
    if (bid < 192) {
        wt_body(qkv_w, wtb1, 512, 1536, bid % 24, bid / 24);
    } else if (bid < 384) {
        const int i = bid - 192;
        wt_body(ff_w1, wtb2, 512, 1536, i % 24, i / 24);
    } else {
        const int i = bid - 384;
        wt_body(ff_w2, wtb3, 1536, 512, i % 8, i / 8);
    }
}

// ---------------------------------------------------------------------------
// bf16 MFMA GEMM: C = op(A @ B + bias). A [M][K], BT [N][K]. 64x64, BK=64.
// SCALEQ: multiply cols < 512 by 0.125 (pre-scales Q in the qkv output).
// ---------------------------------------------------------------------------
template<int RELU, int OBF16, int SCALEQ>
__global__ __launch_bounds__(256) void mgemm_kernel(const ushort* __restrict__ A,
                                                    const ushort* __restrict__ BT,
                                                    const float* __restrict__ bias,
                                                    void* __restrict__ Cv,
                                                    int M, int N, int K) {
    __shared__ __align__(16) ushort As[64 * 64];
    __shared__ __align__(16) ushort Bs[64 * 64];
    const int tid = threadIdx.x;
    const int bm = blockIdx.y * 64, bn = blockIdx.x * 64;
    const int lane = tid & 63, wave = tid >> 6;
    const int wm = (wave >> 1) * 32, wn = (wave & 1) * 32;
    f32x4 acc[2][2];
    #pragma unroll
    for (int i = 0; i < 2; ++i)
        #pragma unroll
        for (int j = 0; j < 2; ++j) acc[i][j] = (f32x4){0.f, 0.f, 0.f, 0.f};

    const int s0  = tid * 2;
    const int rs  = s0 >> 3;
    const int sl0 = s0 & 7;
    for (int k0 = 0; k0 < K; k0 += 64) {
        #pragma unroll
        for (int u = 0; u < 2; ++u) {
            const int sl = sl0 + u;
            const uint4 va = *(const uint4*)&A[(size_t)(bm + rs) * K + k0 + sl*8];
            *(uint4*)((char*)As + rs*128 + ((sl ^ (rs & 7)) << 4)) = va;
            const uint4 vb = *(const uint4*)&BT[(size_t)(bn + rs) * K + k0 + sl*8];
            *(uint4*)((char*)Bs + rs*128 + ((sl ^ (rs & 7)) << 4)) = vb;
        }
        __syncthreads();
        #pragma unroll
        for (int kk = 0; kk < 2; ++kk) {
            short8v af[2], bfv[2];
            #pragma unroll
            for (int mf = 0; mf < 2; ++mf) {
                const int row = wm + mf*16 + (lane & 15);
                const int slot = (kk*4 + (lane >> 4)) ^ (row & 7);
                af[mf] = *(const short8v*)((const char*)As + row*128 + (slot << 4));
            }
            #pragma unroll
            for (int nf = 0; nf < 2; ++nf) {
                const int row = wn + nf*16 + (lane & 15);
                const int slot = (kk*4 + (lane >> 4)) ^ (row & 7);
                bfv[nf] = *(const short8v*)((const char*)Bs + row*128 + (slot << 4));
            }
            #pragma unroll
            for (int mf = 0; mf < 2; ++mf)
                #pragma unroll
                for (int nf = 0; nf < 2; ++nf)
                    acc[mf][nf] = __builtin_amdgcn_mfma_f32_16x16x32_bf16(af[mf], bfv[nf], acc[mf][nf], 0, 0, 0);
        }
        __syncthreads();
    }
    #pragma unroll
    for (int nf = 0; nf < 2; ++nf) {
        const int col = bn + wn + nf*16 + (lane & 15);
        const float bv = bias[col];
        const float qs = (SCALEQ && col < D_) ? 0.125f : 1.0f;
        #pragma unroll
        for (int mf = 0; mf < 2; ++mf) {
            #pragma unroll
            for (int r = 0; r < 4; ++r) {
                const int row = bm + wm + mf*16 + (lane >> 4)*4 + r;
                float v = acc[mf][nf][r] + bv;
                if (RELU) v = fmaxf(v, 0.f);
                if (SCALEQ) v *= qs;
                if (OBF16) ((ushort*)Cv)[(size_t)row * N + col] = f2bf(v);
                else       ((float*)Cv)[(size_t)row * N + col] = v;
            }
        }
    }
}

// ---------------------------------------------------------------------------
// Fused relation MLP (both layers MFMA, in-register handoff). Epilogue now
// folds the key-mask bias and writes bf16: relbM = bf16(16*sigmoid + mask).
// ---------------------------------------------------------------------------
__global__ __launch_bounds__(256) void relmlp_kernel(const float* __restrict__ rel,
                                                     const float* __restrict__ w1,
                                                     const float* __restrict__ b1,
                                                     const float* __restrict__ w2,
                                                     const float* __restrict__ maskf,
                                                     ushort* __restrict__ relbM) {
    __shared__ __align__(16) ushort w1t[512 * 8];
    __shared__ __align__(16) ushort w2t[8 * 512];
    const int tid = threadIdx.x;
    #pragma unroll
    for (int u = 0; u < 2; ++u) {
        const int n = tid + u*256;
        uint4 o;
        o.x = (unsigned)f2bf(w1[n])        | ((unsigned)f2bf(w1[512 + n])  << 16);
        o.y = (unsigned)f2bf(w1[1024 + n]) | ((unsigned)f2bf(w1[1536 + n]) << 16);
        o.z = (unsigned)f2bf(b1[n]);
        o.w = 0;
        *(uint4*)&w1t[n * 8] = o;
        const int ch = n >> 5, w = n & 31, t = w >> 4, i = w & 15;
        const int s = ((i >> 2) << 3) + (t << 2) + (i & 3);
        const int kpos = ch * 32 + s;
        const float4 wlo = *(const float4*)&w2[n*8];
        const float4 whi = *(const float4*)&w2[n*8 + 4];
        const float wvv[8] = {wlo.x, wlo.y, wlo.z, wlo.w, whi.x, whi.y, whi.z, whi.w};
        #pragma unroll
        for (int h = 0; h < 8; ++h) {
            *(ushort*)((char*)w2t + h*1024 + (((kpos >> 3) ^ h) << 4) + (kpos & 7)*2) = f2bf(wvv[h]);
        }
    }
    __syncthreads();

    const int lane = tid & 63, wvid = tid >> 6;
    const int g = lane >> 4, lr = lane & 15;
    const f32x4 z4 = {0.f, 0.f, 0.f, 0.f};
    const int pbase = blockIdx.x * 256 + wvid * 64;

    short8v rf[4];
    #pragma unroll
    for (int pt = 0; pt < 4; ++pt) {
        short8v r8 = {0,0,0,0,0,0,0,0};
        if (g == 0) {
            const float4 ra = *(const float4*)&rel[(size_t)(pbase + pt*16 + lr) * 4];
            r8[0] = (short)f2bf(ra.x); r8[1] = (short)f2bf(ra.y);
            r8[2] = (short)f2bf(ra.z); r8[3] = (short)f2bf(ra.w);
            r8[4] = (short)0x3F80;
        }
        rf[pt] = r8;
    }
    f32x4 acc[4];
    #pragma unroll
    for (int pt = 0; pt < 4; ++pt) acc[pt] = z4;

    #pragma unroll 2
    for (int ch = 0; ch < 16; ++ch) {
        short8v a2 = {0,0,0,0,0,0,0,0};
        if (lr < 8) a2 = *(const short8v*)((const char*)w2t + lr*1024 + (((ch*4 + g) ^ lr) << 4));
        short8v af0 = {0,0,0,0,0,0,0,0}, af1 = {0,0,0,0,0,0,0,0};
        if (g == 0) {
            af0 = *(const short8v*)&w1t[(ch*32 + lr) * 8];
            af1 = *(const short8v*)&w1t[(ch*32 + 16 + lr) * 8];
        }
        #pragma unroll
        for (int pt = 0; pt < 4; ++pt) {
            const f32x4 c0 = __builtin_amdgcn_mfma_f32_16x16x32_bf16(af0, rf[pt], z4, 0, 0, 0);
            const f32x4 c1 = __builtin_amdgcn_mfma_f32_16x16x32_bf16(af1, rf[pt], z4, 0, 0, 0);
            V8 bfrag;
            bfrag.u.x = pk2r(c0[0], c0[1]); bfrag.u.y = pk2r(c0[2], c0[3]);
            bfrag.u.z = pk2r(c1[0], c1[1]); bfrag.u.w = pk2r(c1[2], c1[3]);
            acc[pt] = __builtin_amdgcn_mfma_f32_16x16x32_bf16(a2, bfrag.s, acc[pt], 0, 0, 0);
        }
    }
    if (g < 2) {
        #pragma unroll
        for (int pt = 0; pt < 4; ++pt) {
            const int pair = pbase + pt*16 + lr;
            const int bb_  = pair >> 18;
            const int ij   = pair & 262143;
            const float mv = maskf[bb_ * A_ + (pair & 511)];
            ushort* dst = relbM + (((size_t)(bb_ * 8)) << 18) + ij;
            #pragma unroll
            for (int r = 0; r < 4; ++r) {
                const int h = g*4 + r;
                dst[(size_t)h << 18] = f2bf(16.0f / (1.0f + __expf(-acc[pt][r])) + mv);
            }
        }
    }
}

// ---------------------------------------------------------------------------
// VT[bh][d][j] bf16 <- V rows in qkvb. 64x64 tiles.
// ---------------------------------------------------------------------------
__global__ __launch_bounds__(256) void vt_kernel(const ushort* __restrict__ qkvb,
                                                 ushort* __restrict__ VT) {
    const int bh = blockIdx.y, jt = blockIdx.x;
    const int b = bh >> 3, h = bh & 7;
    __shared__ ushort ts[64][72];
    const int tid = threadIdx.x;
    const int r = tid >> 2, c16 = (tid & 3) * 16;
    const ushort* src = qkvb + (size_t)(b*A_ + jt*64 + r) * TD_ + 2*D_ + h*HD_ + c16;
    *(uint4*)&ts[r][c16]     = *(const uint4*)&src[0];
    *(uint4*)&ts[r][c16 + 8] = *(const uint4*)&src[8];
    __syncthreads();
    const int d = tid >> 2, jb = (tid & 3) * 16;
    unsigned pk[8];
    #pragma unroll
    for (int i = 0; i < 8; ++i)
        pk[i] = (unsigned)ts[jb + i*2][d] | ((unsigned)ts[jb + i*2 + 1][d] << 16);
    uint4* dst = (uint4*)&VT[(size_t)(bh*64 + d) * A_ + jt*64 + jb];
    dst[0] = make_uint4(pk[0], pk[1], pk[2], pk[3]);
    dst[1] = make_uint4(pk[4], pk[5], pk[6], pk[7]);
}

// ---------------------------------------------------------------------------
// Fused attention: one wave per (bh, 16-row i-tile). Swapped QK^T keeps the
// full 512-logit row of i=lane&15 in registers (128 f32 across 4 lane-groups);
// row softmax in-register (+2 shfl); P -> 16KB swizzled LDS (= A-frag layout);
// PV with V-fragments read directly from VT (coalesced 16B). S,P never global.
// Q pre-scaled by 0.125; relbM already holds 16*sigmoid + mask (bf16).
// ---------------------------------------------------------------------------
__global__ __launch_bounds__(64) void attn_kernel(const ushort* __restrict__ qkvb,
                                                  const ushort* __restrict__ relbM,
                                                  const ushort* __restrict__ vtb,
                                                  float* __restrict__ outb) {
    const int blk = blockIdx.x;
    const int bh = blk >> 5, it = blk & 31;
    const int b = bh >> 3, h = bh & 7;
    const int i0 = it * 16;
    const int lane = threadIdx.x;
    const int g = lane >> 4, lr = lane & 15;
    __shared__ __align__(16) ushort Pl[16 * 512];   // [i][j], slot-XOR swizzled

    // Q B-frags: col=i=lr, k=d (2 chunks of 32)
    const ushort* Qrow = qkvb + (size_t)(b*A_ + i0 + lr) * TD_ + h*HD_;
    const short8v qf0 = *(const short8v*)&Qrow[g*8];
    const short8v qf1 = *(const short8v*)&Qrow[32 + g*8];

    // QK^T: s[jt][r] = S[j = jt*16 + 4g + r][i = i0 + lr]
    const ushort* Kbase = qkvb + (size_t)(b*A_) * TD_ + D_ + h*HD_;
    f32x4 s[32];
    #pragma unroll
    for (int jt = 0; jt < 32; ++jt) {
        const ushort* Krow = Kbase + (size_t)(jt*16 + lr) * TD_;
        const short8v a0 = *(const short8v*)&Krow[g*8];
        const short8v a1 = *(const short8v*)&Krow[32 + g*8];
        f32x4 c = {0.f, 0.f, 0.f, 0.f};
        c = __builtin_amdgcn_mfma_f32_16x16x32_bf16(a0, qf0, c, 0, 0, 0);
        c = __builtin_amdgcn_mfma_f32_16x16x32_bf16(a1, qf1, c, 0, 0, 0);
        s[jt] = c;
    }
    // + relbM (bias+mask), bf16 -> f32
    const ushort* rb = relbM + ((size_t)bh << 18) + (size_t)(i0 + lr) * A_;
    #pragma unroll
    for (int jt = 0; jt < 32; ++jt) {
        const uint2 m2 = *(const uint2*)&rb[jt*16 + g*4];
        s[jt][0] += __uint_as_float(m2.x << 16);
        s[jt][1] += __uint_as_float(m2.x & 0xFFFF0000u);
        s[jt][2] += __uint_as_float(m2.y << 16);
        s[jt][3] += __uint_as_float(m2.y & 0xFFFF0000u);
    }
    // row max (row i = lr spans this lane's 128 regs + lanes g^1, g^2)
    float mx = -3.0e38f;
    #pragma unroll
    for (int jt = 0; jt < 32; ++jt)
        mx = fmaxf(mx, fmaxf(fmaxf(s[jt][0], s[jt][1]), fmaxf(s[jt][2], s[jt][3])));
    mx = fmaxf(mx, __shfl_xor(mx, 16));
    mx = fmaxf(mx, __shfl_xor(mx, 32));
    // exp + sum
    float sum = 0.f;
    #pragma unroll
    for (int jt = 0; jt < 32; ++jt) {
        #pragma unroll
        for (int r = 0; r < 4; ++r) {
            const float e = __expf(s[jt][r] - mx);
            s[jt][r] = e;
            sum += e;
        }
    }
    sum += __shfl_xor(sum, 16);
    sum += __shfl_xor(sum, 32);
    const float inv = 1.0f / sum;
    // P -> LDS bf16 (row i=lr, swizzled slots); one b64 write per jt
    char* Plc = (char*)Pl;
    #pragma unroll
    for (int jt = 0; jt < 32; ++jt) {
        uint2 w;
        w.x = pk2(s[jt][0] * inv, s[jt][1] * inv);
        w.y = pk2(s[jt][2] * inv, s[jt][3] * inv);
        const int j0 = jt*16 + g*4;
        *(uint2*)(Plc + lr*1024 + (((j0 >> 3) ^ (lr & 7)) << 4) + (j0 & 7)*2) = w;
    }
    __syncthreads();
    // PV: O[i = 4g+r][d = dt*16 + lr]
    f32x4 o[4];
    #pragma unroll
    for (int dt = 0; dt < 4; ++dt) o[dt] = (f32x4){0.f, 0.f, 0.f, 0.f};
    const ushort* Vb = vtb + (size_t)bh * 64 * A_;
    #pragma unroll
    for (int c = 0; c < 16; ++c) {
        const short8v pa = *(const short8v*)(Plc + lr*1024 + (((c*4 + g) ^ (lr & 7)) << 4));
        #pragma unroll
        for (int dt = 0; dt < 4; ++dt) {
            const short8v vf = *(const short8v*)&Vb[(size_t)(dt*16 + lr) * A_ + c*32 + g*8];
            o[dt] = __builtin_amdgcn_mfma_f32_16x16x32_bf16(pa, vf, o[dt], 0, 0, 0);
        }
    }
    float* Ob = outb + (size_t)(b*A_ + i0) * D_ + h*HD_;
    #pragma unroll
    for (int dt = 0; dt < 4; ++dt)
        #pragma unroll
        for (int r = 0; r < 4; ++r)
            Ob[(size_t)(g*4 + r) * D_ + dt*16 + lr] = o[dt][r];
}

// ---------------------------------------------------------------------------
// Fused residual + LayerNorm (512). Optional bf16 copy of the output.
// ---------------------------------------------------------------------------
template<int BF16OUT>
__global__ __launch_bounds__(256) void ln_kernel(const float* __restrict__ a,
                                                 const float* __restrict__ r,
                                                 const float* __restrict__ g,
                                                 const float* __restrict__ bb,
                                                 float* __restrict__ out,
                                                 ushort* __restrict__ outb) {
    const int row = blockIdx.x;
    const int tid = threadIdx.x;
    const size_t base = (size_t)row * D_ + tid * 2;
    const float2 a2 = *reinterpret_cast<const float2*>(&a[base]);
    const float2 r2 = *reinterpret_cast<const float2*>(&r[base]);
    const float e0 = a2.x + r2.x, e1 = a2.y + r2.y;
    float s = e0 + e1;
    float q = e0*e0 + e1*e1;
    #pragma unroll
    for (int o = 32; o > 0; o >>= 1) { s += __shfl_down(s, o); q += __shfl_down(q, o); }
    __shared__ float rs[4], rq[4];
    if ((tid & 63) == 0) { rs[tid >> 6] = s; rq[tid >> 6] = q; }
    __syncthreads();
    const float S = rs[0]+rs[1]+rs[2]+rs[3];
    const float Q = rq[0]+rq[1]+rq[2]+rq[3];
    const float mean = S * (1.0f/512.0f);
    const float var  = Q * (1.0f/512.0f) - mean*mean;
    const float rstd = rsqrtf(var + 1e-5f);
    const int c = tid*2;
    float2 ov;
    ov.x = (e0 - mean)*rstd*g[c]   + bb[c];
    ov.y = (e1 - mean)*rstd*g[c+1] + bb[c+1];
    *reinterpret_cast<float2*>(&out[base]) = ov;
    if (BF16OUT) {
        *(unsigned*)&outb[base] = pk2(ov.x, ov.y);
    }
}

// ---------------------------------------------------------------------------
extern "C" void kernel_launch(void* const* d_in, const int* in_sizes, int n_in,
                              void* d_out, int out_size, void* d_ws, size_t ws_size,
                              hipStream_t stream) {
    const float* x        = (const float*)d_in[0];
    const void*  mask     = d_in[1];
    const float* relation = (const float*)d_in[2];
    const float* qkv_w    = (const float*)d_in[3];
    const float* qkv_b    = (const float*)d_in[4];
    const float* rel_w1   = (const float*)d_in[5];
    const float* rel_b1   = (const float*)d_in[6];
    const float* rel_w2   = (const float*)d_in[7];
    const float* ff_w1    = (const float*)d_in[8];
    const float* ff_b1    = (const float*)d_in[9];
    const float* ff_w2    = (const float*)d_in[10];
    const float* ff_b2    = (const float*)d_in[11];
    const float* ln1_g    = (const float*)d_in[12];
    const float* ln1_b    = (const float*)d_in[13];
    const float* ln2_g    = (const float*)d_in[14];
    const float* ln2_b    = (const float*)d_in[15];
    float* out = (float*)d_out;

    float* ws     = (float*)d_ws;
    ushort* relbM = (ushort*)ws;                   // 4,194,304 ush (bf16, +mask)
    float*  maskf = (float*)(relbM + 4194304);     // 1,024 f
    float*  attnb = maskf + 1024;                  // 524,288 f
    float*  x1    = attnb + 524288;                // 524,288 f
    ushort* wtb1  = (ushort*)(x1 + 524288);        // 786,432 ush (qkv_w^T)
    ushort* wtb2  = wtb1 + 786432;                 // 786,432 ush (ff_w1^T)
    ushort* wtb3  = wtb2 + 786432;                 // 786,432 ush (ff_w2^T)
    ushort* xb    = wtb3 + 786432;                 // 524,288 ush
    ushort* ffhb  = xb  + 524288;                  // 1,572,864 ush
    ushort* qkvb  = ffhb + 1572864;                // 1,572,864 ush (bf16 qkv, Q pre-scaled)
    ushort* vtb   = qkvb + 1572864;                // 524,288 ush (V^T)
    float*  ff2o  = (float*)qkvb;                  // reuse: qkvb dead after attn
    ushort* x1b   = xb;                            // reuse: xb dead after qkv gemm

    prep_kernel<<<257, 256, 0, stream>>>(x, mask, xb, maskf);
    wt3_kernel<<<576, 256, 0, stream>>>(qkv_w, ff_w1, ff_w2, wtb1, wtb2, wtb3);
    // qkvb = bf16(x @ qkv_w + qkv_b), Q cols pre-scaled by 0.125
    mgemm_kernel<0,1,1><<<dim3(24, 16), 256, 0, stream>>>(xb, wtb1, qkv_b, qkvb, 1024, 1536, 512);
    relmlp_kernel<<<2048, 256, 0, stream>>>(relation, rel_w1, rel_b1, rel_w2, maskf, relbM);
    vt_kernel<<<dim3(8, 16), 256, 0, stream>>>(qkvb, vtb);
    // fused attention: S/P never leave the CU
    attn_kernel<<<512, 64, 0, stream>>>(qkvb, relbM, vtb, attnb);
    ln_kernel<1><<<1024, 256, 0, stream>>>(attnb, x, ln1_g, ln1_b, x1, x1b);
    mgemm_kernel<1,1,0><<<dim3(24, 16), 256, 0, stream>>>(x1b, wtb2, ff_b1, ffhb, 1024, 1536, 512);
    mgemm_kernel<0,0,0><<<dim3(8, 16), 256, 0, stream>>>(ffhb, wtb3, ff_b2, ff2o, 1024, 512, 1536);
    ln_kernel<0><<<1024, 256, 0, stream>>>(ff2o, x1, ln2_g, ln2_b, out, nullptr);
}

// Round 11
// 103.493 us; speedup vs baseline: 5.1763x; 1.1187x over previous
//
#include <hip/hip_runtime.h>
#include <hip/hip_bf16.h>

#define A_  512
#define D_  512
#define H_  8
#define HD_ 64
#define TD_ 1536   // 3*D
#define RH_ 512    // REL_HID

typedef __attribute__((ext_vector_type(8))) short short8v;
typedef __attribute__((ext_vector_type(4))) float f32x4;
typedef __attribute__((ext_vector_type(4))) unsigned int u32x4;
union V8 { u32x4 u; short8v s; };

__device__ __forceinline__ unsigned short f2bf(float f) {
    unsigned int u = __float_as_uint(f);
    u += 0x7FFFu + ((u >> 16) & 1u);
    return (unsigned short)(u >> 16);
}
// pack 2 f32 -> 2 bf16 in one v_cvt_pk_bf16_f32 (no builtin on gfx950)
__device__ __forceinline__ unsigned pk2(float a, float b) {
    unsigned r;
    asm("v_cvt_pk_bf16_f32 %0, %1, %2" : "=v"(r) : "v"(a), "v"(b));
    return r;
}
// relu + pack
__device__ __forceinline__ unsigned pk2r(float a, float b) {
    return pk2(fmaxf(a, 0.f), fmaxf(b, 0.f));
}

// ---------------------------------------------------------------------------
// Transpose + cvt body: fp32 [R][C] -> bf16 [C][R], 64x64 tile.
// ---------------------------------------------------------------------------
__device__ __forceinline__ void wt_body(float (*ts)[65],
                                        const float* __restrict__ in,
                                        ushort* __restrict__ out,
                                        int R, int C, int bx, int by) {
    const int tid = threadIdx.x;
    const int r0 = by * 64, c0 = bx * 64;
    const int r = tid >> 2, cb = (tid & 3) * 16;
    #pragma unroll
    for (int u = 0; u < 4; ++u) {
        const float4 v = *(const float4*)&in[(size_t)(r0 + r) * C + c0 + cb + u*4];
        ts[r][cb + u*4 + 0] = v.x;
        ts[r][cb + u*4 + 1] = v.y;
        ts[r][cb + u*4 + 2] = v.z;
        ts[r][cb + u*4 + 3] = v.w;
    }
    __syncthreads();
    const int oc = tid & 63;
    const int rb = (tid >> 6) * 16;
    unsigned pk[8];
    #pragma unroll
    for (int i = 0; i < 8; ++i) {
        pk[i] = pk2(ts[rb + i*2][oc], ts[rb + i*2 + 1][oc]);
    }
    uint4* dst = (uint4*)&out[(size_t)(c0 + oc) * R + r0 + rb];
    dst[0] = make_uint4(pk[0], pk[1], pk[2], pk[3]);
    dst[1] = make_uint4(pk[4], pk[5], pk[6], pk[7]);
}

// ---------------------------------------------------------------------------
// prep2: [0,256) x->bf16 ; 256 mask bias ; [257,449) qkv_w^T ;
//        [449,641) ff_w1^T ; [641,833) ff_w2^T.
// ---------------------------------------------------------------------------
__global__ __launch_bounds__(256) void prep2_kernel(const float* __restrict__ x,
                                                    const void* __restrict__ mraw,
                                                    const float* __restrict__ qkv_w,
                                                    const float* __restrict__ ff_w1,
                                                    const float* __restrict__ ff_w2,
                                                    ushort* __restrict__ xb,
                                                    float* __restrict__ maskf,
                                                    ushort* __restrict__ wtb1,
                                                    ushort* __restrict__ wtb2,
                                                    ushort* __restrict__ wtb3) {
    __shared__ __align__(16) float ts[64][65];
    const int tid = threadIdx.x;
    const int bid = blockIdx.x;
    if (bid < 256) {
        const int i = (bid * 256 + tid) * 8;
        const float4 a = *(const float4*)&x[i];
        const float4 b = *(const float4*)&x[i + 4];
        uint4 o;
        o.x = pk2(a.x, a.y);
        o.y = pk2(a.z, a.w);
        o.z = pk2(b.x, b.y);
        o.w = pk2(b.z, b.w);
        *(uint4*)&xb[i] = o;
    } else if (bid == 256) {
        int* anyOdd = (int*)ts;
        if (tid == 0) *anyOdd = 0;
        __syncthreads();
        const unsigned char* mb = (const unsigned char*)mraw;
        int local = 0;
        #pragma unroll
        for (int u = 0; u < 4; ++u) {
            const int i = tid * 4 + u;
            if ((i & 3) != 0 && mb[i] != 0) local = 1;
        }
        if (local) atomicOr(anyOdd, 1);
        __syncthreads();
        const bool isByte = (*anyOdd != 0);
        #pragma unroll
        for (int u = 0; u < 4; ++u) {
            const int i = tid * 4 + u;
            int set = isByte ? (mb[i] != 0) : (((const int*)mraw)[i] != 0);
            maskf[i] = set ? -1e9f : 0.0f;
        }
    } else if (bid < 449) {
        const int i = bid - 257;
        wt_body(ts, qkv_w, wtb1, 512, 1536, i % 24, i / 24);
    } else if (bid < 641) {
        const int i = bid - 449;
        wt_body(ts, ff_w1, wtb2, 512, 1536, i % 24, i / 24);
    } else {
        const int i = bid - 641;
        wt_body(ts, ff_w2, wtb3, 1536, 512, i % 8, i / 8);
    }
}

// ---------------------------------------------------------------------------
// bf16 MFMA GEMM body (64x64 tile, BK=64, 4 waves, slot-XOR swizzle).
// ---------------------------------------------------------------------------
template<int RELU, int OBF16, int SCALEQ>
__device__ __forceinline__ void mgemm_body(ushort* As, ushort* Bs,
                                           const ushort* __restrict__ A,
                                           const ushort* __restrict__ BT,
                                           const float* __restrict__ bias,
                                           void* __restrict__ Cv,
                                           int N, int K, int bm, int bn) {
    const int tid = threadIdx.x;
    const int lane = tid & 63, wave = tid >> 6;
    const int wm = (wave >> 1) * 32, wn = (wave & 1) * 32;
    f32x4 acc[2][2];
    #pragma unroll
    for (int i = 0; i < 2; ++i)
        #pragma unroll
        for (int j = 0; j < 2; ++j) acc[i][j] = (f32x4){0.f, 0.f, 0.f, 0.f};

    const int s0  = tid * 2;
    const int rs  = s0 >> 3;
    const int sl0 = s0 & 7;
    for (int k0 = 0; k0 < K; k0 += 64) {
        #pragma unroll
        for (int u = 0; u < 2; ++u) {
            const int sl = sl0 + u;
            const uint4 va = *(const uint4*)&A[(size_t)(bm + rs) * K + k0 + sl*8];
            *(uint4*)((char*)As + rs*128 + ((sl ^ (rs & 7)) << 4)) = va;
            const uint4 vb = *(const uint4*)&BT[(size_t)(bn + rs) * K + k0 + sl*8];
            *(uint4*)((char*)Bs + rs*128 + ((sl ^ (rs & 7)) << 4)) = vb;
        }
        __syncthreads();
        #pragma unroll
        for (int kk = 0; kk < 2; ++kk) {
            short8v af[2], bfv[2];
            #pragma unroll
            for (int mf = 0; mf < 2; ++mf) {
                const int row = wm + mf*16 + (lane & 15);
                const int slot = (kk*4 + (lane >> 4)) ^ (row & 7);
                af[mf] = *(const short8v*)((const char*)As + row*128 + (slot << 4));
            }
            #pragma unroll
            for (int nf = 0; nf < 2; ++nf) {
                const int row = wn + nf*16 + (lane & 15);
                const int slot = (kk*4 + (lane >> 4)) ^ (row & 7);
                bfv[nf] = *(const short8v*)((const char*)Bs + row*128 + (slot << 4));
            }
            #pragma unroll
            for (int mf = 0; mf < 2; ++mf)
                #pragma unroll
                for (int nf = 0; nf < 2; ++nf)
                    acc[mf][nf] = __builtin_amdgcn_mfma_f32_16x16x32_bf16(af[mf], bfv[nf], acc[mf][nf], 0, 0, 0);
        }
        __syncthreads();
    }
    #pragma unroll
    for (int nf = 0; nf < 2; ++nf) {
        const int col = bn + wn + nf*16 + (lane & 15);
        const float bv = bias[col];
        const float qs = (SCALEQ && col < D_) ? 0.125f : 1.0f;
        #pragma unroll
        for (int mf = 0; mf < 2; ++mf) {
            #pragma unroll
            for (int r = 0; r < 4; ++r) {
                const int row = bm + wm + mf*16 + (lane >> 4)*4 + r;
                float v = acc[mf][nf][r] + bv;
                if (RELU) v = fmaxf(v, 0.f);
                if (SCALEQ) v *= qs;
                if (OBF16) ((ushort*)Cv)[(size_t)row * N + col] = f2bf(v);
                else       ((float*)Cv)[(size_t)row * N + col] = v;
            }
        }
    }
}

template<int RELU, int OBF16, int SCALEQ>
__global__ __launch_bounds__(256) void mgemm_kernel(const ushort* __restrict__ A,
                                                    const ushort* __restrict__ BT,
                                                    const float* __restrict__ bias,
                                                    void* __restrict__ Cv,
                                                    int M, int N, int K) {
    __shared__ __align__(16) ushort As[64 * 64];
    __shared__ __align__(16) ushort Bs[64 * 64];
    mgemm_body<RELU, OBF16, SCALEQ>(As, Bs, A, BT, bias, Cv, N, K,
                                    blockIdx.y * 64, blockIdx.x * 64);
}

// ---------------------------------------------------------------------------
// relmlp body: both layers MFMA, in-register handoff (w2 k-permuted).
// Unconditional fragment loads (A-garbage at k>=8 multiplies B=0; layer-2
// C rows 8..15 unused, lr>=8 lanes duplicate rows 0..7).
// ---------------------------------------------------------------------------
__device__ __forceinline__ void relmlp_body(ushort* w1t, ushort* w2t,
                                            const float* __restrict__ rel,
                                            const float* __restrict__ w1,
                                            const float* __restrict__ b1,
                                            const float* __restrict__ w2,
                                            const float* __restrict__ maskf,
                                            ushort* __restrict__ relbM,
                                            int bid) {
    const int tid = threadIdx.x;
    #pragma unroll
    for (int u = 0; u < 2; ++u) {
        const int n = tid + u*256;
        uint4 o;
        o.x = (unsigned)f2bf(w1[n])        | ((unsigned)f2bf(w1[512 + n])  << 16);
        o.y = (unsigned)f2bf(w1[1024 + n]) | ((unsigned)f2bf(w1[1536 + n]) << 16);
        o.z = (unsigned)f2bf(b1[n]);
        o.w = 0;
        *(uint4*)&w1t[n * 8] = o;
        const int ch = n >> 5, w = n & 31, t = w >> 4, i = w & 15;
        const int s = ((i >> 2) << 3) + (t << 2) + (i & 3);
        const int kpos = ch * 32 + s;
        const float4 wlo = *(const float4*)&w2[n*8];
        const float4 whi = *(const float4*)&w2[n*8 + 4];
        const float wvv[8] = {wlo.x, wlo.y, wlo.z, wlo.w, whi.x, whi.y, whi.z, whi.w};
        #pragma unroll
        for (int h = 0; h < 8; ++h) {
            *(ushort*)((char*)w2t + h*1024 + (((kpos >> 3) ^ h) << 4) + (kpos & 7)*2) = f2bf(wvv[h]);
        }
    }
    __syncthreads();

    const int lane = tid & 63, wvid = tid >> 6;
    const int g = lane >> 4, lr = lane & 15;
    const f32x4 z4 = {0.f, 0.f, 0.f, 0.f};
    const int pbase = bid * 256 + wvid * 64;

    short8v rf[4];
    #pragma unroll
    for (int pt = 0; pt < 4; ++pt) {
        short8v r8 = {0,0,0,0,0,0,0,0};
        if (g == 0) {
            const float4 ra = *(const float4*)&rel[(size_t)(pbase + pt*16 + lr) * 4];
            r8[0] = (short)f2bf(ra.x); r8[1] = (short)f2bf(ra.y);
            r8[2] = (short)f2bf(ra.z); r8[3] = (short)f2bf(ra.w);
            r8[4] = (short)0x3F80;
        }
        rf[pt] = r8;
    }
    f32x4 acc[4];
    #pragma unroll
    for (int pt = 0; pt < 4; ++pt) acc[pt] = z4;

    #pragma unroll 2
    for (int ch = 0; ch < 16; ++ch) {
        // unconditional fragment loads (see header comment for why safe)
        const short8v a2  = *(const short8v*)((const char*)w2t + (lr & 7)*1024 + (((ch*4 + g) ^ (lr & 7)) << 4));
        const short8v af0 = *(const short8v*)&w1t[(ch*32 + lr) * 8];
        const short8v af1 = *(const short8v*)&w1t[(ch*32 + 16 + lr) * 8];
        #pragma unroll
        for (int pt = 0; pt < 4; ++pt) {
            const f32x4 c0 = __builtin_amdgcn_mfma_f32_16x16x32_bf16(af0, rf[pt], z4, 0, 0, 0);
            const f32x4 c1 = __builtin_amdgcn_mfma_f32_16x16x32_bf16(af1, rf[pt], z4, 0, 0, 0);
            V8 bfrag;
            bfrag.u.x = pk2r(c0[0], c0[1]); bfrag.u.y = pk2r(c0[2], c0[3]);
            bfrag.u.z = pk2r(c1[0], c1[1]); bfrag.u.w = pk2r(c1[2], c1[3]);
            acc[pt] = __builtin_amdgcn_mfma_f32_16x16x32_bf16(a2, bfrag.s, acc[pt], 0, 0, 0);
        }
    }
    if (g < 2) {
        #pragma unroll
        for (int pt = 0; pt < 4; ++pt) {
            const int pair = pbase + pt*16 + lr;
            const int bb_  = pair >> 18;
            const int ij   = pair & 262143;
            const float mv = maskf[bb_ * A_ + (pair & 511)];
            ushort* dst = relbM + (((size_t)(bb_ * 8)) << 18) + ij;
            #pragma unroll
            for (int r = 0; r < 4; ++r) {
                const int h = g*4 + r;
                dst[(size_t)h << 18] = f2bf(16.0f / (1.0f + __expf(-acc[pt][r])) + mv);
            }
        }
    }
}

// ---------------------------------------------------------------------------
// fused: blocks [0,384) qkv GEMM (Q pre-scaled, bf16 out); [384,2432) relmlp.
// Independent stages share one launch so relmlp's idle MFMA pipe absorbs the
// GEMM while the GEMM's idle VALU absorbs relmlp.
// ---------------------------------------------------------------------------
__global__ __launch_bounds__(256) void fused_qr_kernel(const ushort* __restrict__ xb,
                                                       const ushort* __restrict__ wtb1,
                                                       const float* __restrict__ qkv_b,
                                                       ushort* __restrict__ qkvb,
                                                       const float* __restrict__ rel,
                                                       const float* __restrict__ w1,
                                                       const float* __restrict__ b1,
                                                       const float* __restrict__ w2,
                                                       const float* __restrict__ maskf,
                                                       ushort* __restrict__ relbM) {
    __shared__ __align__(16) char smem[16384];
    const int bid = blockIdx.x;
    if (bid < 384) {
        mgemm_body<0, 1, 1>((ushort*)smem, (ushort*)(smem + 8192),
                            xb, wtb1, qkv_b, qkvb, 1536, 512,
                            (bid / 24) * 64, (bid % 24) * 64);
    } else {
        relmlp_body((ushort*)smem, (ushort*)(smem + 8192),
                    rel, w1, b1, w2, maskf, relbM, bid - 384);
    }
}

// ---------------------------------------------------------------------------
// VT[bh][d][j] bf16 <- V rows in qkvb. 64x64 tiles.
// ---------------------------------------------------------------------------
__global__ __launch_bounds__(256) void vt_kernel(const ushort* __restrict__ qkvb,
                                                 ushort* __restrict__ VT) {
    const int bh = blockIdx.y, jt = blockIdx.x;
    const int b = bh >> 3, h = bh & 7;
    __shared__ ushort ts[64][72];
    const int tid = threadIdx.x;
    const int r = tid >> 2, c16 = (tid & 3) * 16;
    const ushort* src = qkvb + (size_t)(b*A_ + jt*64 + r) * TD_ + 2*D_ + h*HD_ + c16;
    *(uint4*)&ts[r][c16]     = *(const uint4*)&src[0];
    *(uint4*)&ts[r][c16 + 8] = *(const uint4*)&src[8];
    __syncthreads();
    const int d = tid >> 2, jb = (tid & 3) * 16;
    unsigned pk[8];
    #pragma unroll
    for (int i = 0; i < 8; ++i)
        pk[i] = (unsigned)ts[jb + i*2][d] | ((unsigned)ts[jb + i*2 + 1][d] << 16);
    uint4* dst = (uint4*)&VT[(size_t)(bh*64 + d) * A_ + jt*64 + jb];
    dst[0] = make_uint4(pk[0], pk[1], pk[2], pk[3]);
    dst[1] = make_uint4(pk[4], pk[5], pk[6], pk[7]);
}

// ---------------------------------------------------------------------------
// Fused attention: one wave per (bh, 16-row i-tile). Swapped QK^T; softmax
// in-register; P via swizzled LDS; V-frags straight from VT. S,P never global.
// ---------------------------------------------------------------------------
__global__ __launch_bounds__(64) void attn_kernel(const ushort* __restrict__ qkvb,
                                                  const ushort* __restrict__ relbM,
                                                  const ushort* __restrict__ vtb,
                                                  float* __restrict__ outb) {
    const int blk = blockIdx.x;
    const int bh = blk >> 5, it = blk & 31;
    const int b = bh >> 3, h = bh & 7;
    const int i0 = it * 16;
    const int lane = threadIdx.x;
    const int g = lane >> 4, lr = lane & 15;
    __shared__ __align__(16) ushort Pl[16 * 512];

    const ushort* Qrow = qkvb + (size_t)(b*A_ + i0 + lr) * TD_ + h*HD_;
    const short8v qf0 = *(const short8v*)&Qrow[g*8];
    const short8v qf1 = *(const short8v*)&Qrow[32 + g*8];

    const ushort* Kbase = qkvb + (size_t)(b*A_) * TD_ + D_ + h*HD_;
    f32x4 s[32];
    #pragma unroll
    for (int jt = 0; jt < 32; ++jt) {
        const ushort* Krow = Kbase + (size_t)(jt*16 + lr) * TD_;
        const short8v a0 = *(const short8v*)&Krow[g*8];
        const short8v a1 = *(const short8v*)&Krow[32 + g*8];
        f32x4 c = {0.f, 0.f, 0.f, 0.f};
        c = __builtin_amdgcn_mfma_f32_16x16x32_bf16(a0, qf0, c, 0, 0, 0);
        c = __builtin_amdgcn_mfma_f32_16x16x32_bf16(a1, qf1, c, 0, 0, 0);
        s[jt] = c;
    }
    const ushort* rb = relbM + ((size_t)bh << 18) + (size_t)(i0 + lr) * A_;
    #pragma unroll
    for (int jt = 0; jt < 32; ++jt) {
        const uint2 m2 = *(const uint2*)&rb[jt*16 + g*4];
        s[jt][0] += __uint_as_float(m2.x << 16);
        s[jt][1] += __uint_as_float(m2.x & 0xFFFF0000u);
        s[jt][2] += __uint_as_float(m2.y << 16);
        s[jt][3] += __uint_as_float(m2.y & 0xFFFF0000u);
    }
    float mx = -3.0e38f;
    #pragma unroll
    for (int jt = 0; jt < 32; ++jt)
        mx = fmaxf(mx, fmaxf(fmaxf(s[jt][0], s[jt][1]), fmaxf(s[jt][2], s[jt][3])));
    mx = fmaxf(mx, __shfl_xor(mx, 16));
    mx = fmaxf(mx, __shfl_xor(mx, 32));
    float sum = 0.f;
    #pragma unroll
    for (int jt = 0; jt < 32; ++jt) {
        #pragma unroll
        for (int r = 0; r < 4; ++r) {
            const float e = __expf(s[jt][r] - mx);
            s[jt][r] = e;
            sum += e;
        }
    }
    sum += __shfl_xor(sum, 16);
    sum += __shfl_xor(sum, 32);
    const float inv = 1.0f / sum;
    char* Plc = (char*)Pl;
    #pragma unroll
    for (int jt = 0; jt < 32; ++jt) {
        uint2 w;
        w.x = pk2(s[jt][0] * inv, s[jt][1] * inv);
        w.y = pk2(s[jt][2] * inv, s[jt][3] * inv);
        const int j0 = jt*16 + g*4;
        *(uint2*)(Plc + lr*1024 + (((j0 >> 3) ^ (lr & 7)) << 4) + (j0 & 7)*2) = w;
    }
    __syncthreads();
    f32x4 o[4];
    #pragma unroll
    for (int dt = 0; dt < 4; ++dt) o[dt] = (f32x4){0.f, 0.f, 0.f, 0.f};
    const ushort* Vb = vtb + (size_t)bh * 64 * A_;
    #pragma unroll
    for (int c = 0; c < 16; ++c) {
        const short8v pa = *(const short8v*)(Plc + lr*1024 + (((c*4 + g) ^ (lr & 7)) << 4));
        #pragma unroll
        for (int dt = 0; dt < 4; ++dt) {
            const short8v vf = *(const short8v*)&Vb[(size_t)(dt*16 + lr) * A_ + c*32 + g*8];
            o[dt] = __builtin_amdgcn_mfma_f32_16x16x32_bf16(pa, vf, o[dt], 0, 0, 0);
        }
    }
    float* Ob = outb + (size_t)(b*A_ + i0) * D_ + h*HD_;
    #pragma unroll
    for (int dt = 0; dt < 4; ++dt)
        #pragma unroll
        for (int r = 0; r < 4; ++r)
            Ob[(size_t)(g*4 + r) * D_ + dt*16 + lr] = o[dt][r];
}

// ---------------------------------------------------------------------------
// Fused residual + LayerNorm (512). Optional bf16 copy of the output.
// ---------------------------------------------------------------------------
template<int BF16OUT>
__global__ __launch_bounds__(256) void ln_kernel(const float* __restrict__ a,
                                                 const float* __restrict__ r,
                                                 const float* __restrict__ g,
                                                 const float* __restrict__ bb,
                                                 float* __restrict__ out,
                                                 ushort* __restrict__ outb) {
    const int row = blockIdx.x;
    const int tid = threadIdx.x;
    const size_t base = (size_t)row * D_ + tid * 2;
    const float2 a2 = *reinterpret_cast<const float2*>(&a[base]);
    const float2 r2 = *reinterpret_cast<const float2*>(&r[base]);
    const float e0 = a2.x + r2.x, e1 = a2.y + r2.y;
    float s = e0 + e1;
    float q = e0*e0 + e1*e1;
    #pragma unroll
    for (int o = 32; o > 0; o >>= 1) { s += __shfl_down(s, o); q += __shfl_down(q, o); }
    __shared__ float rs[4], rq[4];
    if ((tid & 63) == 0) { rs[tid >> 6] = s; rq[tid >> 6] = q; }
    __syncthreads();
    const float S = rs[0]+rs[1]+rs[2]+rs[3];
    const float Q = rq[0]+rq[1]+rq[2]+rq[3];
    const float mean = S * (1.0f/512.0f);
    const float var  = Q * (1.0f/512.0f) - mean*mean;
    const float rstd = rsqrtf(var + 1e-5f);
    const int c = tid*2;
    float2 ov;
    ov.x = (e0 - mean)*rstd*g[c]   + bb[c];
    ov.y = (e1 - mean)*rstd*g[c+1] + bb[c+1];
    *reinterpret_cast<float2*>(&out[base]) = ov;
    if (BF16OUT) {
        *(unsigned*)&outb[base] = pk2(ov.x, ov.y);
    }
}

// ---------------------------------------------------------------------------
extern "C" void kernel_launch(void* const* d_in, const int* in_sizes, int n_in,
                              void* d_out, int out_size, void* d_ws, size_t ws_size,
                              hipStream_t stream) {
    const float* x        = (const float*)d_in[0];
    const void*  mask     = d_in[1];
    const float* relation = (const float*)d_in[2];
    const float* qkv_w    = (const float*)d_in[3];
    const float* qkv_b    = (const float*)d_in[4];
    const float* rel_w1   = (const float*)d_in[5];
    const float* rel_b1   = (const float*)d_in[6];
    const float* rel_w2   = (const float*)d_in[7];
    const float* ff_w1    = (const float*)d_in[8];
    const float* ff_b1    = (const float*)d_in[9];
    const float* ff_w2    = (const float*)d_in[10];
    const float* ff_b2    = (const float*)d_in[11];
    const float* ln1_g    = (const float*)d_in[12];
    const float* ln1_b    = (const float*)d_in[13];
    const float* ln2_g    = (const float*)d_in[14];
    const float* ln2_b    = (const float*)d_in[15];
    float* out = (float*)d_out;

    float* ws     = (float*)d_ws;
    ushort* relbM = (ushort*)ws;                   // 4,194,304 ush (bf16, +mask)
    float*  maskf = (float*)(relbM + 4194304);     // 1,024 f
    float*  attnb = maskf + 1024;                  // 524,288 f
    float*  x1    = attnb + 524288;                // 524,288 f
    ushort* wtb1  = (ushort*)(x1 + 524288);        // 786,432 ush (qkv_w^T)
    ushort* wtb2  = wtb1 + 786432;                 // 786,432 ush (ff_w1^T)
    ushort* wtb3  = wtb2 + 786432;                 // 786,432 ush (ff_w2^T)
    ushort* xb    = wtb3 + 786432;                 // 524,288 ush
    ushort* ffhb  = xb  + 524288;                  // 1,572,864 ush
    ushort* qkvb  = ffhb + 1572864;                // 1,572,864 ush (bf16 qkv, Q pre-scaled)
    ushort* vtb   = qkvb + 1572864;                // 524,288 ush (V^T)
    float*  ff2o  = (float*)qkvb;                  // reuse: qkvb dead after attn
    ushort* x1b   = xb;                            // reuse: xb dead after fused_qr

    prep2_kernel<<<833, 256, 0, stream>>>(x, mask, qkv_w, ff_w1, ff_w2,
                                          xb, maskf, wtb1, wtb2, wtb3);
    // qkv GEMM (blocks 0..383) concurrent with relmlp (blocks 384..2431)
    fused_qr_kernel<<<2432, 256, 0, stream>>>(xb, wtb1, qkv_b, qkvb,
                                              relation, rel_w1, rel_b1, rel_w2,
                                              maskf, relbM);
    vt_kernel<<<dim3(8, 16), 256, 0, stream>>>(qkvb, vtb);
    attn_kernel<<<512, 64, 0, stream>>>(qkvb, relbM, vtb, attnb);
    ln_kernel<1><<<1024, 256, 0, stream>>>(attnb, x, ln1_g, ln1_b, x1, x1b);
    mgemm_kernel<1,1,0><<<dim3(24, 16), 256, 0, stream>>>(x1b, wtb2, ff_b1, ffhb, 1024, 1536, 512);
    mgemm_kernel<0,0,0><<<dim3(8, 16), 256, 0, stream>>>(ffhb, wtb3, ff_b2, ff2o, 1024, 512, 1536);
    ln_kernel<0><<<1024, 256, 0, stream>>>(ff2o, x1, ln2_g, ln2_b, out, nullptr);
}